// Round 1
// baseline (864.356 us; speedup 1.0000x reference)
//
#include <hip/hip_runtime.h>

#define NN 50000
#define NE 800000

static inline size_t align_up(size_t x, size_t a) { return (x + a - 1) & ~(a - 1); }

// ---------------------------------------------------------------------------
// edge_index dtype probe: if input is int64 (little-endian, values < 2^31),
// every odd int32 word of the first 32 entries is 0. If int32 random ids in
// [0,50000), probability of that is ~(1/50000)^32 = 0.
// ---------------------------------------------------------------------------
__global__ void detect_i64(const int* __restrict__ e, int* __restrict__ flag) {
    int ok = 1;
    for (int k = 1; k < 64; k += 2) ok &= (e[k] == 0);
    *flag = ok;
}

__device__ __forceinline__ int load_src(const int* e, int i, int is64, int E) {
    return is64 ? e[2 * i] : e[i];
}
__device__ __forceinline__ int load_dst(const int* e, int i, int is64, int E) {
    return is64 ? e[2 * (E + i)] : e[E + i];
}

__global__ void count_deg(const int* __restrict__ eidx, const int* __restrict__ flag,
                          int* __restrict__ deg, int E) {
    int i = blockIdx.x * blockDim.x + threadIdx.x;
    if (i >= E) return;
    int is64 = *flag;
    int d = load_dst(eidx, i, is64, E);
    atomicAdd(&deg[d], 1);
}

__global__ void dinv_kernel(const int* __restrict__ deg, float* __restrict__ dinv, int n) {
    int i = blockIdx.x * blockDim.x + threadIdx.x;
    if (i >= n) return;
    dinv[i] = rsqrtf((float)(deg[i] + 1));  // +1 self-loop; always > 0
}

// single-block exclusive scan over n (<= a few 100k) elements, 1024 threads
__global__ __launch_bounds__(1024) void exscan_kernel(const int* __restrict__ cnt,
                                                      int* __restrict__ row_start,
                                                      int* __restrict__ cursor, int n) {
    __shared__ int buf[1024];
    __shared__ int s_carry;
    const int tid = threadIdx.x;
    if (tid == 0) s_carry = 0;
    __syncthreads();
    for (int base = 0; base < n; base += 1024) {
        int i = base + tid;
        int v = (i < n) ? cnt[i] : 0;
        buf[tid] = v;
        __syncthreads();
        for (int off = 1; off < 1024; off <<= 1) {
            int t = (tid >= off) ? buf[tid - off] : 0;
            __syncthreads();
            buf[tid] += t;
            __syncthreads();
        }
        int inc = buf[tid];
        int carry = s_carry;
        int exc = carry + inc - v;
        if (i < n) { row_start[i] = exc; cursor[i] = exc; }
        int total = buf[1023];
        __syncthreads();
        if (tid == 0) s_carry = carry + total;
        __syncthreads();
    }
}

__global__ void scatter_edges(const int* __restrict__ eidx, const int* __restrict__ flag,
                              int* __restrict__ cursor, int* __restrict__ csr_src, int E) {
    int i = blockIdx.x * blockDim.x + threadIdx.x;
    if (i >= E) return;
    int is64 = *flag;
    int s = load_src(eidx, i, is64, E);
    int d = load_dst(eidx, i, is64, E);
    int pos = atomicAdd(&cursor[d], 1);
    csr_src[pos] = s;
}

// ---------------------------------------------------------------------------
// f32 tiled GEMM: C[N,M] = A[N,K] @ B[K,M].  K % BK == 0, M % BN == 0 assumed.
// block = (BM/TM)*(BN/TN) = 256 threads, each computes TM x TN outputs.
// ---------------------------------------------------------------------------
template <int BM, int BN, int BK, int TM, int TN>
__global__ __launch_bounds__(256) void gemm_f32(const float* __restrict__ A,
                                                const float* __restrict__ B,
                                                float* __restrict__ C,
                                                int N, int K, int M) {
    __shared__ float As[BK][BM + 1];
    __shared__ float Bs[BK][BN + 1];
    const int tid = threadIdx.x;
    const int tx = tid % (BN / TN);
    const int ty = tid / (BN / TN);
    const int row0 = blockIdx.y * BM;
    const int col0 = blockIdx.x * BN;

    float acc[TM][TN];
#pragma unroll
    for (int i = 0; i < TM; ++i)
#pragma unroll
        for (int j = 0; j < TN; ++j) acc[i][j] = 0.f;

    for (int k0 = 0; k0 < K; k0 += BK) {
        // load A tile (transposed into LDS)
        for (int idx = tid; idx < BM * BK; idx += 256) {
            int m = idx / BK;
            int k = idx % BK;
            int gr = row0 + m;
            As[k][m] = (gr < N) ? A[(size_t)gr * K + k0 + k] : 0.f;
        }
        // load B tile
        for (int idx = tid; idx < BK * BN; idx += 256) {
            int k = idx / BN;
            int nn = idx % BN;
            Bs[k][nn] = B[(size_t)(k0 + k) * M + col0 + nn];
        }
        __syncthreads();
#pragma unroll
        for (int k = 0; k < BK; ++k) {
            float a[TM], b[TN];
#pragma unroll
            for (int i = 0; i < TM; ++i) a[i] = As[k][ty * TM + i];
#pragma unroll
            for (int j = 0; j < TN; ++j) b[j] = Bs[k][tx * TN + j];
#pragma unroll
            for (int i = 0; i < TM; ++i)
#pragma unroll
                for (int j = 0; j < TN; ++j) acc[i][j] = fmaf(a[i], b[j], acc[i][j]);
        }
        __syncthreads();
    }
#pragma unroll
    for (int i = 0; i < TM; ++i) {
        int gr = row0 + ty * TM + i;
        if (gr < N) {
#pragma unroll
            for (int j = 0; j < TN; ++j)
                C[(size_t)gr * M + col0 + tx * TN + j] = acc[i][j];
        }
    }
}

// ---------------------------------------------------------------------------
// CSR aggregation: out[d][f] = bias[f] + sum_{s in N(d)} dinv[s]*dinv[d]*h[s][f]
//                              + dinv[d]^2 * h[d][f]    (self loop)
// one node per F threads; NPB nodes per block (block = F * NPB threads)
// ---------------------------------------------------------------------------
template <int F, int NPB>
__global__ __launch_bounds__(F * NPB) void agg_kernel(
    const float* __restrict__ h, const int* __restrict__ row_start,
    const int* __restrict__ deg_cnt, const int* __restrict__ csr_src,
    const float* __restrict__ dinv, const float* __restrict__ bias,
    float* __restrict__ out, int relu, int n) {
    const int local = threadIdx.x / F;
    const int f = threadIdx.x % F;
    const int node = blockIdx.x * NPB + local;
    if (node >= n) return;
    const float di = dinv[node];
    float acc = h[(size_t)node * F + f] * di * di;  // self loop
    const int beg = row_start[node];
    const int num = deg_cnt[node];
    for (int e = 0; e < num; ++e) {
        int s = csr_src[beg + e];
        float w = dinv[s] * di;
        acc = fmaf(h[(size_t)s * F + f], w, acc);
    }
    acc += bias[f];
    if (relu) acc = fmaxf(acc, 0.f);
    out[(size_t)node * F + f] = acc;
}

// ---------------------------------------------------------------------------
extern "C" void kernel_launch(void* const* d_in, const int* in_sizes, int n_in,
                              void* d_out, int out_size, void* d_ws, size_t ws_size,
                              hipStream_t stream) {
    const float* x   = (const float*)d_in[0];
    const int*   eix = (const int*)d_in[1];
    const float* W1  = (const float*)d_in[2];
    const float* b1  = (const float*)d_in[3];
    const float* W2  = (const float*)d_in[4];
    const float* b2  = (const float*)d_in[5];
    const float* W3  = (const float*)d_in[6];
    const float* b3  = (const float*)d_in[7];
    float* out = (float*)d_out;

    const int n = NN, E = NE;

    char* p = (char*)d_ws;
    auto alloc = [&](size_t bytes) { void* r = (void*)p; p += align_up(bytes, 256); return r; };
    int*   flag      = (int*)alloc(4);
    int*   deg_cnt   = (int*)alloc((size_t)n * 4);
    float* dinv      = (float*)alloc((size_t)n * 4);
    int*   row_start = (int*)alloc((size_t)n * 4);
    int*   cursor    = (int*)alloc((size_t)n * 4);
    int*   csr_src   = (int*)alloc((size_t)E * 4);
    float* bufA      = (float*)alloc((size_t)n * 256 * 4);
    float* bufB      = (float*)alloc((size_t)n * 256 * 4);
    (void)ws_size; (void)in_sizes; (void)n_in; (void)out_size;

    // ---- graph preprocessing (recomputed every call; deterministic) ----
    hipMemsetAsync(deg_cnt, 0, (size_t)n * 4, stream);
    detect_i64<<<1, 1, 0, stream>>>(eix, flag);
    count_deg<<<(E + 255) / 256, 256, 0, stream>>>(eix, flag, deg_cnt, E);
    dinv_kernel<<<(n + 255) / 256, 256, 0, stream>>>(deg_cnt, dinv, n);
    exscan_kernel<<<1, 1024, 0, stream>>>(deg_cnt, row_start, cursor, n);
    scatter_edges<<<(E + 255) / 256, 256, 0, stream>>>(eix, flag, cursor, csr_src, E);

    // ---- layer 1: x[N,128] @ W1[128,256] -> h1 ; agg -> x2 (relu) ----
    {
        dim3 grid(256 / 64, (n + 63) / 64);
        gemm_f32<64, 64, 16, 4, 4><<<grid, 256, 0, stream>>>(x, W1, bufA, n, 128, 256);
        agg_kernel<256, 1><<<n, 256, 0, stream>>>(bufA, row_start, deg_cnt, csr_src,
                                                  dinv, b1, bufB, 1, n);
    }
    // ---- layer 2: x2[N,256] @ W2[256,128] -> h2 ; agg -> x3 (relu) ----
    float* h2 = bufA;
    float* x3 = bufA + (size_t)n * 128;
    {
        dim3 grid(128 / 64, (n + 63) / 64);
        gemm_f32<64, 64, 16, 4, 4><<<grid, 256, 0, stream>>>(bufB, W2, h2, n, 256, 128);
        agg_kernel<128, 2><<<(n + 1) / 2, 256, 0, stream>>>(h2, row_start, deg_cnt, csr_src,
                                                            dinv, b2, x3, 1, n);
    }
    // ---- layer 3: x3[N,128] @ W3[128,32] -> h3 ; agg -> out (no relu) ----
    {
        dim3 grid(1, (n + 63) / 64);
        gemm_f32<64, 32, 16, 4, 2><<<grid, 256, 0, stream>>>(x3, W3, bufB, n, 128, 32);
        agg_kernel<32, 8><<<(n + 7) / 8, 256, 0, stream>>>(bufB, row_start, deg_cnt, csr_src,
                                                           dinv, b3, out, 0, n);
    }
}

// Round 2
// 522.143 us; speedup vs baseline: 1.6554x; 1.6554x over previous
//
#include <hip/hip_runtime.h>

#define NN 50000
#define NE 800000

static inline size_t align_up(size_t x, size_t a) { return (x + a - 1) & ~(a - 1); }

// ---------------------------------------------------------------------------
// edge_index dtype probe: if input is int64 (little-endian, values < 2^31),
// every odd int32 word of the first 32 entries is 0.
// ---------------------------------------------------------------------------
__global__ void detect_i64(const int* __restrict__ e, int* __restrict__ flag) {
    int ok = 1;
    for (int k = 1; k < 64; k += 2) ok &= (e[k] == 0);
    *flag = ok;
}

__device__ __forceinline__ int load_src(const int* e, int i, int is64, int E) {
    return is64 ? e[2 * i] : e[i];
}
__device__ __forceinline__ int load_dst(const int* e, int i, int is64, int E) {
    return is64 ? e[2 * (E + i)] : e[E + i];
}

__global__ void count_deg(const int* __restrict__ eidx, const int* __restrict__ flag,
                          int* __restrict__ deg, int E) {
    int i = blockIdx.x * blockDim.x + threadIdx.x;
    if (i >= E) return;
    int is64 = *flag;
    int d = load_dst(eidx, i, is64, E);
    atomicAdd(&deg[d], 1);
}

__global__ void dinv_kernel(const int* __restrict__ deg, float* __restrict__ dinv, int n) {
    int i = blockIdx.x * blockDim.x + threadIdx.x;
    if (i >= n) return;
    dinv[i] = rsqrtf((float)(deg[i] + 1));  // +1 self-loop; always > 0
}

// single-block exclusive scan, 1024 threads
__global__ __launch_bounds__(1024) void exscan_kernel(const int* __restrict__ cnt,
                                                      int* __restrict__ row_start,
                                                      int* __restrict__ cursor, int n) {
    __shared__ int buf[1024];
    __shared__ int s_carry;
    const int tid = threadIdx.x;
    if (tid == 0) s_carry = 0;
    __syncthreads();
    for (int base = 0; base < n; base += 1024) {
        int i = base + tid;
        int v = (i < n) ? cnt[i] : 0;
        buf[tid] = v;
        __syncthreads();
        for (int off = 1; off < 1024; off <<= 1) {
            int t = (tid >= off) ? buf[tid - off] : 0;
            __syncthreads();
            buf[tid] += t;
            __syncthreads();
        }
        int inc = buf[tid];
        int carry = s_carry;
        int exc = carry + inc - v;
        if (i < n) { row_start[i] = exc; cursor[i] = exc; }
        int total = buf[1023];
        __syncthreads();
        if (tid == 0) s_carry = carry + total;
        __syncthreads();
    }
}

// scatter edges into CSR, packing {src, dinv[src]} into int2 (one 8B entry)
__global__ void scatter_edges(const int* __restrict__ eidx, const int* __restrict__ flag,
                              const float* __restrict__ dinv,
                              int* __restrict__ cursor, int2* __restrict__ csr, int E) {
    int i = blockIdx.x * blockDim.x + threadIdx.x;
    if (i >= E) return;
    int is64 = *flag;
    int s = load_src(eidx, i, is64, E);
    int d = load_dst(eidx, i, is64, E);
    int pos = atomicAdd(&cursor[d], 1);
    csr[pos] = make_int2(s, __float_as_int(dinv[s]));
}

// ---------------------------------------------------------------------------
// f32 tiled GEMM with optional fused bias + relu epilogue
// ---------------------------------------------------------------------------
template <int BM, int BN, int BK, int TM, int TN, bool BIAS, bool RELU>
__global__ __launch_bounds__(256) void gemm_f32(const float* __restrict__ A,
                                                const float* __restrict__ B,
                                                const float* __restrict__ bias,
                                                float* __restrict__ C,
                                                int N, int K, int M) {
    __shared__ float As[BK][BM + 1];
    __shared__ float Bs[BK][BN + 1];
    const int tid = threadIdx.x;
    const int tx = tid % (BN / TN);
    const int ty = tid / (BN / TN);
    const int row0 = blockIdx.y * BM;
    const int col0 = blockIdx.x * BN;

    float acc[TM][TN];
#pragma unroll
    for (int i = 0; i < TM; ++i)
#pragma unroll
        for (int j = 0; j < TN; ++j) acc[i][j] = 0.f;

    for (int k0 = 0; k0 < K; k0 += BK) {
        for (int idx = tid; idx < BM * BK; idx += 256) {
            int m = idx / BK;
            int k = idx % BK;
            int gr = row0 + m;
            As[k][m] = (gr < N) ? A[(size_t)gr * K + k0 + k] : 0.f;
        }
        for (int idx = tid; idx < BK * BN; idx += 256) {
            int k = idx / BN;
            int nn = idx % BN;
            Bs[k][nn] = B[(size_t)(k0 + k) * M + col0 + nn];
        }
        __syncthreads();
#pragma unroll
        for (int k = 0; k < BK; ++k) {
            float a[TM], b[TN];
#pragma unroll
            for (int i = 0; i < TM; ++i) a[i] = As[k][ty * TM + i];
#pragma unroll
            for (int j = 0; j < TN; ++j) b[j] = Bs[k][tx * TN + j];
#pragma unroll
            for (int i = 0; i < TM; ++i)
#pragma unroll
                for (int j = 0; j < TN; ++j) acc[i][j] = fmaf(a[i], b[j], acc[i][j]);
        }
        __syncthreads();
    }
#pragma unroll
    for (int i = 0; i < TM; ++i) {
        int gr = row0 + ty * TM + i;
        if (gr < N) {
#pragma unroll
            for (int j = 0; j < TN; ++j) {
                float v = acc[i][j];
                if (BIAS) v += bias[col0 + tx * TN + j];
                if (RELU) v = fmaxf(v, 0.f);
                C[(size_t)gr * M + col0 + tx * TN + j] = v;
            }
        }
    }
}

// ---------------------------------------------------------------------------
// CSR aggregation, float4-vectorized, edge loop unrolled x4.
// out[d][:] = (bias) + dinv[d]^2*h[d][:] + sum_e (w_e*dinv[d]) * h[src_e][:]
// F features per node, L = F/4 lanes per node, NPB nodes per block.
// ---------------------------------------------------------------------------
__device__ __forceinline__ float4 fma4(float4 v, float w, float4 a) {
    a.x = fmaf(v.x, w, a.x);
    a.y = fmaf(v.y, w, a.y);
    a.z = fmaf(v.z, w, a.z);
    a.w = fmaf(v.w, w, a.w);
    return a;
}

template <int F, int NPB, bool BIAS, bool RELU>
__global__ __launch_bounds__((F / 4) * NPB) void agg4(
    const float* __restrict__ h, const int* __restrict__ row_start,
    const int* __restrict__ deg_cnt, const int2* __restrict__ csr,
    const float* __restrict__ dinv, const float* __restrict__ bias,
    float* __restrict__ out, int n) {
    constexpr int L = F / 4;
    const int local = threadIdx.x / L;
    const int lane = threadIdx.x % L;
    const int node = blockIdx.x * NPB + local;
    if (node >= n) return;

    const float4* __restrict__ h4 = (const float4*)h;
    const float di = dinv[node];

    float4 acc = h4[(size_t)node * L + lane];
    const float sw = di * di;
    acc.x *= sw; acc.y *= sw; acc.z *= sw; acc.w *= sw;

    const int beg = row_start[node];
    const int num = deg_cnt[node];
    int e = 0;
    for (; e + 4 <= num; e += 4) {
        const int2 c0 = csr[beg + e + 0];
        const int2 c1 = csr[beg + e + 1];
        const int2 c2 = csr[beg + e + 2];
        const int2 c3 = csr[beg + e + 3];
        const float4 v0 = h4[(size_t)c0.x * L + lane];
        const float4 v1 = h4[(size_t)c1.x * L + lane];
        const float4 v2 = h4[(size_t)c2.x * L + lane];
        const float4 v3 = h4[(size_t)c3.x * L + lane];
        acc = fma4(v0, __int_as_float(c0.y) * di, acc);
        acc = fma4(v1, __int_as_float(c1.y) * di, acc);
        acc = fma4(v2, __int_as_float(c2.y) * di, acc);
        acc = fma4(v3, __int_as_float(c3.y) * di, acc);
    }
    for (; e < num; ++e) {
        const int2 c = csr[beg + e];
        const float4 v = h4[(size_t)c.x * L + lane];
        acc = fma4(v, __int_as_float(c.y) * di, acc);
    }
    if (BIAS) {
        const float4 b = ((const float4*)bias)[lane];
        acc.x += b.x; acc.y += b.y; acc.z += b.z; acc.w += b.w;
    }
    if (RELU) {
        acc.x = fmaxf(acc.x, 0.f); acc.y = fmaxf(acc.y, 0.f);
        acc.z = fmaxf(acc.z, 0.f); acc.w = fmaxf(acc.w, 0.f);
    }
    ((float4*)out)[(size_t)node * L + lane] = acc;
}

// ---------------------------------------------------------------------------
extern "C" void kernel_launch(void* const* d_in, const int* in_sizes, int n_in,
                              void* d_out, int out_size, void* d_ws, size_t ws_size,
                              hipStream_t stream) {
    const float* x   = (const float*)d_in[0];
    const int*   eix = (const int*)d_in[1];
    const float* W1  = (const float*)d_in[2];
    const float* b1  = (const float*)d_in[3];
    const float* W2  = (const float*)d_in[4];
    const float* b2  = (const float*)d_in[5];
    const float* W3  = (const float*)d_in[6];
    const float* b3  = (const float*)d_in[7];
    float* out = (float*)d_out;

    const int n = NN, E = NE;

    char* p = (char*)d_ws;
    auto alloc = [&](size_t bytes) { void* r = (void*)p; p += align_up(bytes, 256); return r; };
    int*   flag      = (int*)alloc(4);
    int*   deg_cnt   = (int*)alloc((size_t)n * 4);
    float* dinv      = (float*)alloc((size_t)n * 4);
    int*   row_start = (int*)alloc((size_t)n * 4);
    int*   cursor    = (int*)alloc((size_t)n * 4);
    int2*  csr       = (int2*)alloc((size_t)E * 8);
    float* bufA      = (float*)alloc((size_t)n * 256 * 4);
    float* bufB      = (float*)alloc((size_t)n * 256 * 4);
    (void)ws_size; (void)in_sizes; (void)n_in; (void)out_size;

    // ---- graph preprocessing (recomputed every call; deterministic) ----
    hipMemsetAsync(deg_cnt, 0, (size_t)n * 4, stream);
    detect_i64<<<1, 1, 0, stream>>>(eix, flag);
    count_deg<<<(E + 255) / 256, 256, 0, stream>>>(eix, flag, deg_cnt, E);
    dinv_kernel<<<(n + 255) / 256, 256, 0, stream>>>(deg_cnt, dinv, n);
    exscan_kernel<<<1, 1024, 0, stream>>>(deg_cnt, row_start, cursor, n);
    scatter_edges<<<(E + 255) / 256, 256, 0, stream>>>(eix, flag, dinv, cursor, csr, E);

    // ---- layer 1: agg0 = A_norm @ x  [N,128]; h1 = relu(agg0 @ W1 + b1) [N,256]
    float* agg0 = bufA;
    float* h1   = bufB;
    agg4<128, 8, false, false><<<(n + 7) / 8, 256, 0, stream>>>(
        x, row_start, deg_cnt, csr, dinv, nullptr, agg0, n);
    {
        dim3 grid(256 / 64, (n + 63) / 64);
        gemm_f32<64, 64, 16, 4, 4, true, true><<<grid, 256, 0, stream>>>(
            agg0, W1, b1, h1, n, 128, 256);
    }

    // ---- layer 2: h2 = h1 @ W2 [N,128]; x3 = relu(agg(h2) + b2) [N,128]
    float* h2 = bufA;
    float* x3 = bufB;  // overwrites h1 after gemm2 consumed it (stream-ordered)
    {
        dim3 grid(128 / 64, (n + 63) / 64);
        gemm_f32<64, 64, 16, 4, 4, false, false><<<grid, 256, 0, stream>>>(
            h1, W2, nullptr, h2, n, 256, 128);
    }
    agg4<128, 8, true, true><<<(n + 7) / 8, 256, 0, stream>>>(
        h2, row_start, deg_cnt, csr, dinv, b2, x3, n);

    // ---- layer 3: h3 = x3 @ W3 [N,32]; out = agg(h3) + b3
    float* h3 = bufA;
    {
        dim3 grid(1, (n + 63) / 64);
        gemm_f32<64, 32, 16, 4, 2, false, false><<<grid, 256, 0, stream>>>(
            x3, W3, nullptr, h3, n, 128, 32);
    }
    agg4<32, 32, true, false><<<(n + 31) / 32, 256, 0, stream>>>(
        h3, row_start, deg_cnt, csr, dinv, b3, out, n);
}

// Round 3
// 397.644 us; speedup vs baseline: 2.1737x; 1.3131x over previous
//
#include <hip/hip_runtime.h>

#define NN 50000
#define NE 800000

typedef __attribute__((ext_vector_type(8))) short short8v;   // 8 bf16 in 4 VGPRs
typedef __attribute__((ext_vector_type(4))) float f32x4;

static inline size_t align_up(size_t x, size_t a) { return (x + a - 1) & ~(a - 1); }

__device__ __forceinline__ unsigned short f2bf(float f) {
    unsigned u = __float_as_uint(f);
    unsigned r = u + 0x7FFF + ((u >> 16) & 1);  // round-to-nearest-even
    return (unsigned short)(r >> 16);
}
__device__ __forceinline__ float bf2f(unsigned short h) {
    return __uint_as_float(((unsigned)h) << 16);
}

// ---------------------------------------------------------------------------
// edge_index dtype probe (int64 vs int32 layout)
// ---------------------------------------------------------------------------
__global__ void detect_i64(const int* __restrict__ e, int* __restrict__ flag) {
    int ok = 1;
    for (int k = 1; k < 64; k += 2) ok &= (e[k] == 0);
    *flag = ok;
}

__device__ __forceinline__ int load_src(const int* e, int i, int is64, int E) {
    return is64 ? e[2 * i] : e[i];
}
__device__ __forceinline__ int load_dst(const int* e, int i, int is64, int E) {
    return is64 ? e[2 * (E + i)] : e[E + i];
}

__global__ void count_deg(const int* __restrict__ eidx, const int* __restrict__ flag,
                          int* __restrict__ deg, int E) {
    int i = blockIdx.x * blockDim.x + threadIdx.x;
    if (i >= E) return;
    int is64 = *flag;
    int d = load_dst(eidx, i, is64, E);
    atomicAdd(&deg[d], 1);
}

__global__ void dinv_kernel(const int* __restrict__ deg, float* __restrict__ dinv, int n) {
    int i = blockIdx.x * blockDim.x + threadIdx.x;
    if (i >= n) return;
    dinv[i] = rsqrtf((float)(deg[i] + 1));
}

__global__ __launch_bounds__(1024) void exscan_kernel(const int* __restrict__ cnt,
                                                      int* __restrict__ row_start,
                                                      int* __restrict__ cursor, int n) {
    __shared__ int buf[1024];
    __shared__ int s_carry;
    const int tid = threadIdx.x;
    if (tid == 0) s_carry = 0;
    __syncthreads();
    for (int base = 0; base < n; base += 1024) {
        int i = base + tid;
        int v = (i < n) ? cnt[i] : 0;
        buf[tid] = v;
        __syncthreads();
        for (int off = 1; off < 1024; off <<= 1) {
            int t = (tid >= off) ? buf[tid - off] : 0;
            __syncthreads();
            buf[tid] += t;
            __syncthreads();
        }
        int inc = buf[tid];
        int carry = s_carry;
        int exc = carry + inc - v;
        if (i < n) { row_start[i] = exc; cursor[i] = exc; }
        int total = buf[1023];
        __syncthreads();
        if (tid == 0) s_carry = carry + total;
        __syncthreads();
    }
}

__global__ void scatter_edges(const int* __restrict__ eidx, const int* __restrict__ flag,
                              const float* __restrict__ dinv,
                              int* __restrict__ cursor, int2* __restrict__ csr, int E) {
    int i = blockIdx.x * blockDim.x + threadIdx.x;
    if (i >= E) return;
    int is64 = *flag;
    int s = load_src(eidx, i, is64, E);
    int d = load_dst(eidx, i, is64, E);
    int pos = atomicAdd(&cursor[d], 1);
    csr[pos] = make_int2(s, __float_as_int(dinv[s]));
}

// W[K][M] f32 -> transposed split bf16 Wt_hi[M][K], Wt_lo[M][K]
__global__ void prep_weight(const float* __restrict__ W, unsigned short* __restrict__ th,
                            unsigned short* __restrict__ tl, int K, int M) {
    int i = blockIdx.x * blockDim.x + threadIdx.x;
    if (i >= K * M) return;
    int k = i / M, m = i % M;
    float v = W[i];
    unsigned short h = f2bf(v);
    unsigned short l = f2bf(v - bf2f(h));
    th[(size_t)m * K + k] = h;
    tl[(size_t)m * K + k] = l;
}

// ---------------------------------------------------------------------------
// split-bf16 MFMA GEMM: C[N,M] = (Ahi+Alo)[N,K] @ (Bhi+Blo)[K,M]
// A given as row-major bf16 hi/lo; B given TRANSPOSED ([M][K]) bf16 hi/lo.
// 3 MFMA products: hi*hi + hi*lo + lo*hi (lo*lo dropped, ~2^-18 rel).
// block = 256 threads = 4 waves arranged WM x WN; 16x16x32 fragments.
// ---------------------------------------------------------------------------
template <int BM, int BN, int WM, int WN, bool BIAS, bool RELU, bool SPLITOUT>
__global__ __launch_bounds__(256) void gemm_mfma(
    const unsigned short* __restrict__ Ah, const unsigned short* __restrict__ Al,
    const unsigned short* __restrict__ Bth, const unsigned short* __restrict__ Btl,
    const float* __restrict__ bias,
    float* __restrict__ Cf, unsigned short* __restrict__ Ch, unsigned short* __restrict__ Cl,
    int N, int K, int M) {
    constexpr int KS = 32;
    constexpr int LDA = KS + 8;  // pad to 40 halfs (80B rows): 2-way LDS conflicts only
    constexpr int WTM = BM / WM;
    constexpr int WTN = BN / WN;
    constexpr int FM = WTM / 16;
    constexpr int FN = WTN / 16;
    __shared__ unsigned short sAh[BM][LDA], sAl[BM][LDA];
    __shared__ unsigned short sBh[BN][LDA], sBl[BN][LDA];

    const int tid = threadIdx.x;
    const int lane = tid & 63;
    const int w = tid >> 6;
    const int wr = w / WN, wc = w % WN;
    const int row0 = blockIdx.y * BM;
    const int col0 = blockIdx.x * BN;

    f32x4 acc[FM][FN];
#pragma unroll
    for (int m = 0; m < FM; ++m)
#pragma unroll
        for (int nn = 0; nn < FN; ++nn) {
            f32x4 z = {0.f, 0.f, 0.f, 0.f};
            acc[m][nn] = z;
        }

    for (int k0 = 0; k0 < K; k0 += KS) {
        // stage A tile (16B chunks)
        for (int idx = tid; idx < BM * KS / 8; idx += 256) {
            int r = idx / (KS / 8);
            int s = idx % (KS / 8);
            int gr = row0 + r;
            int4 vh = make_int4(0, 0, 0, 0), vl = make_int4(0, 0, 0, 0);
            if (gr < N) {
                vh = *(const int4*)&Ah[(size_t)gr * K + k0 + s * 8];
                vl = *(const int4*)&Al[(size_t)gr * K + k0 + s * 8];
            }
            *(int4*)&sAh[r][s * 8] = vh;
            *(int4*)&sAl[r][s * 8] = vl;
        }
        // stage B tile (M % BN == 0 for all our shapes)
        for (int idx = tid; idx < BN * KS / 8; idx += 256) {
            int c = idx / (KS / 8);
            int s = idx % (KS / 8);
            int gc = col0 + c;
            *(int4*)&sBh[c][s * 8] = *(const int4*)&Bth[(size_t)gc * K + k0 + s * 8];
            *(int4*)&sBl[c][s * 8] = *(const int4*)&Btl[(size_t)gc * K + k0 + s * 8];
        }
        __syncthreads();

        short8v afh[FM], afl[FM], bfh[FN], bfl[FN];
        const int koff = (lane >> 4) * 8;
        const int rsel = lane & 15;
#pragma unroll
        for (int m = 0; m < FM; ++m) {
            afh[m] = *(const short8v*)&sAh[wr * WTM + m * 16 + rsel][koff];
            afl[m] = *(const short8v*)&sAl[wr * WTM + m * 16 + rsel][koff];
        }
#pragma unroll
        for (int nn = 0; nn < FN; ++nn) {
            bfh[nn] = *(const short8v*)&sBh[wc * WTN + nn * 16 + rsel][koff];
            bfl[nn] = *(const short8v*)&sBl[wc * WTN + nn * 16 + rsel][koff];
        }
#pragma unroll
        for (int m = 0; m < FM; ++m)
#pragma unroll
            for (int nn = 0; nn < FN; ++nn) {
                acc[m][nn] = __builtin_amdgcn_mfma_f32_16x16x32_bf16(afh[m], bfh[nn], acc[m][nn], 0, 0, 0);
                acc[m][nn] = __builtin_amdgcn_mfma_f32_16x16x32_bf16(afh[m], bfl[nn], acc[m][nn], 0, 0, 0);
                acc[m][nn] = __builtin_amdgcn_mfma_f32_16x16x32_bf16(afl[m], bfh[nn], acc[m][nn], 0, 0, 0);
            }
        __syncthreads();
    }

    // epilogue: D layout col=lane&15, row=(lane>>4)*4+reg (m89-verified)
#pragma unroll
    for (int m = 0; m < FM; ++m) {
#pragma unroll
        for (int r = 0; r < 4; ++r) {
            int row = row0 + wr * WTM + m * 16 + (lane >> 4) * 4 + r;
            if (row >= N) continue;
#pragma unroll
            for (int nn = 0; nn < FN; ++nn) {
                int col = col0 + wc * WTN + nn * 16 + (lane & 15);
                float v = acc[m][nn][r];
                if (BIAS) v += bias[col];
                if (RELU) v = fmaxf(v, 0.f);
                if constexpr (SPLITOUT) {
                    unsigned short h = f2bf(v);
                    unsigned short l = f2bf(v - bf2f(h));
                    Ch[(size_t)row * M + col] = h;
                    Cl[(size_t)row * M + col] = l;
                } else {
                    Cf[(size_t)row * M + col] = v;
                }
            }
        }
    }
}

// ---------------------------------------------------------------------------
// CSR aggregation, float4-vectorized, unrolled x4; optional split-bf16 output
// ---------------------------------------------------------------------------
__device__ __forceinline__ float4 fma4(float4 v, float w, float4 a) {
    a.x = fmaf(v.x, w, a.x);
    a.y = fmaf(v.y, w, a.y);
    a.z = fmaf(v.z, w, a.z);
    a.w = fmaf(v.w, w, a.w);
    return a;
}

template <int F, int NPB, bool BIAS, bool RELU, bool SPLITOUT>
__global__ __launch_bounds__((F / 4) * NPB) void agg4(
    const float* __restrict__ h, const int* __restrict__ row_start,
    const int* __restrict__ deg_cnt, const int2* __restrict__ csr,
    const float* __restrict__ dinv, const float* __restrict__ bias,
    float* __restrict__ outf, unsigned short* __restrict__ outh,
    unsigned short* __restrict__ outl, int n) {
    constexpr int L = F / 4;
    const int local = threadIdx.x / L;
    const int lane = threadIdx.x % L;
    const int node = blockIdx.x * NPB + local;
    if (node >= n) return;

    const float4* __restrict__ h4 = (const float4*)h;
    const float di = dinv[node];

    float4 acc = h4[(size_t)node * L + lane];
    const float sw = di * di;
    acc.x *= sw; acc.y *= sw; acc.z *= sw; acc.w *= sw;

    const int beg = row_start[node];
    const int num = deg_cnt[node];
    int e = 0;
    for (; e + 4 <= num; e += 4) {
        const int2 c0 = csr[beg + e + 0];
        const int2 c1 = csr[beg + e + 1];
        const int2 c2 = csr[beg + e + 2];
        const int2 c3 = csr[beg + e + 3];
        const float4 v0 = h4[(size_t)c0.x * L + lane];
        const float4 v1 = h4[(size_t)c1.x * L + lane];
        const float4 v2 = h4[(size_t)c2.x * L + lane];
        const float4 v3 = h4[(size_t)c3.x * L + lane];
        acc = fma4(v0, __int_as_float(c0.y) * di, acc);
        acc = fma4(v1, __int_as_float(c1.y) * di, acc);
        acc = fma4(v2, __int_as_float(c2.y) * di, acc);
        acc = fma4(v3, __int_as_float(c3.y) * di, acc);
    }
    for (; e < num; ++e) {
        const int2 c = csr[beg + e];
        const float4 v = h4[(size_t)c.x * L + lane];
        acc = fma4(v, __int_as_float(c.y) * di, acc);
    }
    if (BIAS) {
        const float4 b = ((const float4*)bias)[lane];
        acc.x += b.x; acc.y += b.y; acc.z += b.z; acc.w += b.w;
    }
    if (RELU) {
        acc.x = fmaxf(acc.x, 0.f); acc.y = fmaxf(acc.y, 0.f);
        acc.z = fmaxf(acc.z, 0.f); acc.w = fmaxf(acc.w, 0.f);
    }
    if constexpr (SPLITOUT) {
        ushort4 hv, lv;
        hv.x = f2bf(acc.x); lv.x = f2bf(acc.x - bf2f(hv.x));
        hv.y = f2bf(acc.y); lv.y = f2bf(acc.y - bf2f(hv.y));
        hv.z = f2bf(acc.z); lv.z = f2bf(acc.z - bf2f(hv.z));
        hv.w = f2bf(acc.w); lv.w = f2bf(acc.w - bf2f(hv.w));
        ((ushort4*)outh)[(size_t)node * L + lane] = hv;
        ((ushort4*)outl)[(size_t)node * L + lane] = lv;
    } else {
        ((float4*)outf)[(size_t)node * L + lane] = acc;
    }
}

// ---------------------------------------------------------------------------
extern "C" void kernel_launch(void* const* d_in, const int* in_sizes, int n_in,
                              void* d_out, int out_size, void* d_ws, size_t ws_size,
                              hipStream_t stream) {
    const float* x   = (const float*)d_in[0];
    const int*   eix = (const int*)d_in[1];
    const float* W1  = (const float*)d_in[2];
    const float* b1  = (const float*)d_in[3];
    const float* W2  = (const float*)d_in[4];
    const float* b2  = (const float*)d_in[5];
    const float* W3  = (const float*)d_in[6];
    const float* b3  = (const float*)d_in[7];
    float* out = (float*)d_out;

    const int n = NN, E = NE;

    char* p = (char*)d_ws;
    auto alloc = [&](size_t bytes) { void* r = (void*)p; p += align_up(bytes, 256); return r; };
    int*   flag      = (int*)alloc(4);
    int*   deg_cnt   = (int*)alloc((size_t)n * 4);
    float* dinv      = (float*)alloc((size_t)n * 4);
    int*   row_start = (int*)alloc((size_t)n * 4);
    int*   cursor    = (int*)alloc((size_t)n * 4);
    int2*  csr       = (int2*)alloc((size_t)E * 8);
    unsigned short* w1th = (unsigned short*)alloc((size_t)128 * 256 * 2);
    unsigned short* w1tl = (unsigned short*)alloc((size_t)128 * 256 * 2);
    unsigned short* w2th = (unsigned short*)alloc((size_t)256 * 128 * 2);
    unsigned short* w2tl = (unsigned short*)alloc((size_t)256 * 128 * 2);
    unsigned short* w3th = (unsigned short*)alloc((size_t)128 * 32 * 2);
    unsigned short* w3tl = (unsigned short*)alloc((size_t)128 * 32 * 2);
    // region R1 (25.6 MB): agg0 hi/lo, later aliased by h2 (f32)
    char* R1 = (char*)alloc((size_t)n * 128 * 4);
    // region R2 (51.2 MB): h1 hi/lo, later aliased by x3 hi/lo + h3 (f32)
    char* R2 = (char*)alloc((size_t)n * 256 * 4);
    (void)ws_size; (void)in_sizes; (void)n_in; (void)out_size;

    unsigned short* agg0h = (unsigned short*)R1;
    unsigned short* agg0l = agg0h + (size_t)n * 128;
    float*          h2f   = (float*)R1;
    unsigned short* h1h   = (unsigned short*)R2;
    unsigned short* h1l   = h1h + (size_t)n * 256;
    unsigned short* x3h   = (unsigned short*)R2;
    unsigned short* x3l   = x3h + (size_t)n * 128;
    float*          h3f   = (float*)(R2 + (size_t)n * 128 * 4);  // after x3 hi/lo

    // ---- graph preprocessing ----
    hipMemsetAsync(deg_cnt, 0, (size_t)n * 4, stream);
    detect_i64<<<1, 1, 0, stream>>>(eix, flag);
    count_deg<<<(E + 255) / 256, 256, 0, stream>>>(eix, flag, deg_cnt, E);
    dinv_kernel<<<(n + 255) / 256, 256, 0, stream>>>(deg_cnt, dinv, n);
    exscan_kernel<<<1, 1024, 0, stream>>>(deg_cnt, row_start, cursor, n);
    scatter_edges<<<(E + 255) / 256, 256, 0, stream>>>(eix, flag, dinv, cursor, csr, E);

    // ---- weight prep (transpose + split) ----
    prep_weight<<<(128 * 256 + 255) / 256, 256, 0, stream>>>(W1, w1th, w1tl, 128, 256);
    prep_weight<<<(256 * 128 + 255) / 256, 256, 0, stream>>>(W2, w2th, w2tl, 256, 128);
    prep_weight<<<(128 * 32 + 255) / 256, 256, 0, stream>>>(W3, w3th, w3tl, 128, 32);

    const int RB = (n + 127) / 128;  // 391 row blocks

    // ---- layer 1: agg0 = A_norm @ x (split out); h1 = relu(agg0 @ W1 + b1) (split out)
    agg4<128, 8, false, false, true><<<(n + 7) / 8, 256, 0, stream>>>(
        x, row_start, deg_cnt, csr, dinv, nullptr, nullptr, agg0h, agg0l, n);
    gemm_mfma<128, 128, 2, 2, true, true, true><<<dim3(2, RB), 256, 0, stream>>>(
        agg0h, agg0l, w1th, w1tl, b1, nullptr, h1h, h1l, n, 128, 256);

    // ---- layer 2: h2 = h1 @ W2 (f32); x3 = relu(agg(h2) + b2) (split out)
    gemm_mfma<128, 128, 2, 2, false, false, false><<<dim3(1, RB), 256, 0, stream>>>(
        h1h, h1l, w2th, w2tl, nullptr, h2f, nullptr, nullptr, n, 256, 128);
    agg4<128, 8, true, true, true><<<(n + 7) / 8, 256, 0, stream>>>(
        h2f, row_start, deg_cnt, csr, dinv, b2, nullptr, x3h, x3l, n);

    // ---- layer 3: h3 = x3 @ W3 (f32); out = agg(h3) + b3
    gemm_mfma<128, 32, 4, 1, false, false, false><<<dim3(1, RB), 256, 0, stream>>>(
        x3h, x3l, w3th, w3tl, nullptr, h3f, nullptr, nullptr, n, 128, 32);
    agg4<32, 32, true, false, false><<<(n + 31) / 32, 256, 0, stream>>>(
        h3f, row_start, deg_cnt, csr, dinv, b3, out, nullptr, nullptr, n);
}

// Round 4
// 306.226 us; speedup vs baseline: 2.8226x; 1.2985x over previous
//
#include <hip/hip_runtime.h>

#define NN 50000
#define NE 800000
#define SCAN_BS 256

typedef __attribute__((ext_vector_type(8))) short short8v;   // 8 bf16 in 4 VGPRs
typedef __attribute__((ext_vector_type(4))) float f32x4;

static inline size_t align_up(size_t x, size_t a) { return (x + a - 1) & ~(a - 1); }

__device__ __forceinline__ unsigned short f2bf(float f) {
    unsigned u = __float_as_uint(f);
    unsigned r = u + 0x7FFF + ((u >> 16) & 1);  // round-to-nearest-even
    return (unsigned short)(r >> 16);
}
__device__ __forceinline__ float bf2f(unsigned short h) {
    return __uint_as_float(((unsigned)h) << 16);
}

// ---------------------------------------------------------------------------
// edge_index dtype probe (int64 vs int32 layout)
// ---------------------------------------------------------------------------
__global__ void detect_i64(const int* __restrict__ e, int* __restrict__ flag) {
    int ok = 1;
    for (int k = 1; k < 64; k += 2) ok &= (e[k] == 0);
    *flag = ok;
}

__device__ __forceinline__ int load_src(const int* e, int i, int is64, int E) {
    return is64 ? e[2 * i] : e[i];
}
__device__ __forceinline__ int load_dst(const int* e, int i, int is64, int E) {
    return is64 ? e[2 * (E + i)] : e[E + i];
}

__global__ void count_deg(const int* __restrict__ eidx, const int* __restrict__ flag,
                          int* __restrict__ deg, int E) {
    int i = blockIdx.x * blockDim.x + threadIdx.x;
    if (i >= E) return;
    int is64 = *flag;
    int d = load_dst(eidx, i, is64, E);
    atomicAdd(&deg[d], 1);
}

__global__ void dinv_kernel(const int* __restrict__ deg, float* __restrict__ dinv, int n) {
    int i = blockIdx.x * blockDim.x + threadIdx.x;
    if (i >= n) return;
    dinv[i] = rsqrtf((float)(deg[i] + 1));
}

// ---------------------------------------------------------------------------
// 3-phase multi-block exclusive scan (n up to SCAN_BS*SCAN_BS*...; here 196 blocks)
// ---------------------------------------------------------------------------
__global__ __launch_bounds__(SCAN_BS) void scan_phase1(const int* __restrict__ cnt,
                                                       int* __restrict__ bsum, int n) {
    __shared__ int s[SCAN_BS];
    int i = blockIdx.x * SCAN_BS + threadIdx.x;
    s[threadIdx.x] = (i < n) ? cnt[i] : 0;
    __syncthreads();
    for (int off = SCAN_BS / 2; off > 0; off >>= 1) {
        if (threadIdx.x < off) s[threadIdx.x] += s[threadIdx.x + off];
        __syncthreads();
    }
    if (threadIdx.x == 0) bsum[blockIdx.x] = s[0];
}

__global__ __launch_bounds__(SCAN_BS) void scan_phase2(int* __restrict__ bsum, int nb) {
    __shared__ int s[SCAN_BS];
    int v = (threadIdx.x < nb) ? bsum[threadIdx.x] : 0;
    s[threadIdx.x] = v;
    __syncthreads();
    for (int off = 1; off < SCAN_BS; off <<= 1) {
        int t = (threadIdx.x >= off) ? s[threadIdx.x - off] : 0;
        __syncthreads();
        s[threadIdx.x] += t;
        __syncthreads();
    }
    if (threadIdx.x < nb) bsum[threadIdx.x] = s[threadIdx.x] - v;  // exclusive
}

__global__ __launch_bounds__(SCAN_BS) void scan_phase3(const int* __restrict__ cnt,
                                                       const int* __restrict__ bsum,
                                                       int* __restrict__ row_start,
                                                       int* __restrict__ cursor, int n) {
    __shared__ int s[SCAN_BS];
    int i = blockIdx.x * SCAN_BS + threadIdx.x;
    int v = (i < n) ? cnt[i] : 0;
    s[threadIdx.x] = v;
    __syncthreads();
    for (int off = 1; off < SCAN_BS; off <<= 1) {
        int t = (threadIdx.x >= off) ? s[threadIdx.x - off] : 0;
        __syncthreads();
        s[threadIdx.x] += t;
        __syncthreads();
    }
    int exc = bsum[blockIdx.x] + s[threadIdx.x] - v;
    if (i < n) { row_start[i] = exc; cursor[i] = exc; }
}

__global__ void scatter_edges(const int* __restrict__ eidx, const int* __restrict__ flag,
                              const float* __restrict__ dinv,
                              int* __restrict__ cursor, int2* __restrict__ csr, int E) {
    int i = blockIdx.x * blockDim.x + threadIdx.x;
    if (i >= E) return;
    int is64 = *flag;
    int s = load_src(eidx, i, is64, E);
    int d = load_dst(eidx, i, is64, E);
    int pos = atomicAdd(&cursor[d], 1);
    csr[pos] = make_int2(s, __float_as_int(dinv[s]));
}

// W[K][M] f32 -> transposed split bf16 Wt_hi[M][K], Wt_lo[M][K]
__global__ void prep_weight(const float* __restrict__ W, unsigned short* __restrict__ th,
                            unsigned short* __restrict__ tl, int K, int M) {
    int i = blockIdx.x * blockDim.x + threadIdx.x;
    if (i >= K * M) return;
    int k = i / M, m = i % M;
    float v = W[i];
    unsigned short h = f2bf(v);
    unsigned short l = f2bf(v - bf2f(h));
    th[(size_t)m * K + k] = h;
    tl[(size_t)m * K + k] = l;
}

// ---------------------------------------------------------------------------
// split-bf16 MFMA GEMM: C[N,M] = (Ahi+Alo)[N,K] @ (Bhi+Blo)[K,M]
// ---------------------------------------------------------------------------
template <int BM, int BN, int WM, int WN, bool BIAS, bool RELU, bool SPLITOUT>
__global__ __launch_bounds__(256) void gemm_mfma(
    const unsigned short* __restrict__ Ah, const unsigned short* __restrict__ Al,
    const unsigned short* __restrict__ Bth, const unsigned short* __restrict__ Btl,
    const float* __restrict__ bias,
    float* __restrict__ Cf, unsigned short* __restrict__ Ch, unsigned short* __restrict__ Cl,
    int N, int K, int M) {
    constexpr int KS = 32;
    constexpr int LDA = KS + 8;  // pad to 40 halfs: 2-way LDS conflicts only
    constexpr int WTM = BM / WM;
    constexpr int WTN = BN / WN;
    constexpr int FM = WTM / 16;
    constexpr int FN = WTN / 16;
    __shared__ unsigned short sAh[BM][LDA], sAl[BM][LDA];
    __shared__ unsigned short sBh[BN][LDA], sBl[BN][LDA];

    const int tid = threadIdx.x;
    const int lane = tid & 63;
    const int w = tid >> 6;
    const int wr = w / WN, wc = w % WN;
    const int row0 = blockIdx.y * BM;
    const int col0 = blockIdx.x * BN;

    f32x4 acc[FM][FN];
#pragma unroll
    for (int m = 0; m < FM; ++m)
#pragma unroll
        for (int nn = 0; nn < FN; ++nn) {
            f32x4 z = {0.f, 0.f, 0.f, 0.f};
            acc[m][nn] = z;
        }

    for (int k0 = 0; k0 < K; k0 += KS) {
        for (int idx = tid; idx < BM * KS / 8; idx += 256) {
            int r = idx / (KS / 8);
            int s = idx % (KS / 8);
            int gr = row0 + r;
            int4 vh = make_int4(0, 0, 0, 0), vl = make_int4(0, 0, 0, 0);
            if (gr < N) {
                vh = *(const int4*)&Ah[(size_t)gr * K + k0 + s * 8];
                vl = *(const int4*)&Al[(size_t)gr * K + k0 + s * 8];
            }
            *(int4*)&sAh[r][s * 8] = vh;
            *(int4*)&sAl[r][s * 8] = vl;
        }
        for (int idx = tid; idx < BN * KS / 8; idx += 256) {
            int c = idx / (KS / 8);
            int s = idx % (KS / 8);
            int gc = col0 + c;
            *(int4*)&sBh[c][s * 8] = *(const int4*)&Bth[(size_t)gc * K + k0 + s * 8];
            *(int4*)&sBl[c][s * 8] = *(const int4*)&Btl[(size_t)gc * K + k0 + s * 8];
        }
        __syncthreads();

        short8v afh[FM], afl[FM], bfh[FN], bfl[FN];
        const int koff = (lane >> 4) * 8;
        const int rsel = lane & 15;
#pragma unroll
        for (int m = 0; m < FM; ++m) {
            afh[m] = *(const short8v*)&sAh[wr * WTM + m * 16 + rsel][koff];
            afl[m] = *(const short8v*)&sAl[wr * WTM + m * 16 + rsel][koff];
        }
#pragma unroll
        for (int nn = 0; nn < FN; ++nn) {
            bfh[nn] = *(const short8v*)&sBh[wc * WTN + nn * 16 + rsel][koff];
            bfl[nn] = *(const short8v*)&sBl[wc * WTN + nn * 16 + rsel][koff];
        }
#pragma unroll
        for (int m = 0; m < FM; ++m)
#pragma unroll
            for (int nn = 0; nn < FN; ++nn) {
                acc[m][nn] = __builtin_amdgcn_mfma_f32_16x16x32_bf16(afh[m], bfh[nn], acc[m][nn], 0, 0, 0);
                acc[m][nn] = __builtin_amdgcn_mfma_f32_16x16x32_bf16(afh[m], bfl[nn], acc[m][nn], 0, 0, 0);
                acc[m][nn] = __builtin_amdgcn_mfma_f32_16x16x32_bf16(afl[m], bfh[nn], acc[m][nn], 0, 0, 0);
            }
        __syncthreads();
    }

    // epilogue: D layout col=lane&15, row=(lane>>4)*4+reg (m89-verified)
#pragma unroll
    for (int m = 0; m < FM; ++m) {
#pragma unroll
        for (int r = 0; r < 4; ++r) {
            int row = row0 + wr * WTM + m * 16 + (lane >> 4) * 4 + r;
            if (row >= N) continue;
#pragma unroll
            for (int nn = 0; nn < FN; ++nn) {
                int col = col0 + wc * WTN + nn * 16 + (lane & 15);
                float v = acc[m][nn][r];
                if (BIAS) v += bias[col];
                if (RELU) v = fmaxf(v, 0.f);
                if constexpr (SPLITOUT) {
                    unsigned short h = f2bf(v);
                    unsigned short l = f2bf(v - bf2f(h));
                    Ch[(size_t)row * M + col] = h;
                    Cl[(size_t)row * M + col] = l;
                } else {
                    Cf[(size_t)row * M + col] = v;
                }
            }
        }
    }
}

// ---------------------------------------------------------------------------
// CSR aggregation, float4-vectorized, unrolled x4; optional split-bf16 output
// ---------------------------------------------------------------------------
__device__ __forceinline__ float4 fma4(float4 v, float w, float4 a) {
    a.x = fmaf(v.x, w, a.x);
    a.y = fmaf(v.y, w, a.y);
    a.z = fmaf(v.z, w, a.z);
    a.w = fmaf(v.w, w, a.w);
    return a;
}

template <int F, int NPB, bool BIAS, bool RELU, bool SPLITOUT>
__global__ __launch_bounds__((F / 4) * NPB) void agg4(
    const float* __restrict__ h, const int* __restrict__ row_start,
    const int* __restrict__ deg_cnt, const int2* __restrict__ csr,
    const float* __restrict__ dinv, const float* __restrict__ bias,
    float* __restrict__ outf, unsigned short* __restrict__ outh,
    unsigned short* __restrict__ outl, int n) {
    constexpr int L = F / 4;
    const int local = threadIdx.x / L;
    const int lane = threadIdx.x % L;
    const int node = blockIdx.x * NPB + local;
    if (node >= n) return;

    const float4* __restrict__ h4 = (const float4*)h;
    const float di = dinv[node];

    float4 acc = h4[(size_t)node * L + lane];
    const float sw = di * di;
    acc.x *= sw; acc.y *= sw; acc.z *= sw; acc.w *= sw;

    const int beg = row_start[node];
    const int num = deg_cnt[node];
    int e = 0;
    for (; e + 4 <= num; e += 4) {
        const int2 c0 = csr[beg + e + 0];
        const int2 c1 = csr[beg + e + 1];
        const int2 c2 = csr[beg + e + 2];
        const int2 c3 = csr[beg + e + 3];
        const float4 v0 = h4[(size_t)c0.x * L + lane];
        const float4 v1 = h4[(size_t)c1.x * L + lane];
        const float4 v2 = h4[(size_t)c2.x * L + lane];
        const float4 v3 = h4[(size_t)c3.x * L + lane];
        acc = fma4(v0, __int_as_float(c0.y) * di, acc);
        acc = fma4(v1, __int_as_float(c1.y) * di, acc);
        acc = fma4(v2, __int_as_float(c2.y) * di, acc);
        acc = fma4(v3, __int_as_float(c3.y) * di, acc);
    }
    for (; e < num; ++e) {
        const int2 c = csr[beg + e];
        const float4 v = h4[(size_t)c.x * L + lane];
        acc = fma4(v, __int_as_float(c.y) * di, acc);
    }
    if (BIAS) {
        const float4 b = ((const float4*)bias)[lane];
        acc.x += b.x; acc.y += b.y; acc.z += b.z; acc.w += b.w;
    }
    if (RELU) {
        acc.x = fmaxf(acc.x, 0.f); acc.y = fmaxf(acc.y, 0.f);
        acc.z = fmaxf(acc.z, 0.f); acc.w = fmaxf(acc.w, 0.f);
    }
    if constexpr (SPLITOUT) {
        ushort4 hv, lv;
        hv.x = f2bf(acc.x); lv.x = f2bf(acc.x - bf2f(hv.x));
        hv.y = f2bf(acc.y); lv.y = f2bf(acc.y - bf2f(hv.y));
        hv.z = f2bf(acc.z); lv.z = f2bf(acc.z - bf2f(hv.z));
        hv.w = f2bf(acc.w); lv.w = f2bf(acc.w - bf2f(hv.w));
        ((ushort4*)outh)[(size_t)node * L + lane] = hv;
        ((ushort4*)outl)[(size_t)node * L + lane] = lv;
    } else {
        ((float4*)outf)[(size_t)node * L + lane] = acc;
    }
}

// ---------------------------------------------------------------------------
extern "C" void kernel_launch(void* const* d_in, const int* in_sizes, int n_in,
                              void* d_out, int out_size, void* d_ws, size_t ws_size,
                              hipStream_t stream) {
    const float* x   = (const float*)d_in[0];
    const int*   eix = (const int*)d_in[1];
    const float* W1  = (const float*)d_in[2];
    const float* b1  = (const float*)d_in[3];
    const float* W2  = (const float*)d_in[4];
    const float* b2  = (const float*)d_in[5];
    const float* W3  = (const float*)d_in[6];
    const float* b3  = (const float*)d_in[7];
    float* out = (float*)d_out;

    const int n = NN, E = NE;
    const int nblk = (n + SCAN_BS - 1) / SCAN_BS;  // 196 <= SCAN_BS

    char* p = (char*)d_ws;
    auto alloc = [&](size_t bytes) { void* r = (void*)p; p += align_up(bytes, 256); return r; };
    int*   flag      = (int*)alloc(4);
    int*   deg_cnt   = (int*)alloc((size_t)n * 4);
    float* dinv      = (float*)alloc((size_t)n * 4);
    int*   row_start = (int*)alloc((size_t)n * 4);
    int*   cursor    = (int*)alloc((size_t)n * 4);
    int*   bsum      = (int*)alloc((size_t)nblk * 4);
    int2*  csr       = (int2*)alloc((size_t)E * 8);
    unsigned short* w1th = (unsigned short*)alloc((size_t)128 * 256 * 2);
    unsigned short* w1tl = (unsigned short*)alloc((size_t)128 * 256 * 2);
    unsigned short* w2th = (unsigned short*)alloc((size_t)256 * 128 * 2);
    unsigned short* w2tl = (unsigned short*)alloc((size_t)256 * 128 * 2);
    unsigned short* w3th = (unsigned short*)alloc((size_t)128 * 32 * 2);
    unsigned short* w3tl = (unsigned short*)alloc((size_t)128 * 32 * 2);
    // region R1 (25.6 MB): agg0 hi/lo, later aliased by h2 (f32)
    char* R1 = (char*)alloc((size_t)n * 128 * 4);
    // region R2 (51.2 MB): h1 hi/lo, later aliased by x3 hi/lo + h3 (f32)
    char* R2 = (char*)alloc((size_t)n * 256 * 4);
    (void)ws_size; (void)in_sizes; (void)n_in; (void)out_size;

    unsigned short* agg0h = (unsigned short*)R1;
    unsigned short* agg0l = agg0h + (size_t)n * 128;
    float*          h2f   = (float*)R1;
    unsigned short* h1h   = (unsigned short*)R2;
    unsigned short* h1l   = h1h + (size_t)n * 256;
    unsigned short* x3h   = (unsigned short*)R2;
    unsigned short* x3l   = x3h + (size_t)n * 128;
    float*          h3f   = (float*)(R2 + (size_t)n * 128 * 4);  // after x3 hi/lo

    // ---- graph preprocessing ----
    hipMemsetAsync(deg_cnt, 0, (size_t)n * 4, stream);
    detect_i64<<<1, 1, 0, stream>>>(eix, flag);
    count_deg<<<(E + 255) / 256, 256, 0, stream>>>(eix, flag, deg_cnt, E);
    dinv_kernel<<<(n + 255) / 256, 256, 0, stream>>>(deg_cnt, dinv, n);
    scan_phase1<<<nblk, SCAN_BS, 0, stream>>>(deg_cnt, bsum, n);
    scan_phase2<<<1, SCAN_BS, 0, stream>>>(bsum, nblk);
    scan_phase3<<<nblk, SCAN_BS, 0, stream>>>(deg_cnt, bsum, row_start, cursor, n);
    scatter_edges<<<(E + 255) / 256, 256, 0, stream>>>(eix, flag, dinv, cursor, csr, E);

    // ---- weight prep (transpose + split) ----
    prep_weight<<<(128 * 256 + 255) / 256, 256, 0, stream>>>(W1, w1th, w1tl, 128, 256);
    prep_weight<<<(256 * 128 + 255) / 256, 256, 0, stream>>>(W2, w2th, w2tl, 256, 128);
    prep_weight<<<(128 * 32 + 255) / 256, 256, 0, stream>>>(W3, w3th, w3tl, 128, 32);

    const int RB = (n + 127) / 128;  // 391 row blocks

    // ---- layer 1: agg0 = A_norm @ x (split out); h1 = relu(agg0 @ W1 + b1) (split out)
    agg4<128, 8, false, false, true><<<(n + 7) / 8, 256, 0, stream>>>(
        x, row_start, deg_cnt, csr, dinv, nullptr, nullptr, agg0h, agg0l, n);
    gemm_mfma<128, 128, 2, 2, true, true, true><<<dim3(2, RB), 256, 0, stream>>>(
        agg0h, agg0l, w1th, w1tl, b1, nullptr, h1h, h1l, n, 128, 256);

    // ---- layer 2: h2 = h1 @ W2 (f32); x3 = relu(agg(h2) + b2) (split out)
    gemm_mfma<128, 128, 2, 2, false, false, false><<<dim3(1, RB), 256, 0, stream>>>(
        h1h, h1l, w2th, w2tl, nullptr, h2f, nullptr, nullptr, n, 256, 128);
    agg4<128, 8, true, true, true><<<(n + 7) / 8, 256, 0, stream>>>(
        h2f, row_start, deg_cnt, csr, dinv, b2, nullptr, x3h, x3l, n);

    // ---- layer 3: h3 = x3 @ W3 (f32); out = agg(h3) + b3
    gemm_mfma<128, 32, 4, 1, false, false, false><<<dim3(1, RB), 256, 0, stream>>>(
        x3h, x3l, w3th, w3tl, nullptr, h3f, nullptr, nullptr, n, 128, 32);
    agg4<32, 32, true, false, false><<<(n + 31) / 32, 256, 0, stream>>>(
        h3f, row_start, deg_cnt, csr, dinv, b3, out, nullptr, nullptr, n);
}

// Round 5
// 279.193 us; speedup vs baseline: 3.0959x; 1.0968x over previous
//
#include <hip/hip_runtime.h>
#include <hip/hip_fp16.h>

#define NN 50000
#define NE 800000
#define SCAN_BS 256

typedef __attribute__((ext_vector_type(8))) short short8v;   // 8 bf16 in 4 VGPRs
typedef __attribute__((ext_vector_type(4))) float f32x4;

static inline size_t align_up(size_t x, size_t a) { return (x + a - 1) & ~(a - 1); }

__device__ __forceinline__ unsigned short f2bf(float f) {
    unsigned u = __float_as_uint(f);
    unsigned r = u + 0x7FFF + ((u >> 16) & 1);  // round-to-nearest-even
    return (unsigned short)(r >> 16);
}
__device__ __forceinline__ float bf2f(unsigned short h) {
    return __uint_as_float(((unsigned)h) << 16);
}

union U8 {
    ushort4 u;
    __half2 h[2];
};

__device__ __forceinline__ float4 u8_to_f4(ushort4 uu) {
    U8 c;
    c.u = uu;
    float2 f01 = __half22float2(c.h[0]);
    float2 f23 = __half22float2(c.h[1]);
    return make_float4(f01.x, f01.y, f23.x, f23.y);
}

// ---------------------------------------------------------------------------
// edge_index dtype probe (int64 vs int32 layout)
// ---------------------------------------------------------------------------
__global__ void detect_i64(const int* __restrict__ e, int* __restrict__ flag) {
    int ok = 1;
    for (int k = 1; k < 64; k += 2) ok &= (e[k] == 0);
    *flag = ok;
}

__device__ __forceinline__ int load_src(const int* e, int i, int is64, int E) {
    return is64 ? e[2 * i] : e[i];
}
__device__ __forceinline__ int load_dst(const int* e, int i, int is64, int E) {
    return is64 ? e[2 * (E + i)] : e[E + i];
}

__global__ void count_deg(const int* __restrict__ eidx, const int* __restrict__ flag,
                          int* __restrict__ deg, int E) {
    int i = blockIdx.x * blockDim.x + threadIdx.x;
    if (i >= E) return;
    int is64 = *flag;
    int d = load_dst(eidx, i, is64, E);
    atomicAdd(&deg[d], 1);
}

__global__ void dinv_kernel(const int* __restrict__ deg, float* __restrict__ dinv, int n) {
    int i = blockIdx.x * blockDim.x + threadIdx.x;
    if (i >= n) return;
    dinv[i] = rsqrtf((float)(deg[i] + 1));
}

// ---------------------------------------------------------------------------
// 3-phase multi-block exclusive scan
// ---------------------------------------------------------------------------
__global__ __launch_bounds__(SCAN_BS) void scan_phase1(const int* __restrict__ cnt,
                                                       int* __restrict__ bsum, int n) {
    __shared__ int s[SCAN_BS];
    int i = blockIdx.x * SCAN_BS + threadIdx.x;
    s[threadIdx.x] = (i < n) ? cnt[i] : 0;
    __syncthreads();
    for (int off = SCAN_BS / 2; off > 0; off >>= 1) {
        if (threadIdx.x < off) s[threadIdx.x] += s[threadIdx.x + off];
        __syncthreads();
    }
    if (threadIdx.x == 0) bsum[blockIdx.x] = s[0];
}

__global__ __launch_bounds__(SCAN_BS) void scan_phase2(int* __restrict__ bsum, int nb) {
    __shared__ int s[SCAN_BS];
    int v = (threadIdx.x < nb) ? bsum[threadIdx.x] : 0;
    s[threadIdx.x] = v;
    __syncthreads();
    for (int off = 1; off < SCAN_BS; off <<= 1) {
        int t = (threadIdx.x >= off) ? s[threadIdx.x - off] : 0;
        __syncthreads();
        s[threadIdx.x] += t;
        __syncthreads();
    }
    if (threadIdx.x < nb) bsum[threadIdx.x] = s[threadIdx.x] - v;  // exclusive
}

__global__ __launch_bounds__(SCAN_BS) void scan_phase3(const int* __restrict__ cnt,
                                                       const int* __restrict__ bsum,
                                                       int* __restrict__ row_start,
                                                       int* __restrict__ cursor, int n) {
    __shared__ int s[SCAN_BS];
    int i = blockIdx.x * SCAN_BS + threadIdx.x;
    int v = (i < n) ? cnt[i] : 0;
    s[threadIdx.x] = v;
    __syncthreads();
    for (int off = 1; off < SCAN_BS; off <<= 1) {
        int t = (threadIdx.x >= off) ? s[threadIdx.x - off] : 0;
        __syncthreads();
        s[threadIdx.x] += t;
        __syncthreads();
    }
    int exc = bsum[blockIdx.x] + s[threadIdx.x] - v;
    if (i < n) { row_start[i] = exc; cursor[i] = exc; }
}

__global__ void scatter_edges(const int* __restrict__ eidx, const int* __restrict__ flag,
                              const float* __restrict__ dinv,
                              int* __restrict__ cursor, int2* __restrict__ csr, int E) {
    int i = blockIdx.x * blockDim.x + threadIdx.x;
    if (i >= E) return;
    int is64 = *flag;
    int s = load_src(eidx, i, is64, E);
    int d = load_dst(eidx, i, is64, E);
    int pos = atomicAdd(&cursor[d], 1);
    csr[pos] = make_int2(s, __float_as_int(dinv[s]));
}

// W[K][M] f32 -> transposed split bf16 Wt_hi[M][K], Wt_lo[M][K]
__global__ void prep_weight(const float* __restrict__ W, unsigned short* __restrict__ th,
                            unsigned short* __restrict__ tl, int K, int M) {
    int i = blockIdx.x * blockDim.x + threadIdx.x;
    if (i >= K * M) return;
    int k = i / M, m = i % M;
    float v = W[i];
    unsigned short h = f2bf(v);
    unsigned short l = f2bf(v - bf2f(h));
    th[(size_t)m * K + k] = h;
    tl[(size_t)m * K + k] = l;
}

// f32 [total4*4] -> fp16, float4-at-a-time
__global__ void cast_f16(const float* __restrict__ in, __half* __restrict__ out, int total4) {
    int i = blockIdx.x * blockDim.x + threadIdx.x;
    if (i >= total4) return;
    float4 v = ((const float4*)in)[i];
    U8 c;
    c.h[0] = __floats2half2_rn(v.x, v.y);
    c.h[1] = __floats2half2_rn(v.z, v.w);
    ((ushort4*)out)[i] = c.u;
}

// ---------------------------------------------------------------------------
// split-bf16 MFMA GEMM: C[N,M] = (Ahi+Alo)[N,K] @ (Bhi+Blo)[K,M]
// OUTMODE: 0 = f32, 1 = split bf16 (hi/lo), 2 = fp16
// ---------------------------------------------------------------------------
template <int BM, int BN, int WM, int WN, bool BIAS, bool RELU, int OUTMODE>
__global__ __launch_bounds__(256) void gemm_mfma(
    const unsigned short* __restrict__ Ah, const unsigned short* __restrict__ Al,
    const unsigned short* __restrict__ Bth, const unsigned short* __restrict__ Btl,
    const float* __restrict__ bias,
    float* __restrict__ Cf, unsigned short* __restrict__ Ch, unsigned short* __restrict__ Cl,
    __half* __restrict__ Chf,
    int N, int K, int M) {
    constexpr int KS = 32;
    constexpr int LDA = KS + 8;  // pad to 40 halfs: 2-way LDS conflicts only
    constexpr int WTM = BM / WM;
    constexpr int WTN = BN / WN;
    constexpr int FM = WTM / 16;
    constexpr int FN = WTN / 16;
    __shared__ unsigned short sAh[BM][LDA], sAl[BM][LDA];
    __shared__ unsigned short sBh[BN][LDA], sBl[BN][LDA];

    const int tid = threadIdx.x;
    const int lane = tid & 63;
    const int w = tid >> 6;
    const int wr = w / WN, wc = w % WN;
    const int row0 = blockIdx.y * BM;
    const int col0 = blockIdx.x * BN;

    f32x4 acc[FM][FN];
#pragma unroll
    for (int m = 0; m < FM; ++m)
#pragma unroll
        for (int nn = 0; nn < FN; ++nn) {
            f32x4 z = {0.f, 0.f, 0.f, 0.f};
            acc[m][nn] = z;
        }

    for (int k0 = 0; k0 < K; k0 += KS) {
        for (int idx = tid; idx < BM * KS / 8; idx += 256) {
            int r = idx / (KS / 8);
            int s = idx % (KS / 8);
            int gr = row0 + r;
            int4 vh = make_int4(0, 0, 0, 0), vl = make_int4(0, 0, 0, 0);
            if (gr < N) {
                vh = *(const int4*)&Ah[(size_t)gr * K + k0 + s * 8];
                vl = *(const int4*)&Al[(size_t)gr * K + k0 + s * 8];
            }
            *(int4*)&sAh[r][s * 8] = vh;
            *(int4*)&sAl[r][s * 8] = vl;
        }
        for (int idx = tid; idx < BN * KS / 8; idx += 256) {
            int c = idx / (KS / 8);
            int s = idx % (KS / 8);
            int gc = col0 + c;
            *(int4*)&sBh[c][s * 8] = *(const int4*)&Bth[(size_t)gc * K + k0 + s * 8];
            *(int4*)&sBl[c][s * 8] = *(const int4*)&Btl[(size_t)gc * K + k0 + s * 8];
        }
        __syncthreads();

        short8v afh[FM], afl[FM], bfh[FN], bfl[FN];
        const int koff = (lane >> 4) * 8;
        const int rsel = lane & 15;
#pragma unroll
        for (int m = 0; m < FM; ++m) {
            afh[m] = *(const short8v*)&sAh[wr * WTM + m * 16 + rsel][koff];
            afl[m] = *(const short8v*)&sAl[wr * WTM + m * 16 + rsel][koff];
        }
#pragma unroll
        for (int nn = 0; nn < FN; ++nn) {
            bfh[nn] = *(const short8v*)&sBh[wc * WTN + nn * 16 + rsel][koff];
            bfl[nn] = *(const short8v*)&sBl[wc * WTN + nn * 16 + rsel][koff];
        }
#pragma unroll
        for (int m = 0; m < FM; ++m)
#pragma unroll
            for (int nn = 0; nn < FN; ++nn) {
                acc[m][nn] = __builtin_amdgcn_mfma_f32_16x16x32_bf16(afh[m], bfh[nn], acc[m][nn], 0, 0, 0);
                acc[m][nn] = __builtin_amdgcn_mfma_f32_16x16x32_bf16(afh[m], bfl[nn], acc[m][nn], 0, 0, 0);
                acc[m][nn] = __builtin_amdgcn_mfma_f32_16x16x32_bf16(afl[m], bfh[nn], acc[m][nn], 0, 0, 0);
            }
        __syncthreads();
    }

    // epilogue: D layout col=lane&15, row=(lane>>4)*4+reg (m89-verified)
#pragma unroll
    for (int m = 0; m < FM; ++m) {
#pragma unroll
        for (int r = 0; r < 4; ++r) {
            int row = row0 + wr * WTM + m * 16 + (lane >> 4) * 4 + r;
            if (row >= N) continue;
#pragma unroll
            for (int nn = 0; nn < FN; ++nn) {
                int col = col0 + wc * WTN + nn * 16 + (lane & 15);
                float v = acc[m][nn][r];
                if (BIAS) v += bias[col];
                if (RELU) v = fmaxf(v, 0.f);
                if constexpr (OUTMODE == 1) {
                    unsigned short h = f2bf(v);
                    unsigned short l = f2bf(v - bf2f(h));
                    Ch[(size_t)row * M + col] = h;
                    Cl[(size_t)row * M + col] = l;
                } else if constexpr (OUTMODE == 2) {
                    Chf[(size_t)row * M + col] = __float2half_rn(v);
                } else {
                    Cf[(size_t)row * M + col] = v;
                }
            }
        }
    }
}

// ---------------------------------------------------------------------------
// CSR aggregation over fp16 feature table, unrolled x8, f32 accumulate.
// OUTMODE: 0 = f32, 1 = split bf16
// ---------------------------------------------------------------------------
__device__ __forceinline__ float4 fma4(float4 v, float w, float4 a) {
    a.x = fmaf(v.x, w, a.x);
    a.y = fmaf(v.y, w, a.y);
    a.z = fmaf(v.z, w, a.z);
    a.w = fmaf(v.w, w, a.w);
    return a;
}

template <int F, int NPB, bool BIAS, bool RELU, int OUTMODE>
__global__ __launch_bounds__((F / 4) * NPB) void agg4h(
    const __half* __restrict__ h, const int* __restrict__ row_start,
    const int* __restrict__ deg_cnt, const int2* __restrict__ csr,
    const float* __restrict__ dinv, const float* __restrict__ bias,
    float* __restrict__ outf, unsigned short* __restrict__ outh,
    unsigned short* __restrict__ outl, int n) {
    constexpr int L = F / 4;
    const int local = threadIdx.x / L;
    const int lane = threadIdx.x % L;
    const int node = blockIdx.x * NPB + local;
    if (node >= n) return;

    const ushort4* __restrict__ h4 = (const ushort4*)h;
    const float di = dinv[node];

    float4 acc = u8_to_f4(h4[(size_t)node * L + lane]);
    const float sw = di * di;
    acc.x *= sw; acc.y *= sw; acc.z *= sw; acc.w *= sw;

    const int beg = row_start[node];
    const int num = deg_cnt[node];
    int e = 0;
    for (; e + 8 <= num; e += 8) {
        int2 c[8];
        float4 v[8];
#pragma unroll
        for (int u = 0; u < 8; ++u) c[u] = csr[beg + e + u];
#pragma unroll
        for (int u = 0; u < 8; ++u) v[u] = u8_to_f4(h4[(size_t)c[u].x * L + lane]);
#pragma unroll
        for (int u = 0; u < 8; ++u) acc = fma4(v[u], __int_as_float(c[u].y) * di, acc);
    }
    for (; e < num; ++e) {
        const int2 c = csr[beg + e];
        const float4 v = u8_to_f4(h4[(size_t)c.x * L + lane]);
        acc = fma4(v, __int_as_float(c.y) * di, acc);
    }
    if (BIAS) {
        const float4 b = ((const float4*)bias)[lane];
        acc.x += b.x; acc.y += b.y; acc.z += b.z; acc.w += b.w;
    }
    if (RELU) {
        acc.x = fmaxf(acc.x, 0.f); acc.y = fmaxf(acc.y, 0.f);
        acc.z = fmaxf(acc.z, 0.f); acc.w = fmaxf(acc.w, 0.f);
    }
    if constexpr (OUTMODE == 1) {
        ushort4 hv, lv;
        hv.x = f2bf(acc.x); lv.x = f2bf(acc.x - bf2f(hv.x));
        hv.y = f2bf(acc.y); lv.y = f2bf(acc.y - bf2f(hv.y));
        hv.z = f2bf(acc.z); lv.z = f2bf(acc.z - bf2f(hv.z));
        hv.w = f2bf(acc.w); lv.w = f2bf(acc.w - bf2f(hv.w));
        ((ushort4*)outh)[(size_t)node * L + lane] = hv;
        ((ushort4*)outl)[(size_t)node * L + lane] = lv;
    } else {
        ((float4*)outf)[(size_t)node * L + lane] = acc;
    }
}

// ---------------------------------------------------------------------------
extern "C" void kernel_launch(void* const* d_in, const int* in_sizes, int n_in,
                              void* d_out, int out_size, void* d_ws, size_t ws_size,
                              hipStream_t stream) {
    const float* x   = (const float*)d_in[0];
    const int*   eix = (const int*)d_in[1];
    const float* W1  = (const float*)d_in[2];
    const float* b1  = (const float*)d_in[3];
    const float* W2  = (const float*)d_in[4];
    const float* b2  = (const float*)d_in[5];
    const float* W3  = (const float*)d_in[6];
    const float* b3  = (const float*)d_in[7];
    float* out = (float*)d_out;

    const int n = NN, E = NE;
    const int nblk = (n + SCAN_BS - 1) / SCAN_BS;  // 196 <= SCAN_BS

    char* p = (char*)d_ws;
    auto alloc = [&](size_t bytes) { void* r = (void*)p; p += align_up(bytes, 256); return r; };
    int*   flag      = (int*)alloc(4);
    int*   deg_cnt   = (int*)alloc((size_t)n * 4);
    float* dinv      = (float*)alloc((size_t)n * 4);
    int*   row_start = (int*)alloc((size_t)n * 4);
    int*   cursor    = (int*)alloc((size_t)n * 4);
    int*   bsum      = (int*)alloc((size_t)nblk * 4);
    int2*  csr       = (int2*)alloc((size_t)E * 8);
    unsigned short* w1th = (unsigned short*)alloc((size_t)128 * 256 * 2);
    unsigned short* w1tl = (unsigned short*)alloc((size_t)128 * 256 * 2);
    unsigned short* w2th = (unsigned short*)alloc((size_t)256 * 128 * 2);
    unsigned short* w2tl = (unsigned short*)alloc((size_t)256 * 128 * 2);
    unsigned short* w3th = (unsigned short*)alloc((size_t)128 * 32 * 2);
    unsigned short* w3tl = (unsigned short*)alloc((size_t)128 * 32 * 2);
    // region R1 (25.6 MB): agg0 hi/lo; later aliased by h2 (fp16)
    char* R1 = (char*)alloc((size_t)n * 128 * 4);
    // region R2 (51.2 MB): xh fp16; then h1 hi/lo; then x3 hi/lo + h3 fp16
    char* R2 = (char*)alloc((size_t)n * 256 * 4);
    (void)ws_size; (void)in_sizes; (void)n_in; (void)out_size;

    unsigned short* agg0h = (unsigned short*)R1;
    unsigned short* agg0l = agg0h + (size_t)n * 128;
    __half*         h2h   = (__half*)R1;                  // after agg0 consumed by gemm1
    __half*         xh    = (__half*)R2;                  // consumed by agg1 before gemm1 writes h1
    unsigned short* h1h   = (unsigned short*)R2;
    unsigned short* h1l   = h1h + (size_t)n * 256;
    unsigned short* x3h   = (unsigned short*)R2;          // after h1 consumed by gemm2
    unsigned short* x3l   = x3h + (size_t)n * 128;
    __half*         h3h   = (__half*)(R2 + (size_t)n * 128 * 4);  // after x3 hi/lo

    // ---- graph preprocessing ----
    hipMemsetAsync(deg_cnt, 0, (size_t)n * 4, stream);
    detect_i64<<<1, 1, 0, stream>>>(eix, flag);
    count_deg<<<(E + 255) / 256, 256, 0, stream>>>(eix, flag, deg_cnt, E);
    dinv_kernel<<<(n + 255) / 256, 256, 0, stream>>>(deg_cnt, dinv, n);
    scan_phase1<<<nblk, SCAN_BS, 0, stream>>>(deg_cnt, bsum, n);
    scan_phase2<<<1, SCAN_BS, 0, stream>>>(bsum, nblk);
    scan_phase3<<<nblk, SCAN_BS, 0, stream>>>(deg_cnt, bsum, row_start, cursor, n);
    scatter_edges<<<(E + 255) / 256, 256, 0, stream>>>(eix, flag, dinv, cursor, csr, E);

    // ---- weight prep (transpose + split) ----
    prep_weight<<<(128 * 256 + 255) / 256, 256, 0, stream>>>(W1, w1th, w1tl, 128, 256);
    prep_weight<<<(256 * 128 + 255) / 256, 256, 0, stream>>>(W2, w2th, w2tl, 256, 128);
    prep_weight<<<(128 * 32 + 255) / 256, 256, 0, stream>>>(W3, w3th, w3tl, 128, 32);

    // ---- cast x -> fp16 gather table ----
    cast_f16<<<((n * 128 / 4) + 255) / 256, 256, 0, stream>>>(x, xh, n * 128 / 4);

    const int RB = (n + 127) / 128;  // 391 row blocks

    // ---- layer 1: agg0 = A_norm @ x (split bf16 out); h1 = relu(agg0 @ W1 + b1) (split bf16)
    agg4h<128, 8, false, false, 1><<<(n + 7) / 8, 256, 0, stream>>>(
        xh, row_start, deg_cnt, csr, dinv, nullptr, nullptr, agg0h, agg0l, n);
    gemm_mfma<128, 128, 2, 2, true, true, 1><<<dim3(2, RB), 256, 0, stream>>>(
        agg0h, agg0l, w1th, w1tl, b1, nullptr, h1h, h1l, nullptr, n, 128, 256);

    // ---- layer 2: h2 = h1 @ W2 (fp16 out); x3 = relu(agg(h2) + b2) (split bf16)
    gemm_mfma<128, 128, 2, 2, false, false, 2><<<dim3(1, RB), 256, 0, stream>>>(
        h1h, h1l, w2th, w2tl, nullptr, nullptr, nullptr, nullptr, h2h, n, 256, 128);
    agg4h<128, 8, true, true, 1><<<(n + 7) / 8, 256, 0, stream>>>(
        h2h, row_start, deg_cnt, csr, dinv, b2, nullptr, x3h, x3l, n);

    // ---- layer 3: h3 = x3 @ W3 (fp16 out); out = agg(h3) + b3 (f32)
    gemm_mfma<128, 32, 4, 1, false, false, 2><<<dim3(1, RB), 256, 0, stream>>>(
        x3h, x3l, w3th, w3tl, nullptr, nullptr, nullptr, nullptr, h3h, n, 128, 32);
    agg4h<32, 32, true, false, 0><<<(n + 31) / 32, 256, 0, stream>>>(
        h3h, row_start, deg_cnt, csr, dinv, b3, out, nullptr, nullptr, n);
}

// Round 6
// 277.478 us; speedup vs baseline: 3.1150x; 1.0062x over previous
//
#include <hip/hip_runtime.h>
#include <hip/hip_fp16.h>

#define NN 50000
#define NE 800000
#define SCAN_BS 256

typedef __attribute__((ext_vector_type(8))) short short8v;   // 8 bf16 in 4 VGPRs
typedef __attribute__((ext_vector_type(4))) float f32x4;

static inline size_t align_up(size_t x, size_t a) { return (x + a - 1) & ~(a - 1); }

__device__ __forceinline__ unsigned short f2bf(float f) {
    unsigned u = __float_as_uint(f);
    unsigned r = u + 0x7FFF + ((u >> 16) & 1);  // round-to-nearest-even
    return (unsigned short)(r >> 16);
}
__device__ __forceinline__ float bf2f(unsigned short h) {
    return __uint_as_float(((unsigned)h) << 16);
}

union U8 {
    ushort4 u;
    __half2 h[2];
};

__device__ __forceinline__ float4 u8_to_f4(ushort4 uu) {
    U8 c;
    c.u = uu;
    float2 f01 = __half22float2(c.h[0]);
    float2 f23 = __half22float2(c.h[1]);
    return make_float4(f01.x, f01.y, f23.x, f23.y);
}

// ---------------------------------------------------------------------------
// edge_index dtype probe (int64 vs int32 layout)
// ---------------------------------------------------------------------------
__global__ void detect_i64(const int* __restrict__ e, int* __restrict__ flag) {
    int ok = 1;
    for (int k = 1; k < 64; k += 2) ok &= (e[k] == 0);
    *flag = ok;
}

__device__ __forceinline__ int load_src(const int* e, int i, int is64, int E) {
    return is64 ? e[2 * i] : e[i];
}
__device__ __forceinline__ int load_dst(const int* e, int i, int is64, int E) {
    return is64 ? e[2 * (E + i)] : e[E + i];
}

__global__ void count_deg(const int* __restrict__ eidx, const int* __restrict__ flag,
                          int* __restrict__ deg, int E) {
    int i = blockIdx.x * blockDim.x + threadIdx.x;
    if (i >= E) return;
    int is64 = *flag;
    int d = load_dst(eidx, i, is64, E);
    atomicAdd(&deg[d], 1);
}

// ---------------------------------------------------------------------------
// 3-phase multi-block exclusive scan; phase1 also emits dinv = rsqrt(deg+1)
// ---------------------------------------------------------------------------
__global__ __launch_bounds__(SCAN_BS) void scan_phase1(const int* __restrict__ cnt,
                                                       int* __restrict__ bsum,
                                                       float* __restrict__ dinv, int n) {
    __shared__ int s[SCAN_BS];
    int i = blockIdx.x * SCAN_BS + threadIdx.x;
    int v = (i < n) ? cnt[i] : 0;
    if (i < n) dinv[i] = rsqrtf((float)(v + 1));  // +1 self-loop
    s[threadIdx.x] = v;
    __syncthreads();
    for (int off = SCAN_BS / 2; off > 0; off >>= 1) {
        if (threadIdx.x < off) s[threadIdx.x] += s[threadIdx.x + off];
        __syncthreads();
    }
    if (threadIdx.x == 0) bsum[blockIdx.x] = s[0];
}

__global__ __launch_bounds__(SCAN_BS) void scan_phase2(int* __restrict__ bsum, int nb) {
    __shared__ int s[SCAN_BS];
    int v = (threadIdx.x < nb) ? bsum[threadIdx.x] : 0;
    s[threadIdx.x] = v;
    __syncthreads();
    for (int off = 1; off < SCAN_BS; off <<= 1) {
        int t = (threadIdx.x >= off) ? s[threadIdx.x - off] : 0;
        __syncthreads();
        s[threadIdx.x] += t;
        __syncthreads();
    }
    if (threadIdx.x < nb) bsum[threadIdx.x] = s[threadIdx.x] - v;  // exclusive
}

__global__ __launch_bounds__(SCAN_BS) void scan_phase3(const int* __restrict__ cnt,
                                                       const int* __restrict__ bsum,
                                                       int* __restrict__ row_start,
                                                       int* __restrict__ cursor, int n) {
    __shared__ int s[SCAN_BS];
    int i = blockIdx.x * SCAN_BS + threadIdx.x;
    int v = (i < n) ? cnt[i] : 0;
    s[threadIdx.x] = v;
    __syncthreads();
    for (int off = 1; off < SCAN_BS; off <<= 1) {
        int t = (threadIdx.x >= off) ? s[threadIdx.x - off] : 0;
        __syncthreads();
        s[threadIdx.x] += t;
        __syncthreads();
    }
    int exc = bsum[blockIdx.x] + s[threadIdx.x] - v;
    if (i < n) { row_start[i] = exc; cursor[i] = exc; }
}

// CSR scatter: 4B src-only entries (weights are pre-folded into gather tables)
__global__ void scatter_edges(const int* __restrict__ eidx, const int* __restrict__ flag,
                              int* __restrict__ cursor, int* __restrict__ csr, int E) {
    int i = blockIdx.x * blockDim.x + threadIdx.x;
    if (i >= E) return;
    int is64 = *flag;
    int s = load_src(eidx, i, is64, E);
    int d = load_dst(eidx, i, is64, E);
    int pos = atomicAdd(&cursor[d], 1);
    csr[pos] = s;
}

// W[K][M] f32 -> transposed split bf16 Wt_hi[M][K], Wt_lo[M][K]
__global__ void prep_weight(const float* __restrict__ W, unsigned short* __restrict__ th,
                            unsigned short* __restrict__ tl, int K, int M) {
    int i = blockIdx.x * blockDim.x + threadIdx.x;
    if (i >= K * M) return;
    int k = i / M, m = i % M;
    float v = W[i];
    unsigned short h = f2bf(v);
    unsigned short l = f2bf(v - bf2f(h));
    th[(size_t)m * K + k] = h;
    tl[(size_t)m * K + k] = l;
}

// f32 [n x F] -> fp16 gather table, pre-scaled by dinv[row]; float4-at-a-time
template <int L>  // L = F/4
__global__ void cast_f16_scaled(const float* __restrict__ in, const float* __restrict__ dinv,
                                __half* __restrict__ out, int total4) {
    int i = blockIdx.x * blockDim.x + threadIdx.x;
    if (i >= total4) return;
    float4 v = ((const float4*)in)[i];
    float s = dinv[i / L];
    U8 c;
    c.h[0] = __floats2half2_rn(v.x * s, v.y * s);
    c.h[1] = __floats2half2_rn(v.z * s, v.w * s);
    ((ushort4*)out)[i] = c.u;
}

// ---------------------------------------------------------------------------
// split-bf16 MFMA GEMM: C[N,M] = (Ahi+Alo)[N,K] @ (Bhi+Blo)[K,M]
// OUTMODE: 0 = f32, 1 = split bf16 (hi/lo), 2 = fp16
// SCALE: multiply output row by dscale[row] (for pre-scaled gather tables)
// ---------------------------------------------------------------------------
template <int BM, int BN, int WM, int WN, bool BIAS, bool RELU, int OUTMODE, bool SCALE>
__global__ __launch_bounds__(256) void gemm_mfma(
    const unsigned short* __restrict__ Ah, const unsigned short* __restrict__ Al,
    const unsigned short* __restrict__ Bth, const unsigned short* __restrict__ Btl,
    const float* __restrict__ bias, const float* __restrict__ dscale,
    float* __restrict__ Cf, unsigned short* __restrict__ Ch, unsigned short* __restrict__ Cl,
    __half* __restrict__ Chf,
    int N, int K, int M) {
    constexpr int KS = 32;
    constexpr int LDA = KS + 8;  // pad to 40 halfs: 2-way LDS conflicts only
    constexpr int WTM = BM / WM;
    constexpr int WTN = BN / WN;
    constexpr int FM = WTM / 16;
    constexpr int FN = WTN / 16;
    __shared__ unsigned short sAh[BM][LDA], sAl[BM][LDA];
    __shared__ unsigned short sBh[BN][LDA], sBl[BN][LDA];

    const int tid = threadIdx.x;
    const int lane = tid & 63;
    const int w = tid >> 6;
    const int wr = w / WN, wc = w % WN;
    const int row0 = blockIdx.y * BM;
    const int col0 = blockIdx.x * BN;

    f32x4 acc[FM][FN];
#pragma unroll
    for (int m = 0; m < FM; ++m)
#pragma unroll
        for (int nn = 0; nn < FN; ++nn) {
            f32x4 z = {0.f, 0.f, 0.f, 0.f};
            acc[m][nn] = z;
        }

    for (int k0 = 0; k0 < K; k0 += KS) {
        for (int idx = tid; idx < BM * KS / 8; idx += 256) {
            int r = idx / (KS / 8);
            int s = idx % (KS / 8);
            int gr = row0 + r;
            int4 vh = make_int4(0, 0, 0, 0), vl = make_int4(0, 0, 0, 0);
            if (gr < N) {
                vh = *(const int4*)&Ah[(size_t)gr * K + k0 + s * 8];
                vl = *(const int4*)&Al[(size_t)gr * K + k0 + s * 8];
            }
            *(int4*)&sAh[r][s * 8] = vh;
            *(int4*)&sAl[r][s * 8] = vl;
        }
        for (int idx = tid; idx < BN * KS / 8; idx += 256) {
            int c = idx / (KS / 8);
            int s = idx % (KS / 8);
            int gc = col0 + c;
            *(int4*)&sBh[c][s * 8] = *(const int4*)&Bth[(size_t)gc * K + k0 + s * 8];
            *(int4*)&sBl[c][s * 8] = *(const int4*)&Btl[(size_t)gc * K + k0 + s * 8];
        }
        __syncthreads();

        short8v afh[FM], afl[FM], bfh[FN], bfl[FN];
        const int koff = (lane >> 4) * 8;
        const int rsel = lane & 15;
#pragma unroll
        for (int m = 0; m < FM; ++m) {
            afh[m] = *(const short8v*)&sAh[wr * WTM + m * 16 + rsel][koff];
            afl[m] = *(const short8v*)&sAl[wr * WTM + m * 16 + rsel][koff];
        }
#pragma unroll
        for (int nn = 0; nn < FN; ++nn) {
            bfh[nn] = *(const short8v*)&sBh[wc * WTN + nn * 16 + rsel][koff];
            bfl[nn] = *(const short8v*)&sBl[wc * WTN + nn * 16 + rsel][koff];
        }
#pragma unroll
        for (int m = 0; m < FM; ++m)
#pragma unroll
            for (int nn = 0; nn < FN; ++nn) {
                acc[m][nn] = __builtin_amdgcn_mfma_f32_16x16x32_bf16(afh[m], bfh[nn], acc[m][nn], 0, 0, 0);
                acc[m][nn] = __builtin_amdgcn_mfma_f32_16x16x32_bf16(afh[m], bfl[nn], acc[m][nn], 0, 0, 0);
                acc[m][nn] = __builtin_amdgcn_mfma_f32_16x16x32_bf16(afl[m], bfh[nn], acc[m][nn], 0, 0, 0);
            }
        __syncthreads();
    }

    // epilogue: D layout col=lane&15, row=(lane>>4)*4+reg (m89-verified)
#pragma unroll
    for (int m = 0; m < FM; ++m) {
#pragma unroll
        for (int r = 0; r < 4; ++r) {
            int row = row0 + wr * WTM + m * 16 + (lane >> 4) * 4 + r;
            if (row >= N) continue;
            float rs = SCALE ? dscale[row] : 1.f;
#pragma unroll
            for (int nn = 0; nn < FN; ++nn) {
                int col = col0 + wc * WTN + nn * 16 + (lane & 15);
                float v = acc[m][nn][r];
                if (BIAS) v += bias[col];
                if (RELU) v = fmaxf(v, 0.f);
                if (SCALE) v *= rs;
                if constexpr (OUTMODE == 1) {
                    unsigned short h = f2bf(v);
                    unsigned short l = f2bf(v - bf2f(h));
                    Ch[(size_t)row * M + col] = h;
                    Cl[(size_t)row * M + col] = l;
                } else if constexpr (OUTMODE == 2) {
                    Chf[(size_t)row * M + col] = __float2half_rn(v);
                } else {
                    Cf[(size_t)row * M + col] = v;
                }
            }
        }
    }
}

// ---------------------------------------------------------------------------
// CSR aggregation over PRE-SCALED fp16 table h' = dinv ⊙ h:
// out[d] = dinv[d] * (h'[d] + Σ_{s∈N(d)} h'[s]) + bias ; unrolled x8
// OUTMODE: 0 = f32, 1 = split bf16
// ---------------------------------------------------------------------------
__device__ __forceinline__ float4 add4(float4 v, float4 a) {
    a.x += v.x; a.y += v.y; a.z += v.z; a.w += v.w;
    return a;
}

template <int F, int NPB, bool BIAS, bool RELU, int OUTMODE>
__global__ __launch_bounds__((F / 4) * NPB) void agg4h(
    const __half* __restrict__ h, const int* __restrict__ row_start,
    const int* __restrict__ deg_cnt, const int* __restrict__ csr,
    const float* __restrict__ dinv, const float* __restrict__ bias,
    float* __restrict__ outf, unsigned short* __restrict__ outh,
    unsigned short* __restrict__ outl, int n) {
    constexpr int L = F / 4;
    const int local = threadIdx.x / L;
    const int lane = threadIdx.x % L;
    const int node = blockIdx.x * NPB + local;
    if (node >= n) return;

    const ushort4* __restrict__ h4 = (const ushort4*)h;
    const float di = dinv[node];

    float4 acc = u8_to_f4(h4[(size_t)node * L + lane]);  // self term h'[d]

    const int beg = row_start[node];
    const int num = deg_cnt[node];
    int e = 0;
    for (; e + 8 <= num; e += 8) {
        int c[8];
        float4 v[8];
#pragma unroll
        for (int u = 0; u < 8; ++u) c[u] = csr[beg + e + u];
#pragma unroll
        for (int u = 0; u < 8; ++u) v[u] = u8_to_f4(h4[(size_t)c[u] * L + lane]);
#pragma unroll
        for (int u = 0; u < 8; ++u) acc = add4(v[u], acc);
    }
    for (; e < num; ++e) {
        const int c = csr[beg + e];
        acc = add4(u8_to_f4(h4[(size_t)c * L + lane]), acc);
    }
    acc.x *= di; acc.y *= di; acc.z *= di; acc.w *= di;
    if (BIAS) {
        const float4 b = ((const float4*)bias)[lane];
        acc.x += b.x; acc.y += b.y; acc.z += b.z; acc.w += b.w;
    }
    if (RELU) {
        acc.x = fmaxf(acc.x, 0.f); acc.y = fmaxf(acc.y, 0.f);
        acc.z = fmaxf(acc.z, 0.f); acc.w = fmaxf(acc.w, 0.f);
    }
    if constexpr (OUTMODE == 1) {
        ushort4 hv, lv;
        hv.x = f2bf(acc.x); lv.x = f2bf(acc.x - bf2f(hv.x));
        hv.y = f2bf(acc.y); lv.y = f2bf(acc.y - bf2f(hv.y));
        hv.z = f2bf(acc.z); lv.z = f2bf(acc.z - bf2f(hv.z));
        hv.w = f2bf(acc.w); lv.w = f2bf(acc.w - bf2f(hv.w));
        ((ushort4*)outh)[(size_t)node * L + lane] = hv;
        ((ushort4*)outl)[(size_t)node * L + lane] = lv;
    } else {
        ((float4*)outf)[(size_t)node * L + lane] = acc;
    }
}

// ---------------------------------------------------------------------------
extern "C" void kernel_launch(void* const* d_in, const int* in_sizes, int n_in,
                              void* d_out, int out_size, void* d_ws, size_t ws_size,
                              hipStream_t stream) {
    const float* x   = (const float*)d_in[0];
    const int*   eix = (const int*)d_in[1];
    const float* W1  = (const float*)d_in[2];
    const float* b1  = (const float*)d_in[3];
    const float* W2  = (const float*)d_in[4];
    const float* b2  = (const float*)d_in[5];
    const float* W3  = (const float*)d_in[6];
    const float* b3  = (const float*)d_in[7];
    float* out = (float*)d_out;

    const int n = NN, E = NE;
    const int nblk = (n + SCAN_BS - 1) / SCAN_BS;  // 196 <= SCAN_BS

    char* p = (char*)d_ws;
    auto alloc = [&](size_t bytes) { void* r = (void*)p; p += align_up(bytes, 256); return r; };
    int*   flag      = (int*)alloc(4);
    int*   deg_cnt   = (int*)alloc((size_t)n * 4);
    float* dinv      = (float*)alloc((size_t)n * 4);
    int*   row_start = (int*)alloc((size_t)n * 4);
    int*   cursor    = (int*)alloc((size_t)n * 4);
    int*   bsum      = (int*)alloc((size_t)nblk * 4);
    int*   csr       = (int*)alloc((size_t)E * 4);
    unsigned short* w1th = (unsigned short*)alloc((size_t)128 * 256 * 2);
    unsigned short* w1tl = (unsigned short*)alloc((size_t)128 * 256 * 2);
    unsigned short* w2th = (unsigned short*)alloc((size_t)256 * 128 * 2);
    unsigned short* w2tl = (unsigned short*)alloc((size_t)256 * 128 * 2);
    unsigned short* w3th = (unsigned short*)alloc((size_t)128 * 32 * 2);
    unsigned short* w3tl = (unsigned short*)alloc((size_t)128 * 32 * 2);
    // region R1 (25.6 MB): agg0 hi/lo; later aliased by h2' (fp16, scaled)
    char* R1 = (char*)alloc((size_t)n * 128 * 4);
    // region R2 (51.2 MB): x' fp16; then h1 hi/lo; then x3 hi/lo + h3' fp16
    char* R2 = (char*)alloc((size_t)n * 256 * 4);
    (void)ws_size; (void)in_sizes; (void)n_in; (void)out_size;

    unsigned short* agg0h = (unsigned short*)R1;
    unsigned short* agg0l = agg0h + (size_t)n * 128;
    __half*         h2h   = (__half*)R1;                  // after agg0 consumed by gemm1
    __half*         xh    = (__half*)R2;                  // consumed by agg1 before gemm1 writes h1
    unsigned short* h1h   = (unsigned short*)R2;
    unsigned short* h1l   = h1h + (size_t)n * 256;
    unsigned short* x3h   = (unsigned short*)R2;          // after h1 consumed by gemm2
    unsigned short* x3l   = x3h + (size_t)n * 128;
    __half*         h3h   = (__half*)(R2 + (size_t)n * 128 * 4);  // after x3 hi/lo

    // ---- graph preprocessing ----
    hipMemsetAsync(deg_cnt, 0, (size_t)n * 4, stream);
    detect_i64<<<1, 1, 0, stream>>>(eix, flag);
    count_deg<<<(E + 255) / 256, 256, 0, stream>>>(eix, flag, deg_cnt, E);
    scan_phase1<<<nblk, SCAN_BS, 0, stream>>>(deg_cnt, bsum, dinv, n);
    scan_phase2<<<1, SCAN_BS, 0, stream>>>(bsum, nblk);
    scan_phase3<<<nblk, SCAN_BS, 0, stream>>>(deg_cnt, bsum, row_start, cursor, n);
    scatter_edges<<<(E + 255) / 256, 256, 0, stream>>>(eix, flag, cursor, csr, E);

    // ---- weight prep (transpose + split) ----
    prep_weight<<<(128 * 256 + 255) / 256, 256, 0, stream>>>(W1, w1th, w1tl, 128, 256);
    prep_weight<<<(256 * 128 + 255) / 256, 256, 0, stream>>>(W2, w2th, w2tl, 256, 128);
    prep_weight<<<(128 * 32 + 255) / 256, 256, 0, stream>>>(W3, w3th, w3tl, 128, 32);

    // ---- cast x -> pre-scaled fp16 gather table x' = dinv ⊙ x ----
    cast_f16_scaled<32><<<((n * 128 / 4) + 255) / 256, 256, 0, stream>>>(
        x, dinv, xh, n * 128 / 4);

    const int RB = (n + 127) / 128;  // 391 row blocks

    // ---- layer 1: agg0 = A_norm @ x (split bf16); h1 = relu(agg0 @ W1 + b1) (split bf16)
    agg4h<128, 8, false, false, 1><<<(n + 7) / 8, 256, 0, stream>>>(
        xh, row_start, deg_cnt, csr, dinv, nullptr, nullptr, agg0h, agg0l, n);
    gemm_mfma<128, 128, 2, 2, true, true, 1, false><<<dim3(2, RB), 256, 0, stream>>>(
        agg0h, agg0l, w1th, w1tl, b1, nullptr, nullptr, h1h, h1l, nullptr, n, 128, 256);

    // ---- layer 2: h2' = dinv ⊙ (h1 @ W2) (fp16); x3 = relu(agg + b2) (split bf16)
    gemm_mfma<128, 128, 2, 2, false, false, 2, true><<<dim3(1, RB), 256, 0, stream>>>(
        h1h, h1l, w2th, w2tl, nullptr, dinv, nullptr, nullptr, nullptr, h2h, n, 256, 128);
    agg4h<128, 8, true, true, 1><<<(n + 7) / 8, 256, 0, stream>>>(
        h2h, row_start, deg_cnt, csr, dinv, b2, nullptr, x3h, x3l, n);

    // ---- layer 3: h3' = dinv ⊙ (x3 @ W3) (fp16); out = agg + b3 (f32)
    gemm_mfma<128, 32, 4, 1, false, false, 2, true><<<dim3(1, RB), 256, 0, stream>>>(
        x3h, x3l, w3th, w3tl, nullptr, dinv, nullptr, nullptr, nullptr, h3h, n, 128, 32);
    agg4h<32, 32, true, false, 0><<<(n + 31) / 32, 256, 0, stream>>>(
        h3h, row_start, deg_cnt, csr, dinv, b3, out, nullptr, nullptr, n);
}

// Round 7
// 206.516 us; speedup vs baseline: 4.1854x; 1.3436x over previous
//
#include <hip/hip_runtime.h>
#include <hip/hip_fp16.h>

#define NN 50000
#define NE 800000
#define NBKT 391          // ceil(50000/128) buckets of 128 nodes
#define P1B 128           // blocks in hist/scatter passes

typedef __attribute__((ext_vector_type(8))) short short8v;   // 8 bf16 in 4 VGPRs
typedef __attribute__((ext_vector_type(4))) float f32x4;

static inline size_t align_up(size_t x, size_t a) { return (x + a - 1) & ~(a - 1); }

__device__ __forceinline__ unsigned short f2bf(float f) {
    unsigned u = __float_as_uint(f);
    unsigned r = u + 0x7FFF + ((u >> 16) & 1);  // round-to-nearest-even
    return (unsigned short)(r >> 16);
}
__device__ __forceinline__ float bf2f(unsigned short h) {
    return __uint_as_float(((unsigned)h) << 16);
}

union U8 {
    ushort4 u;
    __half2 h[2];
};

__device__ __forceinline__ float4 u8_to_f4(ushort4 uu) {
    U8 c;
    c.u = uu;
    float2 f01 = __half22float2(c.h[0]);
    float2 f23 = __half22float2(c.h[1]);
    return make_float4(f01.x, f01.y, f23.x, f23.y);
}

// int64-vs-int32 edge layout probe, per-block (values < 2^31 => odd words zero)
__device__ __forceinline__ int detect64(const int* __restrict__ e) {
    int ok = 1;
    for (int k = 1; k < 64; k += 2) ok &= (e[k] == 0);
    return ok;
}

// ---------------------------------------------------------------------------
// P1: per-block bucket histogram; reserve per-(block,bucket) chunk in gcount
// ---------------------------------------------------------------------------
__global__ __launch_bounds__(256) void bucket_hist(const int* __restrict__ e,
                                                   int* __restrict__ gcount,
                                                   int* __restrict__ base, int E) {
    __shared__ int hist[NBKT];
    const int is64 = detect64(e);
    for (int t = threadIdx.x; t < NBKT; t += 256) hist[t] = 0;
    __syncthreads();
    const int chunk = (E + P1B - 1) / P1B;
    const int b0 = blockIdx.x * chunk;
    const int b1 = min(E, b0 + chunk);
    for (int i = b0 + threadIdx.x; i < b1; i += 256) {
        int d = is64 ? e[2 * (E + i)] : e[E + i];
        atomicAdd(&hist[d >> 7], 1);
    }
    __syncthreads();
    for (int t = threadIdx.x; t < NBKT; t += 256)
        base[blockIdx.x * NBKT + t] = atomicAdd(&gcount[t], hist[t]);
}

// ---------------------------------------------------------------------------
// P2: exclusive scan of bucket counts -> bucket_start[0..NBKT]
// ---------------------------------------------------------------------------
__global__ __launch_bounds__(512) void bucket_scan(const int* __restrict__ gcount,
                                                   int* __restrict__ bstart, int nb) {
    __shared__ int s[512];
    const int t = threadIdx.x;
    int v = (t < nb) ? gcount[t] : 0;
    s[t] = v;
    __syncthreads();
    for (int off = 1; off < 512; off <<= 1) {
        int tv = (t >= off) ? s[t - off] : 0;
        __syncthreads();
        s[t] += tv;
        __syncthreads();
    }
    if (t < nb) bstart[t] = s[t] - v;
    if (t == 0) bstart[nb] = s[511];  // total = E
}

// ---------------------------------------------------------------------------
// P3: scatter (src,dst) pairs into bucket-binned order; per-(block,bucket)
// chunks are contiguous -> line-friendly writes
// ---------------------------------------------------------------------------
__global__ __launch_bounds__(256) void bucket_scatter(const int* __restrict__ e,
                                                      const int* __restrict__ bstart,
                                                      const int* __restrict__ base,
                                                      int2* __restrict__ pairs, int E) {
    __shared__ int cur[NBKT];
    const int is64 = detect64(e);
    for (int t = threadIdx.x; t < NBKT; t += 256)
        cur[t] = bstart[t] + base[blockIdx.x * NBKT + t];
    __syncthreads();
    const int chunk = (E + P1B - 1) / P1B;
    const int b0 = blockIdx.x * chunk;
    const int b1 = min(E, b0 + chunk);
    for (int i = b0 + threadIdx.x; i < b1; i += 256) {
        int s = is64 ? e[2 * i] : e[i];
        int d = is64 ? e[2 * (E + i)] : e[E + i];
        int pos = atomicAdd(&cur[d >> 7], 1);
        pairs[pos] = make_int2(s, d);
    }
}

// ---------------------------------------------------------------------------
// P4: one block per bucket. Stream pairs twice: (1) local deg count + scan,
// write deg/row_start/dinv; (2) LDS-cursor scatter src -> contiguous CSR range.
// ---------------------------------------------------------------------------
__global__ __launch_bounds__(256) void bucket_finalize(const int2* __restrict__ pairs,
                                                       const int* __restrict__ bstart,
                                                       int* __restrict__ row_start,
                                                       int* __restrict__ deg_cnt,
                                                       float* __restrict__ dinv,
                                                       int* __restrict__ csr, int n) {
    __shared__ int ldeg[128];
    __shared__ int lscan[128];
    __shared__ int cur[128];
    const int bkt = blockIdx.x;
    const int s0 = bstart[bkt], s1 = bstart[bkt + 1];
    if (threadIdx.x < 128) ldeg[threadIdx.x] = 0;
    __syncthreads();
    for (int i = s0 + threadIdx.x; i < s1; i += 256)
        atomicAdd(&ldeg[pairs[i].y & 127], 1);
    __syncthreads();
    if (threadIdx.x < 128) lscan[threadIdx.x] = ldeg[threadIdx.x];
    __syncthreads();
    for (int off = 1; off < 128; off <<= 1) {
        int v = 0;
        if (threadIdx.x < 128 && threadIdx.x >= off) v = lscan[threadIdx.x - off];
        __syncthreads();
        if (threadIdx.x < 128) lscan[threadIdx.x] += v;
        __syncthreads();
    }
    if (threadIdx.x < 128) {
        int node = (bkt << 7) + threadIdx.x;
        int exc = s0 + lscan[threadIdx.x] - ldeg[threadIdx.x];
        cur[threadIdx.x] = exc;
        if (node < n) {
            row_start[node] = exc;
            deg_cnt[node] = ldeg[threadIdx.x];
            dinv[node] = rsqrtf((float)(ldeg[threadIdx.x] + 1));  // +1 self-loop
        }
    }
    __syncthreads();
    for (int i = s0 + threadIdx.x; i < s1; i += 256) {
        int2 pr = pairs[i];
        int pos = atomicAdd(&cur[pr.y & 127], 1);
        csr[pos] = pr.x;
    }
}

// ---------------------------------------------------------------------------
// all weights: f32 [K][M] -> transposed split bf16 [M][K] hi/lo (one launch)
// ---------------------------------------------------------------------------
__global__ void prep_weights_all(const float* __restrict__ W1, const float* __restrict__ W2,
                                 const float* __restrict__ W3,
                                 unsigned short* __restrict__ w1th, unsigned short* __restrict__ w1tl,
                                 unsigned short* __restrict__ w2th, unsigned short* __restrict__ w2tl,
                                 unsigned short* __restrict__ w3th, unsigned short* __restrict__ w3tl) {
    int i = blockIdx.x * blockDim.x + threadIdx.x;
    const float* W;
    unsigned short *th, *tl;
    int K, M, j;
    if (i < 32768)      { W = W1; th = w1th; tl = w1tl; K = 128; M = 256; j = i; }
    else if (i < 65536) { W = W2; th = w2th; tl = w2tl; K = 256; M = 128; j = i - 32768; }
    else if (i < 69632) { W = W3; th = w3th; tl = w3tl; K = 128; M = 32;  j = i - 65536; }
    else return;
    int k = j / M, m = j % M;
    float v = W[j];
    unsigned short h = f2bf(v);
    unsigned short l = f2bf(v - bf2f(h));
    th[(size_t)m * K + k] = h;
    tl[(size_t)m * K + k] = l;
}

// f32 [n x F] -> fp16 gather table, pre-scaled by dinv[row]; float4-at-a-time
template <int L>  // L = F/4
__global__ void cast_f16_scaled(const float* __restrict__ in, const float* __restrict__ dinv,
                                __half* __restrict__ out, int total4) {
    int i = blockIdx.x * blockDim.x + threadIdx.x;
    if (i >= total4) return;
    float4 v = ((const float4*)in)[i];
    float s = dinv[i / L];
    U8 c;
    c.h[0] = __floats2half2_rn(v.x * s, v.y * s);
    c.h[1] = __floats2half2_rn(v.z * s, v.w * s);
    ((ushort4*)out)[i] = c.u;
}

// ---------------------------------------------------------------------------
// split-bf16 MFMA GEMM: C[N,M] = (Ahi+Alo)[N,K] @ (Bhi+Blo)[K,M]
// OUTMODE: 0 = f32, 1 = split bf16 (hi/lo), 2 = fp16
// SCALE: multiply output row by dscale[row] (for pre-scaled gather tables)
// ---------------------------------------------------------------------------
template <int BM, int BN, int WM, int WN, bool BIAS, bool RELU, int OUTMODE, bool SCALE>
__global__ __launch_bounds__(256) void gemm_mfma(
    const unsigned short* __restrict__ Ah, const unsigned short* __restrict__ Al,
    const unsigned short* __restrict__ Bth, const unsigned short* __restrict__ Btl,
    const float* __restrict__ bias, const float* __restrict__ dscale,
    float* __restrict__ Cf, unsigned short* __restrict__ Ch, unsigned short* __restrict__ Cl,
    __half* __restrict__ Chf,
    int N, int K, int M) {
    constexpr int KS = 32;
    constexpr int LDA = KS + 8;  // pad to 40 halfs: 2-way LDS conflicts only
    constexpr int WTM = BM / WM;
    constexpr int WTN = BN / WN;
    constexpr int FM = WTM / 16;
    constexpr int FN = WTN / 16;
    __shared__ unsigned short sAh[BM][LDA], sAl[BM][LDA];
    __shared__ unsigned short sBh[BN][LDA], sBl[BN][LDA];

    const int tid = threadIdx.x;
    const int lane = tid & 63;
    const int w = tid >> 6;
    const int wr = w / WN, wc = w % WN;
    const int row0 = blockIdx.y * BM;
    const int col0 = blockIdx.x * BN;

    f32x4 acc[FM][FN];
#pragma unroll
    for (int m = 0; m < FM; ++m)
#pragma unroll
        for (int nn = 0; nn < FN; ++nn) {
            f32x4 z = {0.f, 0.f, 0.f, 0.f};
            acc[m][nn] = z;
        }

    for (int k0 = 0; k0 < K; k0 += KS) {
        for (int idx = tid; idx < BM * KS / 8; idx += 256) {
            int r = idx / (KS / 8);
            int s = idx % (KS / 8);
            int gr = row0 + r;
            int4 vh = make_int4(0, 0, 0, 0), vl = make_int4(0, 0, 0, 0);
            if (gr < N) {
                vh = *(const int4*)&Ah[(size_t)gr * K + k0 + s * 8];
                vl = *(const int4*)&Al[(size_t)gr * K + k0 + s * 8];
            }
            *(int4*)&sAh[r][s * 8] = vh;
            *(int4*)&sAl[r][s * 8] = vl;
        }
        for (int idx = tid; idx < BN * KS / 8; idx += 256) {
            int c = idx / (KS / 8);
            int s = idx % (KS / 8);
            int gc = col0 + c;
            *(int4*)&sBh[c][s * 8] = *(const int4*)&Bth[(size_t)gc * K + k0 + s * 8];
            *(int4*)&sBl[c][s * 8] = *(const int4*)&Btl[(size_t)gc * K + k0 + s * 8];
        }
        __syncthreads();

        short8v afh[FM], afl[FM], bfh[FN], bfl[FN];
        const int koff = (lane >> 4) * 8;
        const int rsel = lane & 15;
#pragma unroll
        for (int m = 0; m < FM; ++m) {
            afh[m] = *(const short8v*)&sAh[wr * WTM + m * 16 + rsel][koff];
            afl[m] = *(const short8v*)&sAl[wr * WTM + m * 16 + rsel][koff];
        }
#pragma unroll
        for (int nn = 0; nn < FN; ++nn) {
            bfh[nn] = *(const short8v*)&sBh[wc * WTN + nn * 16 + rsel][koff];
            bfl[nn] = *(const short8v*)&sBl[wc * WTN + nn * 16 + rsel][koff];
        }
#pragma unroll
        for (int m = 0; m < FM; ++m)
#pragma unroll
            for (int nn = 0; nn < FN; ++nn) {
                acc[m][nn] = __builtin_amdgcn_mfma_f32_16x16x32_bf16(afh[m], bfh[nn], acc[m][nn], 0, 0, 0);
                acc[m][nn] = __builtin_amdgcn_mfma_f32_16x16x32_bf16(afh[m], bfl[nn], acc[m][nn], 0, 0, 0);
                acc[m][nn] = __builtin_amdgcn_mfma_f32_16x16x32_bf16(afl[m], bfh[nn], acc[m][nn], 0, 0, 0);
            }
        __syncthreads();
    }

    // epilogue: D layout col=lane&15, row=(lane>>4)*4+reg (m89-verified)
#pragma unroll
    for (int m = 0; m < FM; ++m) {
#pragma unroll
        for (int r = 0; r < 4; ++r) {
            int row = row0 + wr * WTM + m * 16 + (lane >> 4) * 4 + r;
            if (row >= N) continue;
            float rs = SCALE ? dscale[row] : 1.f;
#pragma unroll
            for (int nn = 0; nn < FN; ++nn) {
                int col = col0 + wc * WTN + nn * 16 + (lane & 15);
                float v = acc[m][nn][r];
                if (BIAS) v += bias[col];
                if (RELU) v = fmaxf(v, 0.f);
                if (SCALE) v *= rs;
                if constexpr (OUTMODE == 1) {
                    unsigned short h = f2bf(v);
                    unsigned short l = f2bf(v - bf2f(h));
                    Ch[(size_t)row * M + col] = h;
                    Cl[(size_t)row * M + col] = l;
                } else if constexpr (OUTMODE == 2) {
                    Chf[(size_t)row * M + col] = __float2half_rn(v);
                } else {
                    Cf[(size_t)row * M + col] = v;
                }
            }
        }
    }
}

// ---------------------------------------------------------------------------
// CSR aggregation over PRE-SCALED fp16 table h' = dinv ⊙ h:
// out[d] = dinv[d] * (h'[d] + Σ_{s∈N(d)} h'[s]) + bias ; unrolled x8
// OUTMODE: 0 = f32, 1 = split bf16
// ---------------------------------------------------------------------------
__device__ __forceinline__ float4 add4(float4 v, float4 a) {
    a.x += v.x; a.y += v.y; a.z += v.z; a.w += v.w;
    return a;
}

template <int F, int NPB, bool BIAS, bool RELU, int OUTMODE>
__global__ __launch_bounds__((F / 4) * NPB) void agg4h(
    const __half* __restrict__ h, const int* __restrict__ row_start,
    const int* __restrict__ deg_cnt, const int* __restrict__ csr,
    const float* __restrict__ dinv, const float* __restrict__ bias,
    float* __restrict__ outf, unsigned short* __restrict__ outh,
    unsigned short* __restrict__ outl, int n) {
    constexpr int L = F / 4;
    const int local = threadIdx.x / L;
    const int lane = threadIdx.x % L;
    const int node = blockIdx.x * NPB + local;
    if (node >= n) return;

    const ushort4* __restrict__ h4 = (const ushort4*)h;
    const float di = dinv[node];

    float4 acc = u8_to_f4(h4[(size_t)node * L + lane]);  // self term h'[d]

    const int beg = row_start[node];
    const int num = deg_cnt[node];
    int e = 0;
    for (; e + 8 <= num; e += 8) {
        int c[8];
        float4 v[8];
#pragma unroll
        for (int u = 0; u < 8; ++u) c[u] = csr[beg + e + u];
#pragma unroll
        for (int u = 0; u < 8; ++u) v[u] = u8_to_f4(h4[(size_t)c[u] * L + lane]);
#pragma unroll
        for (int u = 0; u < 8; ++u) acc = add4(v[u], acc);
    }
    for (; e < num; ++e) {
        const int c = csr[beg + e];
        acc = add4(u8_to_f4(h4[(size_t)c * L + lane]), acc);
    }
    acc.x *= di; acc.y *= di; acc.z *= di; acc.w *= di;
    if (BIAS) {
        const float4 b = ((const float4*)bias)[lane];
        acc.x += b.x; acc.y += b.y; acc.z += b.z; acc.w += b.w;
    }
    if (RELU) {
        acc.x = fmaxf(acc.x, 0.f); acc.y = fmaxf(acc.y, 0.f);
        acc.z = fmaxf(acc.z, 0.f); acc.w = fmaxf(acc.w, 0.f);
    }
    if constexpr (OUTMODE == 1) {
        ushort4 hv, lv;
        hv.x = f2bf(acc.x); lv.x = f2bf(acc.x - bf2f(hv.x));
        hv.y = f2bf(acc.y); lv.y = f2bf(acc.y - bf2f(hv.y));
        hv.z = f2bf(acc.z); lv.z = f2bf(acc.z - bf2f(hv.z));
        hv.w = f2bf(acc.w); lv.w = f2bf(acc.w - bf2f(hv.w));
        ((ushort4*)outh)[(size_t)node * L + lane] = hv;
        ((ushort4*)outl)[(size_t)node * L + lane] = lv;
    } else {
        ((float4*)outf)[(size_t)node * L + lane] = acc;
    }
}

// ---------------------------------------------------------------------------
extern "C" void kernel_launch(void* const* d_in, const int* in_sizes, int n_in,
                              void* d_out, int out_size, void* d_ws, size_t ws_size,
                              hipStream_t stream) {
    const float* x   = (const float*)d_in[0];
    const int*   eix = (const int*)d_in[1];
    const float* W1  = (const float*)d_in[2];
    const float* b1  = (const float*)d_in[3];
    const float* W2  = (const float*)d_in[4];
    const float* b2  = (const float*)d_in[5];
    const float* W3  = (const float*)d_in[6];
    const float* b3  = (const float*)d_in[7];
    float* out = (float*)d_out;

    const int n = NN, E = NE;

    char* p = (char*)d_ws;
    auto alloc = [&](size_t bytes) { void* r = (void*)p; p += align_up(bytes, 256); return r; };
    int*   deg_cnt   = (int*)alloc((size_t)n * 4);
    float* dinv      = (float*)alloc((size_t)n * 4);
    int*   row_start = (int*)alloc((size_t)n * 4);
    int*   gcount    = (int*)alloc((size_t)(NBKT + 1) * 4);
    int*   bstart    = (int*)alloc((size_t)(NBKT + 1) * 4);
    int*   base      = (int*)alloc((size_t)P1B * NBKT * 4);
    int2*  pairs     = (int2*)alloc((size_t)E * 8);
    int*   csr       = (int*)alloc((size_t)E * 4);
    unsigned short* w1th = (unsigned short*)alloc((size_t)128 * 256 * 2);
    unsigned short* w1tl = (unsigned short*)alloc((size_t)128 * 256 * 2);
    unsigned short* w2th = (unsigned short*)alloc((size_t)256 * 128 * 2);
    unsigned short* w2tl = (unsigned short*)alloc((size_t)256 * 128 * 2);
    unsigned short* w3th = (unsigned short*)alloc((size_t)128 * 32 * 2);
    unsigned short* w3tl = (unsigned short*)alloc((size_t)128 * 32 * 2);
    // region R1 (25.6 MB): agg0 hi/lo; later aliased by h2' (fp16, scaled)
    char* R1 = (char*)alloc((size_t)n * 128 * 4);
    // region R2 (51.2 MB): x' fp16; then h1 hi/lo; then x3 hi/lo + h3' fp16
    char* R2 = (char*)alloc((size_t)n * 256 * 4);
    (void)ws_size; (void)in_sizes; (void)n_in; (void)out_size;

    unsigned short* agg0h = (unsigned short*)R1;
    unsigned short* agg0l = agg0h + (size_t)n * 128;
    __half*         h2h   = (__half*)R1;                  // after agg0 consumed by gemm1
    __half*         xh    = (__half*)R2;                  // consumed by agg1 before gemm1 writes h1
    unsigned short* h1h   = (unsigned short*)R2;
    unsigned short* h1l   = h1h + (size_t)n * 256;
    unsigned short* x3h   = (unsigned short*)R2;          // after h1 consumed by gemm2
    unsigned short* x3l   = x3h + (size_t)n * 128;
    __half*         h3h   = (__half*)(R2 + (size_t)n * 128 * 4);  // after x3 hi/lo

    // ---- graph preprocessing: bucket-sorted CSR build ----
    hipMemsetAsync(gcount, 0, (size_t)(NBKT + 1) * 4, stream);
    bucket_hist<<<P1B, 256, 0, stream>>>(eix, gcount, base, E);
    bucket_scan<<<1, 512, 0, stream>>>(gcount, bstart, NBKT);
    bucket_scatter<<<P1B, 256, 0, stream>>>(eix, bstart, base, pairs, E);
    bucket_finalize<<<NBKT, 256, 0, stream>>>(pairs, bstart, row_start, deg_cnt, dinv, csr, n);

    // ---- weight prep (transpose + split, one launch) ----
    prep_weights_all<<<(69632 + 255) / 256, 256, 0, stream>>>(
        W1, W2, W3, w1th, w1tl, w2th, w2tl, w3th, w3tl);

    // ---- cast x -> pre-scaled fp16 gather table x' = dinv ⊙ x ----
    cast_f16_scaled<32><<<((n * 128 / 4) + 255) / 256, 256, 0, stream>>>(
        x, dinv, xh, n * 128 / 4);

    const int RB = (n + 127) / 128;  // 391 row blocks

    // ---- layer 1: agg0 = A_norm @ x (split bf16); h1 = relu(agg0 @ W1 + b1) (split bf16)
    agg4h<128, 8, false, false, 1><<<(n + 7) / 8, 256, 0, stream>>>(
        xh, row_start, deg_cnt, csr, dinv, nullptr, nullptr, agg0h, agg0l, n);
    gemm_mfma<128, 128, 2, 2, true, true, 1, false><<<dim3(2, RB), 256, 0, stream>>>(
        agg0h, agg0l, w1th, w1tl, b1, nullptr, nullptr, h1h, h1l, nullptr, n, 128, 256);

    // ---- layer 2: h2' = dinv ⊙ (h1 @ W2) (fp16); x3 = relu(agg + b2) (split bf16)
    gemm_mfma<128, 128, 2, 2, false, false, 2, true><<<dim3(1, RB), 256, 0, stream>>>(
        h1h, h1l, w2th, w2tl, nullptr, dinv, nullptr, nullptr, nullptr, h2h, n, 256, 128);
    agg4h<128, 8, true, true, 1><<<(n + 7) / 8, 256, 0, stream>>>(
        h2h, row_start, deg_cnt, csr, dinv, b2, nullptr, x3h, x3l, n);

    // ---- layer 3: h3' = dinv ⊙ (x3 @ W3) (fp16); out = agg + b3 (f32)
    gemm_mfma<128, 32, 4, 1, false, false, 2, true><<<dim3(1, RB), 256, 0, stream>>>(
        x3h, x3l, w3th, w3tl, nullptr, dinv, nullptr, nullptr, nullptr, h3h, n, 128, 32);
    agg4h<32, 32, true, false, 0><<<(n + 31) / 32, 256, 0, stream>>>(
        h3h, row_start, deg_cnt, csr, dinv, b3, out, nullptr, nullptr, n);
}

// Round 8
// 183.800 us; speedup vs baseline: 4.7027x; 1.1236x over previous
//
#include <hip/hip_runtime.h>
#include <hip/hip_fp16.h>

#define NN 50000
#define NE 800000
#define NBKT 391          // ceil(50000/128) buckets of 128 nodes
#define P1B 128           // blocks in hist/scatter passes

typedef __attribute__((ext_vector_type(8))) _Float16 half8v;  // 8 fp16 in 4 VGPRs
typedef __attribute__((ext_vector_type(4))) float f32x4;

static inline size_t align_up(size_t x, size_t a) { return (x + a - 1) & ~(a - 1); }

union U8 {
    ushort4 u;
    __half2 h[2];
};

__device__ __forceinline__ float4 u8_to_f4(ushort4 uu) {
    U8 c;
    c.u = uu;
    float2 f01 = __half22float2(c.h[0]);
    float2 f23 = __half22float2(c.h[1]);
    return make_float4(f01.x, f01.y, f23.x, f23.y);
}

__device__ __forceinline__ ushort4 f4_to_u8(float4 v) {
    U8 c;
    c.h[0] = __floats2half2_rn(v.x, v.y);
    c.h[1] = __floats2half2_rn(v.z, v.w);
    return c.u;
}

// int64-vs-int32 edge layout probe (values < 2^31 => odd words zero)
__device__ __forceinline__ int detect64(const int* __restrict__ e) {
    int ok = 1;
    for (int k = 1; k < 64; k += 2) ok &= (e[k] == 0);
    return ok;
}

// ---------------------------------------------------------------------------
// P1: per-block bucket histogram; reserve per-(block,bucket) chunk in gcount
// ---------------------------------------------------------------------------
__global__ __launch_bounds__(256) void bucket_hist(const int* __restrict__ e,
                                                   int* __restrict__ gcount,
                                                   int* __restrict__ base, int E) {
    __shared__ int hist[NBKT];
    const int is64 = detect64(e);
    for (int t = threadIdx.x; t < NBKT; t += 256) hist[t] = 0;
    __syncthreads();
    const int chunk = (E + P1B - 1) / P1B;
    const int b0 = blockIdx.x * chunk;
    const int b1 = min(E, b0 + chunk);
    for (int i = b0 + threadIdx.x; i < b1; i += 256) {
        int d = is64 ? e[2 * (E + i)] : e[E + i];
        atomicAdd(&hist[d >> 7], 1);
    }
    __syncthreads();
    for (int t = threadIdx.x; t < NBKT; t += 256)
        base[blockIdx.x * NBKT + t] = atomicAdd(&gcount[t], hist[t]);
}

// ---------------------------------------------------------------------------
// P2: exclusive scan of bucket counts -> bucket_start[0..NBKT]
// ---------------------------------------------------------------------------
__global__ __launch_bounds__(512) void bucket_scan(const int* __restrict__ gcount,
                                                   int* __restrict__ bstart, int nb) {
    __shared__ int s[512];
    const int t = threadIdx.x;
    int v = (t < nb) ? gcount[t] : 0;
    s[t] = v;
    __syncthreads();
    for (int off = 1; off < 512; off <<= 1) {
        int tv = (t >= off) ? s[t - off] : 0;
        __syncthreads();
        s[t] += tv;
        __syncthreads();
    }
    if (t < nb) bstart[t] = s[t] - v;
    if (t == 0) bstart[nb] = s[511];  // total = E
}

// ---------------------------------------------------------------------------
// P3: scatter (src,dst) pairs into bucket-binned order; per-(block,bucket)
// chunks are contiguous -> line-friendly writes
// ---------------------------------------------------------------------------
__global__ __launch_bounds__(256) void bucket_scatter(const int* __restrict__ e,
                                                      const int* __restrict__ bstart,
                                                      const int* __restrict__ base,
                                                      int2* __restrict__ pairs, int E) {
    __shared__ int cur[NBKT];
    const int is64 = detect64(e);
    for (int t = threadIdx.x; t < NBKT; t += 256)
        cur[t] = bstart[t] + base[blockIdx.x * NBKT + t];
    __syncthreads();
    const int chunk = (E + P1B - 1) / P1B;
    const int b0 = blockIdx.x * chunk;
    const int b1 = min(E, b0 + chunk);
    for (int i = b0 + threadIdx.x; i < b1; i += 256) {
        int s = is64 ? e[2 * i] : e[i];
        int d = is64 ? e[2 * (E + i)] : e[E + i];
        int pos = atomicAdd(&cur[d >> 7], 1);
        pairs[pos] = make_int2(s, d);
    }
}

// ---------------------------------------------------------------------------
// P4: one block per bucket. Stream pairs twice: (1) local deg count + scan,
// write deg/row_start/dinv; (2) LDS-cursor scatter src -> contiguous CSR range.
// ---------------------------------------------------------------------------
__global__ __launch_bounds__(256) void bucket_finalize(const int2* __restrict__ pairs,
                                                       const int* __restrict__ bstart,
                                                       int* __restrict__ row_start,
                                                       int* __restrict__ deg_cnt,
                                                       float* __restrict__ dinv,
                                                       int* __restrict__ csr, int n) {
    __shared__ int ldeg[128];
    __shared__ int lscan[128];
    __shared__ int cur[128];
    const int bkt = blockIdx.x;
    const int s0 = bstart[bkt], s1 = bstart[bkt + 1];
    if (threadIdx.x < 128) ldeg[threadIdx.x] = 0;
    __syncthreads();
    for (int i = s0 + threadIdx.x; i < s1; i += 256)
        atomicAdd(&ldeg[pairs[i].y & 127], 1);
    __syncthreads();
    if (threadIdx.x < 128) lscan[threadIdx.x] = ldeg[threadIdx.x];
    __syncthreads();
    for (int off = 1; off < 128; off <<= 1) {
        int v = 0;
        if (threadIdx.x < 128 && threadIdx.x >= off) v = lscan[threadIdx.x - off];
        __syncthreads();
        if (threadIdx.x < 128) lscan[threadIdx.x] += v;
        __syncthreads();
    }
    if (threadIdx.x < 128) {
        int node = (bkt << 7) + threadIdx.x;
        int exc = s0 + lscan[threadIdx.x] - ldeg[threadIdx.x];
        cur[threadIdx.x] = exc;
        if (node < n) {
            row_start[node] = exc;
            deg_cnt[node] = ldeg[threadIdx.x];
            dinv[node] = rsqrtf((float)(ldeg[threadIdx.x] + 1));  // +1 self-loop
        }
    }
    __syncthreads();
    for (int i = s0 + threadIdx.x; i < s1; i += 256) {
        int2 pr = pairs[i];
        int pos = atomicAdd(&cur[pr.y & 127], 1);
        csr[pos] = pr.x;
    }
}

// ---------------------------------------------------------------------------
// all weights: f32 [K][M] -> transposed split fp16 [M][K] hi/lo (one launch);
// also zeroes gcount (replaces a 40us rocclr fill dispatch)
// ---------------------------------------------------------------------------
__global__ void prep_weights_all(const float* __restrict__ W1, const float* __restrict__ W2,
                                 const float* __restrict__ W3,
                                 unsigned short* __restrict__ w1th, unsigned short* __restrict__ w1tl,
                                 unsigned short* __restrict__ w2th, unsigned short* __restrict__ w2tl,
                                 unsigned short* __restrict__ w3th, unsigned short* __restrict__ w3tl,
                                 int* __restrict__ gcount) {
    int i = blockIdx.x * blockDim.x + threadIdx.x;
    if (i < NBKT + 1) gcount[i] = 0;
    const float* W;
    unsigned short *th, *tl;
    int K, M, j;
    if (i < 32768)      { W = W1; th = w1th; tl = w1tl; K = 128; M = 256; j = i; }
    else if (i < 65536) { W = W2; th = w2th; tl = w2tl; K = 256; M = 128; j = i - 32768; }
    else if (i < 69632) { W = W3; th = w3th; tl = w3tl; K = 128; M = 32;  j = i - 65536; }
    else return;
    int k = j / M, m = j % M;
    float v = W[j];
    __half h = __float2half_rn(v);
    __half l = __float2half_rn(v - __half2float(h));
    th[(size_t)m * K + k] = __half_as_ushort(h);
    tl[(size_t)m * K + k] = __half_as_ushort(l);
}

// f32 [n x F] -> fp16 gather table, pre-scaled by dinv[row]; float4-at-a-time
template <int L>  // L = F/4
__global__ void cast_f16_scaled(const float* __restrict__ in, const float* __restrict__ dinv,
                                unsigned short* __restrict__ out, int total4) {
    int i = blockIdx.x * blockDim.x + threadIdx.x;
    if (i >= total4) return;
    float4 v = ((const float4*)in)[i];
    float s = dinv[i / L];
    v.x *= s; v.y *= s; v.z *= s; v.w *= s;
    ((ushort4*)out)[i] = f4_to_u8(v);
}

// ---------------------------------------------------------------------------
// fp16 MFMA GEMM: C[N,M] = A[N,K](fp16) @ (Wh+Wl)[K,M](split fp16, transposed)
// 2 MFMA per acc per K-step: a*wh + a*wl. W rel err ~6e-8; A rel err 2.4e-4.
// OUTF16: write fp16 (else f32). SCALE: multiply row by dscale[row].
// ---------------------------------------------------------------------------
template <int BM, int BN, int WM, int WN, bool BIAS, bool RELU, bool OUTF16, bool SCALE>
__global__ __launch_bounds__(256) void gemm_f16(
    const unsigned short* __restrict__ A,
    const unsigned short* __restrict__ Wth, const unsigned short* __restrict__ Wtl,
    const float* __restrict__ bias, const float* __restrict__ dscale,
    float* __restrict__ Cf, unsigned short* __restrict__ Ch,
    int N, int K, int M) {
    constexpr int KS = 32;
    constexpr int LDA = KS + 8;  // 40 halfs/row: 2-way LDS conflicts only (free)
    constexpr int WTM = BM / WM;
    constexpr int WTN = BN / WN;
    constexpr int FM = WTM / 16;
    constexpr int FN = WTN / 16;
    __shared__ unsigned short sA[BM][LDA], sWh[BN][LDA], sWl[BN][LDA];

    const int tid = threadIdx.x;
    const int lane = tid & 63;
    const int w = tid >> 6;
    const int wr = w / WN, wc = w % WN;
    const int row0 = blockIdx.y * BM;
    const int col0 = blockIdx.x * BN;

    f32x4 acc[FM][FN];
#pragma unroll
    for (int m = 0; m < FM; ++m)
#pragma unroll
        for (int nn = 0; nn < FN; ++nn) {
            f32x4 z = {0.f, 0.f, 0.f, 0.f};
            acc[m][nn] = z;
        }

    for (int k0 = 0; k0 < K; k0 += KS) {
        for (int idx = tid; idx < BM * KS / 8; idx += 256) {
            int r = idx / (KS / 8);
            int s = idx % (KS / 8);
            int gr = row0 + r;
            int4 va = make_int4(0, 0, 0, 0);
            if (gr < N) va = *(const int4*)&A[(size_t)gr * K + k0 + s * 8];
            *(int4*)&sA[r][s * 8] = va;
        }
        for (int idx = tid; idx < BN * KS / 8; idx += 256) {
            int c = idx / (KS / 8);
            int s = idx % (KS / 8);
            int gc = col0 + c;
            *(int4*)&sWh[c][s * 8] = *(const int4*)&Wth[(size_t)gc * K + k0 + s * 8];
            *(int4*)&sWl[c][s * 8] = *(const int4*)&Wtl[(size_t)gc * K + k0 + s * 8];
        }
        __syncthreads();

        half8v af[FM], wfh[FN], wfl[FN];
        const int koff = (lane >> 4) * 8;
        const int rsel = lane & 15;
#pragma unroll
        for (int m = 0; m < FM; ++m)
            af[m] = *(const half8v*)&sA[wr * WTM + m * 16 + rsel][koff];
#pragma unroll
        for (int nn = 0; nn < FN; ++nn) {
            wfh[nn] = *(const half8v*)&sWh[wc * WTN + nn * 16 + rsel][koff];
            wfl[nn] = *(const half8v*)&sWl[wc * WTN + nn * 16 + rsel][koff];
        }
#pragma unroll
        for (int m = 0; m < FM; ++m)
#pragma unroll
            for (int nn = 0; nn < FN; ++nn) {
                acc[m][nn] = __builtin_amdgcn_mfma_f32_16x16x32_f16(af[m], wfh[nn], acc[m][nn], 0, 0, 0);
                acc[m][nn] = __builtin_amdgcn_mfma_f32_16x16x32_f16(af[m], wfl[nn], acc[m][nn], 0, 0, 0);
            }
        __syncthreads();
    }

    // epilogue: D layout col=lane&15, row=(lane>>4)*4+reg (m89-verified)
#pragma unroll
    for (int m = 0; m < FM; ++m) {
#pragma unroll
        for (int r = 0; r < 4; ++r) {
            int row = row0 + wr * WTM + m * 16 + (lane >> 4) * 4 + r;
            if (row >= N) continue;
            float rs = SCALE ? dscale[row] : 1.f;
#pragma unroll
            for (int nn = 0; nn < FN; ++nn) {
                int col = col0 + wc * WTN + nn * 16 + (lane & 15);
                float v = acc[m][nn][r];
                if (BIAS) v += bias[col];
                if (RELU) v = fmaxf(v, 0.f);
                if (SCALE) v *= rs;
                if constexpr (OUTF16) {
                    Ch[(size_t)row * M + col] = __half_as_ushort(__float2half_rn(v));
                } else {
                    Cf[(size_t)row * M + col] = v;
                }
            }
        }
    }
}

// ---------------------------------------------------------------------------
// CSR aggregation over PRE-SCALED fp16 table h' = dinv ⊙ h:
// out[d] = dinv[d] * (h'[d] + Σ_{s∈N(d)} h'[s]) + bias ; unrolled x8
// OUTF16: write fp16 single table (else f32)
// ---------------------------------------------------------------------------
__device__ __forceinline__ float4 add4(float4 v, float4 a) {
    a.x += v.x; a.y += v.y; a.z += v.z; a.w += v.w;
    return a;
}

template <int F, int NPB, bool BIAS, bool RELU, bool OUTF16>
__global__ __launch_bounds__((F / 4) * NPB) void agg4h(
    const unsigned short* __restrict__ h, const int* __restrict__ row_start,
    const int* __restrict__ deg_cnt, const int* __restrict__ csr,
    const float* __restrict__ dinv, const float* __restrict__ bias,
    float* __restrict__ outf, unsigned short* __restrict__ outh, int n) {
    constexpr int L = F / 4;
    const int local = threadIdx.x / L;
    const int lane = threadIdx.x % L;
    const int node = blockIdx.x * NPB + local;
    if (node >= n) return;

    const ushort4* __restrict__ h4 = (const ushort4*)h;
    const float di = dinv[node];

    float4 acc = u8_to_f4(h4[(size_t)node * L + lane]);  // self term h'[d]

    const int beg = row_start[node];
    const int num = deg_cnt[node];
    int e = 0;
    for (; e + 8 <= num; e += 8) {
        int c[8];
        float4 v[8];
#pragma unroll
        for (int u = 0; u < 8; ++u) c[u] = csr[beg + e + u];
#pragma unroll
        for (int u = 0; u < 8; ++u) v[u] = u8_to_f4(h4[(size_t)c[u] * L + lane]);
#pragma unroll
        for (int u = 0; u < 8; ++u) acc = add4(v[u], acc);
    }
    for (; e < num; ++e) {
        const int c = csr[beg + e];
        acc = add4(u8_to_f4(h4[(size_t)c * L + lane]), acc);
    }
    acc.x *= di; acc.y *= di; acc.z *= di; acc.w *= di;
    if (BIAS) {
        const float4 b = ((const float4*)bias)[lane];
        acc.x += b.x; acc.y += b.y; acc.z += b.z; acc.w += b.w;
    }
    if (RELU) {
        acc.x = fmaxf(acc.x, 0.f); acc.y = fmaxf(acc.y, 0.f);
        acc.z = fmaxf(acc.z, 0.f); acc.w = fmaxf(acc.w, 0.f);
    }
    if constexpr (OUTF16) {
        ((ushort4*)outh)[(size_t)node * L + lane] = f4_to_u8(acc);
    } else {
        ((float4*)outf)[(size_t)node * L + lane] = acc;
    }
}

// ---------------------------------------------------------------------------
extern "C" void kernel_launch(void* const* d_in, const int* in_sizes, int n_in,
                              void* d_out, int out_size, void* d_ws, size_t ws_size,
                              hipStream_t stream) {
    const float* x   = (const float*)d_in[0];
    const int*   eix = (const int*)d_in[1];
    const float* W1  = (const float*)d_in[2];
    const float* b1  = (const float*)d_in[3];
    const float* W2  = (const float*)d_in[4];
    const float* b2  = (const float*)d_in[5];
    const float* W3  = (const float*)d_in[6];
    const float* b3  = (const float*)d_in[7];
    float* out = (float*)d_out;

    const int n = NN, E = NE;

    char* p = (char*)d_ws;
    auto alloc = [&](size_t bytes) { void* r = (void*)p; p += align_up(bytes, 256); return r; };
    int*   deg_cnt   = (int*)alloc((size_t)n * 4);
    float* dinv      = (float*)alloc((size_t)n * 4);
    int*   row_start = (int*)alloc((size_t)n * 4);
    int*   gcount    = (int*)alloc((size_t)(NBKT + 1) * 4);
    int*   bstart    = (int*)alloc((size_t)(NBKT + 1) * 4);
    int*   base      = (int*)alloc((size_t)P1B * NBKT * 4);
    int2*  pairs     = (int2*)alloc((size_t)E * 8);
    int*   csr       = (int*)alloc((size_t)E * 4);
    unsigned short* w1th = (unsigned short*)alloc((size_t)128 * 256 * 2);
    unsigned short* w1tl = (unsigned short*)alloc((size_t)128 * 256 * 2);
    unsigned short* w2th = (unsigned short*)alloc((size_t)256 * 128 * 2);
    unsigned short* w2tl = (unsigned short*)alloc((size_t)256 * 128 * 2);
    unsigned short* w3th = (unsigned short*)alloc((size_t)128 * 32 * 2);
    unsigned short* w3tl = (unsigned short*)alloc((size_t)128 * 32 * 2);
    unsigned short* xh    = (unsigned short*)alloc((size_t)n * 128 * 2);  // x'  fp16
    unsigned short* agg0  = (unsigned short*)alloc((size_t)n * 128 * 2);  // agg0 fp16
    unsigned short* h1    = (unsigned short*)alloc((size_t)n * 256 * 2);  // h1  fp16
    unsigned short* h2s   = (unsigned short*)alloc((size_t)n * 128 * 2);  // h2' fp16 (scaled)
    unsigned short* x3    = (unsigned short*)alloc((size_t)n * 128 * 2);  // x3  fp16
    unsigned short* h3s   = (unsigned short*)alloc((size_t)n * 32 * 2);   // h3' fp16 (scaled)
    (void)ws_size; (void)in_sizes; (void)n_in; (void)out_size;

    // ---- weight prep first (also zeroes gcount, ordered before bucket_hist) ----
    prep_weights_all<<<(69632 + 255) / 256, 256, 0, stream>>>(
        W1, W2, W3, w1th, w1tl, w2th, w2tl, w3th, w3tl, gcount);

    // ---- graph preprocessing: bucket-sorted CSR build ----
    bucket_hist<<<P1B, 256, 0, stream>>>(eix, gcount, base, E);
    bucket_scan<<<1, 512, 0, stream>>>(gcount, bstart, NBKT);
    bucket_scatter<<<P1B, 256, 0, stream>>>(eix, bstart, base, pairs, E);
    bucket_finalize<<<NBKT, 256, 0, stream>>>(pairs, bstart, row_start, deg_cnt, dinv, csr, n);

    // ---- cast x -> pre-scaled fp16 gather table x' = dinv ⊙ x ----
    cast_f16_scaled<32><<<((n * 128 / 4) + 255) / 256, 256, 0, stream>>>(
        x, dinv, xh, n * 128 / 4);

    const int RB = (n + 127) / 128;  // 391 row blocks

    // ---- layer 1: agg0 = A_norm @ x (fp16); h1 = relu(agg0 @ W1 + b1) (fp16)
    agg4h<128, 8, false, false, true><<<(n + 7) / 8, 256, 0, stream>>>(
        xh, row_start, deg_cnt, csr, dinv, nullptr, nullptr, agg0, n);
    gemm_f16<128, 128, 2, 2, true, true, true, false><<<dim3(2, RB), 256, 0, stream>>>(
        agg0, w1th, w1tl, b1, nullptr, nullptr, h1, n, 128, 256);

    // ---- layer 2: h2' = dinv ⊙ (h1 @ W2) (fp16); x3 = relu(agg + b2) (fp16)
    gemm_f16<128, 128, 2, 2, false, false, true, true><<<dim3(1, RB), 256, 0, stream>>>(
        h1, w2th, w2tl, nullptr, dinv, nullptr, h2s, n, 256, 128);
    agg4h<128, 8, true, true, true><<<(n + 7) / 8, 256, 0, stream>>>(
        h2s, row_start, deg_cnt, csr, dinv, b2, nullptr, x3, n);

    // ---- layer 3: h3' = dinv ⊙ (x3 @ W3) (fp16); out = agg + b3 (f32)
    gemm_f16<128, 32, 4, 1, false, false, true, true><<<dim3(1, RB), 256, 0, stream>>>(
        x3, w3th, w3tl, nullptr, dinv, nullptr, h3s, n, 128, 32);
    agg4h<32, 32, true, false, false><<<(n + 31) / 32, 256, 0, stream>>>(
        h3s, row_start, deg_cnt, csr, dinv, b3, out, nullptr, n);
}

// Round 9
// 176.964 us; speedup vs baseline: 4.8844x; 1.0386x over previous
//
#include <hip/hip_runtime.h>
#include <hip/hip_fp16.h>

#define NN 50000
#define NE 800000
#define NBKT 391          // ceil(50000/128) buckets of 128 nodes
#define P1B 128           // blocks in hist/scatter passes

typedef __attribute__((ext_vector_type(8))) _Float16 half8v;  // 8 fp16 in 4 VGPRs
typedef __attribute__((ext_vector_type(4))) float f32x4;

static inline size_t align_up(size_t x, size_t a) { return (x + a - 1) & ~(a - 1); }

union U8 {
    ushort4 u;
    __half2 h[2];
};

__device__ __forceinline__ float4 u8_to_f4(ushort4 uu) {
    U8 c;
    c.u = uu;
    float2 f01 = __half22float2(c.h[0]);
    float2 f23 = __half22float2(c.h[1]);
    return make_float4(f01.x, f01.y, f23.x, f23.y);
}

__device__ __forceinline__ ushort4 f4_to_u8(float4 v) {
    U8 c;
    c.h[0] = __floats2half2_rn(v.x, v.y);
    c.h[1] = __floats2half2_rn(v.z, v.w);
    return c.u;
}

// int64-vs-int32 edge layout probe (values < 2^31 => odd words zero)
__device__ __forceinline__ int detect64(const int* __restrict__ e) {
    int ok = 1;
    for (int k = 1; k < 64; k += 2) ok &= (e[k] == 0);
    return ok;
}

// ---------------------------------------------------------------------------
// P1: per-block bucket histogram; reserve per-(block,bucket) chunk in gcount
// ---------------------------------------------------------------------------
__global__ __launch_bounds__(256) void bucket_hist(const int* __restrict__ e,
                                                   int* __restrict__ gcount,
                                                   int* __restrict__ base, int E) {
    __shared__ int hist[NBKT];
    const int is64 = detect64(e);
    for (int t = threadIdx.x; t < NBKT; t += 256) hist[t] = 0;
    __syncthreads();
    const int chunk = (E + P1B - 1) / P1B;
    const int b0 = blockIdx.x * chunk;
    const int b1 = min(E, b0 + chunk);
    for (int i = b0 + threadIdx.x; i < b1; i += 256) {
        int d = is64 ? e[2 * (E + i)] : e[E + i];
        atomicAdd(&hist[d >> 7], 1);
    }
    __syncthreads();
    for (int t = threadIdx.x; t < NBKT; t += 256)
        base[blockIdx.x * NBKT + t] = atomicAdd(&gcount[t], hist[t]);
}

// ---------------------------------------------------------------------------
// P2: exclusive scan of bucket counts -> bucket_start[0..NBKT]
// ---------------------------------------------------------------------------
__global__ __launch_bounds__(512) void bucket_scan(const int* __restrict__ gcount,
                                                   int* __restrict__ bstart, int nb) {
    __shared__ int s[512];
    const int t = threadIdx.x;
    int v = (t < nb) ? gcount[t] : 0;
    s[t] = v;
    __syncthreads();
    for (int off = 1; off < 512; off <<= 1) {
        int tv = (t >= off) ? s[t - off] : 0;
        __syncthreads();
        s[t] += tv;
        __syncthreads();
    }
    if (t < nb) bstart[t] = s[t] - v;
    if (t == 0) bstart[nb] = s[511];  // total = E
}

// ---------------------------------------------------------------------------
// P3: scatter packed edges (src u16 | dst_local u7) into bucket-binned order
// ---------------------------------------------------------------------------
__global__ __launch_bounds__(256) void bucket_scatter(const int* __restrict__ e,
                                                      const int* __restrict__ bstart,
                                                      const int* __restrict__ base,
                                                      unsigned* __restrict__ pairs, int E) {
    __shared__ int cur[NBKT];
    const int is64 = detect64(e);
    for (int t = threadIdx.x; t < NBKT; t += 256)
        cur[t] = bstart[t] + base[blockIdx.x * NBKT + t];
    __syncthreads();
    const int chunk = (E + P1B - 1) / P1B;
    const int b0 = blockIdx.x * chunk;
    const int b1 = min(E, b0 + chunk);
    for (int i = b0 + threadIdx.x; i < b1; i += 256) {
        int s = is64 ? e[2 * i] : e[i];
        int d = is64 ? e[2 * (E + i)] : e[E + i];
        int pos = atomicAdd(&cur[d >> 7], 1);
        pairs[pos] = (unsigned)s | ((unsigned)(d & 127) << 16);
    }
}

// ---------------------------------------------------------------------------
// P4: one block per bucket. (1) local deg count + scan -> deg/row_start/dinv;
// (2) LDS-cursor scatter src -> contiguous u16 CSR range; (3) fused cast of
// this bucket's x rows to pre-scaled fp16 (x' = dinv ⊙ x).
// ---------------------------------------------------------------------------
__global__ __launch_bounds__(256) void bucket_finalize(const unsigned* __restrict__ pairs,
                                                       const int* __restrict__ bstart,
                                                       const float* __restrict__ x,
                                                       int* __restrict__ row_start,
                                                       int* __restrict__ deg_cnt,
                                                       float* __restrict__ dinv,
                                                       unsigned short* __restrict__ csr,
                                                       unsigned short* __restrict__ xh, int n) {
    __shared__ int ldeg[128];
    __shared__ int lscan[128];
    __shared__ int cur[128];
    __shared__ float sdinv[128];
    const int bkt = blockIdx.x;
    const int s0 = bstart[bkt], s1 = bstart[bkt + 1];
    if (threadIdx.x < 128) ldeg[threadIdx.x] = 0;
    __syncthreads();
    for (int i = s0 + threadIdx.x; i < s1; i += 256)
        atomicAdd(&ldeg[pairs[i] >> 16], 1);
    __syncthreads();
    if (threadIdx.x < 128) lscan[threadIdx.x] = ldeg[threadIdx.x];
    __syncthreads();
    for (int off = 1; off < 128; off <<= 1) {
        int v = 0;
        if (threadIdx.x < 128 && threadIdx.x >= off) v = lscan[threadIdx.x - off];
        __syncthreads();
        if (threadIdx.x < 128) lscan[threadIdx.x] += v;
        __syncthreads();
    }
    if (threadIdx.x < 128) {
        int node = (bkt << 7) + threadIdx.x;
        int exc = s0 + lscan[threadIdx.x] - ldeg[threadIdx.x];
        cur[threadIdx.x] = exc;
        float di = rsqrtf((float)(ldeg[threadIdx.x] + 1));  // +1 self-loop
        sdinv[threadIdx.x] = di;
        if (node < n) {
            row_start[node] = exc;
            deg_cnt[node] = ldeg[threadIdx.x];
            dinv[node] = di;
        }
    }
    __syncthreads();
    // csr scatter (u16 src)
    for (int i = s0 + threadIdx.x; i < s1; i += 256) {
        unsigned pr = pairs[i];
        int pos = atomicAdd(&cur[pr >> 16], 1);
        csr[pos] = (unsigned short)(pr & 0xFFFFu);
    }
    // fused cast: x rows of this bucket -> pre-scaled fp16 (linear, coalesced)
    for (int idx = threadIdx.x; idx < 128 * 32; idx += 256) {
        int ln = idx >> 5;         // local node
        int c4 = idx & 31;         // float4 chunk within row (128 feats)
        int node = (bkt << 7) + ln;
        if (node < n) {
            float4 v = ((const float4*)x)[(size_t)node * 32 + c4];
            float s = sdinv[ln];
            v.x *= s; v.y *= s; v.z *= s; v.w *= s;
            ((ushort4*)xh)[(size_t)node * 32 + c4] = f4_to_u8(v);
        }
    }
}

// ---------------------------------------------------------------------------
// all weights: f32 [K][M] -> transposed fp16 [M][K] (one launch);
// also zeroes gcount (replaces a rocclr fill dispatch)
// ---------------------------------------------------------------------------
__global__ void prep_weights_all(const float* __restrict__ W1, const float* __restrict__ W2,
                                 const float* __restrict__ W3,
                                 unsigned short* __restrict__ w1t,
                                 unsigned short* __restrict__ w2t,
                                 unsigned short* __restrict__ w3t,
                                 int* __restrict__ gcount) {
    int i = blockIdx.x * blockDim.x + threadIdx.x;
    if (i < NBKT + 1) gcount[i] = 0;
    const float* W;
    unsigned short* th;
    int K, M, j;
    if (i < 32768)      { W = W1; th = w1t; K = 128; M = 256; j = i; }
    else if (i < 65536) { W = W2; th = w2t; K = 256; M = 128; j = i - 32768; }
    else if (i < 69632) { W = W3; th = w3t; K = 128; M = 32;  j = i - 65536; }
    else return;
    int k = j / M, m = j % M;
    th[(size_t)m * K + k] = __half_as_ushort(__float2half_rn(W[j]));
}

// ---------------------------------------------------------------------------
// fp16 MFMA GEMM: C[N,M] = A[N,K](fp16) @ W[K,M](fp16, transposed)
// OUTF16: write fp16 (else f32). SCALE: multiply row by dscale[row].
// ---------------------------------------------------------------------------
template <int BM, int BN, int WM, int WN, bool BIAS, bool RELU, bool OUTF16, bool SCALE>
__global__ __launch_bounds__(256) void gemm_f16(
    const unsigned short* __restrict__ A,
    const unsigned short* __restrict__ Wt,
    const float* __restrict__ bias, const float* __restrict__ dscale,
    float* __restrict__ Cf, unsigned short* __restrict__ Ch,
    int N, int K, int M) {
    constexpr int KS = 32;
    constexpr int LDA = KS + 8;  // 40 halfs/row: 2-way LDS conflicts only (free)
    constexpr int WTM = BM / WM;
    constexpr int WTN = BN / WN;
    constexpr int FM = WTM / 16;
    constexpr int FN = WTN / 16;
    __shared__ unsigned short sA[BM][LDA], sW[BN][LDA];

    const int tid = threadIdx.x;
    const int lane = tid & 63;
    const int w = tid >> 6;
    const int wr = w / WN, wc = w % WN;
    const int row0 = blockIdx.y * BM;
    const int col0 = blockIdx.x * BN;

    f32x4 acc[FM][FN];
#pragma unroll
    for (int m = 0; m < FM; ++m)
#pragma unroll
        for (int nn = 0; nn < FN; ++nn) {
            f32x4 z = {0.f, 0.f, 0.f, 0.f};
            acc[m][nn] = z;
        }

    for (int k0 = 0; k0 < K; k0 += KS) {
        for (int idx = tid; idx < BM * KS / 8; idx += 256) {
            int r = idx / (KS / 8);
            int s = idx % (KS / 8);
            int gr = row0 + r;
            int4 va = make_int4(0, 0, 0, 0);
            if (gr < N) va = *(const int4*)&A[(size_t)gr * K + k0 + s * 8];
            *(int4*)&sA[r][s * 8] = va;
        }
        for (int idx = tid; idx < BN * KS / 8; idx += 256) {
            int c = idx / (KS / 8);
            int s = idx % (KS / 8);
            int gc = col0 + c;
            *(int4*)&sW[c][s * 8] = *(const int4*)&Wt[(size_t)gc * K + k0 + s * 8];
        }
        __syncthreads();

        half8v af[FM], wf[FN];
        const int koff = (lane >> 4) * 8;
        const int rsel = lane & 15;
#pragma unroll
        for (int m = 0; m < FM; ++m)
            af[m] = *(const half8v*)&sA[wr * WTM + m * 16 + rsel][koff];
#pragma unroll
        for (int nn = 0; nn < FN; ++nn)
            wf[nn] = *(const half8v*)&sW[wc * WTN + nn * 16 + rsel][koff];
#pragma unroll
        for (int m = 0; m < FM; ++m)
#pragma unroll
            for (int nn = 0; nn < FN; ++nn)
                acc[m][nn] = __builtin_amdgcn_mfma_f32_16x16x32_f16(af[m], wf[nn], acc[m][nn], 0, 0, 0);
        __syncthreads();
    }

    // epilogue: D layout col=lane&15, row=(lane>>4)*4+reg (m89-verified)
#pragma unroll
    for (int m = 0; m < FM; ++m) {
#pragma unroll
        for (int r = 0; r < 4; ++r) {
            int row = row0 + wr * WTM + m * 16 + (lane >> 4) * 4 + r;
            if (row >= N) continue;
            float rs = SCALE ? dscale[row] : 1.f;
#pragma unroll
            for (int nn = 0; nn < FN; ++nn) {
                int col = col0 + wc * WTN + nn * 16 + (lane & 15);
                float v = acc[m][nn][r];
                if (BIAS) v += bias[col];
                if (RELU) v = fmaxf(v, 0.f);
                if (SCALE) v *= rs;
                if constexpr (OUTF16) {
                    Ch[(size_t)row * M + col] = __half_as_ushort(__float2half_rn(v));
                } else {
                    Cf[(size_t)row * M + col] = v;
                }
            }
        }
    }
}

// ---------------------------------------------------------------------------
// CSR aggregation over PRE-SCALED fp16 table h' = dinv ⊙ h:
// out[d] = dinv[d] * (h'[d] + Σ_{s∈N(d)} h'[s]) + bias
// u16 CSR; raw gather loads batched before convert (force MLP)
// ---------------------------------------------------------------------------
__device__ __forceinline__ float4 add4(float4 v, float4 a) {
    a.x += v.x; a.y += v.y; a.z += v.z; a.w += v.w;
    return a;
}

template <int F, int NPB, bool BIAS, bool RELU, bool OUTF16>
__global__ __launch_bounds__((F / 4) * NPB) void agg4h(
    const unsigned short* __restrict__ h, const int* __restrict__ row_start,
    const int* __restrict__ deg_cnt, const unsigned short* __restrict__ csr,
    const float* __restrict__ dinv, const float* __restrict__ bias,
    float* __restrict__ outf, unsigned short* __restrict__ outh, int n) {
    constexpr int L = F / 4;
    const int local = threadIdx.x / L;
    const int lane = threadIdx.x % L;
    const int node = blockIdx.x * NPB + local;
    if (node >= n) return;

    const ushort4* __restrict__ h4 = (const ushort4*)h;
    const float di = dinv[node];

    float4 acc = u8_to_f4(h4[(size_t)node * L + lane]);  // self term h'[d]

    const int beg = row_start[node];
    const int num = deg_cnt[node];
    int e = 0;
    for (; e + 8 <= num; e += 8) {
        int c[8];
        ushort4 raw[8];
#pragma unroll
        for (int u = 0; u < 8; ++u) c[u] = csr[beg + e + u];
#pragma unroll
        for (int u = 0; u < 8; ++u) raw[u] = h4[(size_t)c[u] * L + lane];
#pragma unroll
        for (int u = 0; u < 8; ++u) acc = add4(u8_to_f4(raw[u]), acc);
    }
    for (; e < num; ++e) {
        const int c = csr[beg + e];
        acc = add4(u8_to_f4(h4[(size_t)c * L + lane]), acc);
    }
    acc.x *= di; acc.y *= di; acc.z *= di; acc.w *= di;
    if (BIAS) {
        const float4 b = ((const float4*)bias)[lane];
        acc.x += b.x; acc.y += b.y; acc.z += b.z; acc.w += b.w;
    }
    if (RELU) {
        acc.x = fmaxf(acc.x, 0.f); acc.y = fmaxf(acc.y, 0.f);
        acc.z = fmaxf(acc.z, 0.f); acc.w = fmaxf(acc.w, 0.f);
    }
    if constexpr (OUTF16) {
        ((ushort4*)outh)[(size_t)node * L + lane] = f4_to_u8(acc);
    } else {
        ((float4*)outf)[(size_t)node * L + lane] = acc;
    }
}

// ---------------------------------------------------------------------------
extern "C" void kernel_launch(void* const* d_in, const int* in_sizes, int n_in,
                              void* d_out, int out_size, void* d_ws, size_t ws_size,
                              hipStream_t stream) {
    const float* x   = (const float*)d_in[0];
    const int*   eix = (const int*)d_in[1];
    const float* W1  = (const float*)d_in[2];
    const float* b1  = (const float*)d_in[3];
    const float* W2  = (const float*)d_in[4];
    const float* b2  = (const float*)d_in[5];
    const float* W3  = (const float*)d_in[6];
    const float* b3  = (const float*)d_in[7];
    float* out = (float*)d_out;

    const int n = NN, E = NE;

    char* p = (char*)d_ws;
    auto alloc = [&](size_t bytes) { void* r = (void*)p; p += align_up(bytes, 256); return r; };
    int*   deg_cnt   = (int*)alloc((size_t)n * 4);
    float* dinv      = (float*)alloc((size_t)n * 4);
    int*   row_start = (int*)alloc((size_t)n * 4);
    int*   gcount    = (int*)alloc((size_t)(NBKT + 1) * 4);
    int*   bstart    = (int*)alloc((size_t)(NBKT + 1) * 4);
    int*   base      = (int*)alloc((size_t)P1B * NBKT * 4);
    unsigned* pairs  = (unsigned*)alloc((size_t)E * 4);
    unsigned short* csr = (unsigned short*)alloc((size_t)E * 2);
    unsigned short* w1t = (unsigned short*)alloc((size_t)128 * 256 * 2);
    unsigned short* w2t = (unsigned short*)alloc((size_t)256 * 128 * 2);
    unsigned short* w3t = (unsigned short*)alloc((size_t)128 * 32 * 2);
    unsigned short* xh   = (unsigned short*)alloc((size_t)n * 128 * 2);  // x'  fp16
    unsigned short* agg0 = (unsigned short*)alloc((size_t)n * 128 * 2);  // agg0 fp16
    unsigned short* h1   = (unsigned short*)alloc((size_t)n * 256 * 2);  // h1  fp16
    unsigned short* h2s  = (unsigned short*)alloc((size_t)n * 128 * 2);  // h2' fp16 (scaled)
    unsigned short* x3   = (unsigned short*)alloc((size_t)n * 128 * 2);  // x3  fp16
    unsigned short* h3s  = (unsigned short*)alloc((size_t)n * 32 * 2);   // h3' fp16 (scaled)
    (void)ws_size; (void)in_sizes; (void)n_in; (void)out_size;

    // ---- weight prep first (also zeroes gcount, ordered before bucket_hist) ----
    prep_weights_all<<<(69632 + 255) / 256, 256, 0, stream>>>(
        W1, W2, W3, w1t, w2t, w3t, gcount);

    // ---- graph preprocessing: bucket-sorted CSR build (+ fused x cast) ----
    bucket_hist<<<P1B, 256, 0, stream>>>(eix, gcount, base, E);
    bucket_scan<<<1, 512, 0, stream>>>(gcount, bstart, NBKT);
    bucket_scatter<<<P1B, 256, 0, stream>>>(eix, bstart, base, pairs, E);
    bucket_finalize<<<NBKT, 256, 0, stream>>>(pairs, bstart, x, row_start, deg_cnt,
                                              dinv, csr, xh, n);

    const int RB = (n + 127) / 128;  // 391 row blocks

    // ---- layer 1: agg0 = A_norm @ x (fp16); h1 = relu(agg0 @ W1 + b1) (fp16)
    agg4h<128, 8, false, false, true><<<(n + 7) / 8, 256, 0, stream>>>(
        xh, row_start, deg_cnt, csr, dinv, nullptr, nullptr, agg0, n);
    gemm_f16<128, 128, 2, 2, true, true, true, false><<<dim3(2, RB), 256, 0, stream>>>(
        agg0, w1t, b1, nullptr, nullptr, h1, n, 128, 256);

    // ---- layer 2: h2' = dinv ⊙ (h1 @ W2) (fp16); x3 = relu(agg + b2) (fp16)
    gemm_f16<128, 128, 2, 2, false, false, true, true><<<dim3(1, RB), 256, 0, stream>>>(
        h1, w2t, nullptr, dinv, nullptr, h2s, n, 256, 128);
    agg4h<128, 8, true, true, true><<<(n + 7) / 8, 256, 0, stream>>>(
        h2s, row_start, deg_cnt, csr, dinv, b2, nullptr, x3, n);

    // ---- layer 3: h3' = dinv ⊙ (x3 @ W3) (fp16); out = agg + b3 (f32)
    gemm_f16<128, 32, 4, 1, false, false, true, true><<<dim3(1, RB), 256, 0, stream>>>(
        x3, w3t, nullptr, dinv, nullptr, h3s, n, 128, 32);
    agg4h<32, 32, true, false, false><<<(n + 31) / 32, 256, 0, stream>>>(
        h3s, row_start, deg_cnt, csr, dinv, b3, out, nullptr, n);
}

// Round 10
// 174.582 us; speedup vs baseline: 4.9510x; 1.0136x over previous
//
#include <hip/hip_runtime.h>
#include <hip/hip_fp16.h>

#define NN 50000
#define NE 800000
#define NBKT 391          // ceil(50000/128) buckets of 128 nodes
#define P1B 256           // blocks in hist/scatter passes

typedef __attribute__((ext_vector_type(8))) _Float16 half8v;  // 8 fp16 in 4 VGPRs
typedef __attribute__((ext_vector_type(4))) float f32x4;

static inline size_t align_up(size_t x, size_t a) { return (x + a - 1) & ~(a - 1); }

union U8 {
    ushort4 u;
    __half2 h[2];
};

__device__ __forceinline__ float4 u8_to_f4(ushort4 uu) {
    U8 c;
    c.u = uu;
    float2 f01 = __half22float2(c.h[0]);
    float2 f23 = __half22float2(c.h[1]);
    return make_float4(f01.x, f01.y, f23.x, f23.y);
}

__device__ __forceinline__ ushort4 f4_to_u8(float4 v) {
    U8 c;
    c.h[0] = __floats2half2_rn(v.x, v.y);
    c.h[1] = __floats2half2_rn(v.z, v.w);
    return c.u;
}

// int64-vs-int32 edge layout probe (values < 2^31 => odd words zero)
__device__ __forceinline__ int detect64(const int* __restrict__ e) {
    int ok = 1;
    for (int k = 1; k < 64; k += 2) ok &= (e[k] == 0);
    return ok;
}

// ---------------------------------------------------------------------------
// P1: per-block bucket histogram; reserve per-(block,bucket) chunk in gcount
// ---------------------------------------------------------------------------
__global__ __launch_bounds__(256) void bucket_hist(const int* __restrict__ e,
                                                   int* __restrict__ gcount,
                                                   int* __restrict__ base, int E) {
    __shared__ int hist[NBKT];
    const int is64 = detect64(e);
    for (int t = threadIdx.x; t < NBKT; t += 256) hist[t] = 0;
    __syncthreads();
    const int chunk = (E + P1B - 1) / P1B;
    const int b0 = blockIdx.x * chunk;
    const int b1 = min(E, b0 + chunk);
    for (int i = b0 + threadIdx.x; i < b1; i += 256) {
        int d = is64 ? e[2 * (E + i)] : e[E + i];
        atomicAdd(&hist[d >> 7], 1);
    }
    __syncthreads();
    for (int t = threadIdx.x; t < NBKT; t += 256)
        base[blockIdx.x * NBKT + t] = atomicAdd(&gcount[t], hist[t]);
}

// ---------------------------------------------------------------------------
// P2: exclusive scan of bucket counts -> bucket_start[0..NBKT]
// ---------------------------------------------------------------------------
__global__ __launch_bounds__(512) void bucket_scan(const int* __restrict__ gcount,
                                                   int* __restrict__ bstart, int nb) {
    __shared__ int s[512];
    const int t = threadIdx.x;
    int v = (t < nb) ? gcount[t] : 0;
    s[t] = v;
    __syncthreads();
    for (int off = 1; off < 512; off <<= 1) {
        int tv = (t >= off) ? s[t - off] : 0;
        __syncthreads();
        s[t] += tv;
        __syncthreads();
    }
    if (t < nb) bstart[t] = s[t] - v;
    if (t == 0) bstart[nb] = s[511];  // total = E
}

// ---------------------------------------------------------------------------
// P3: scatter packed edges (src u16 | dst_local u7) into bucket-binned order
// ---------------------------------------------------------------------------
__global__ __launch_bounds__(256) void bucket_scatter(const int* __restrict__ e,
                                                      const int* __restrict__ bstart,
                                                      const int* __restrict__ base,
                                                      unsigned* __restrict__ pairs, int E) {
    __shared__ int cur[NBKT];
    const int is64 = detect64(e);
    for (int t = threadIdx.x; t < NBKT; t += 256)
        cur[t] = bstart[t] + base[blockIdx.x * NBKT + t];
    __syncthreads();
    const int chunk = (E + P1B - 1) / P1B;
    const int b0 = blockIdx.x * chunk;
    const int b1 = min(E, b0 + chunk);
    for (int i = b0 + threadIdx.x; i < b1; i += 256) {
        int s = is64 ? e[2 * i] : e[i];
        int d = is64 ? e[2 * (E + i)] : e[E + i];
        int pos = atomicAdd(&cur[d >> 7], 1);
        pairs[pos] = (unsigned)s | ((unsigned)(d & 127) << 16);
    }
}

// ---------------------------------------------------------------------------
// P4: one block per bucket. (1) local deg count + scan -> deg/row_start/dinv;
// (2) LDS-cursor scatter src -> contiguous u16 CSR range; (3) fused cast of
// this bucket's x rows to pre-scaled fp16 (x' = dinv ⊙ x).
// ---------------------------------------------------------------------------
__global__ __launch_bounds__(256) void bucket_finalize(const unsigned* __restrict__ pairs,
                                                       const int* __restrict__ bstart,
                                                       const float* __restrict__ x,
                                                       int* __restrict__ row_start,
                                                       int* __restrict__ deg_cnt,
                                                       float* __restrict__ dinv,
                                                       unsigned short* __restrict__ csr,
                                                       unsigned short* __restrict__ xh, int n) {
    __shared__ int ldeg[128];
    __shared__ int lscan[128];
    __shared__ int cur[128];
    __shared__ float sdinv[128];
    const int bkt = blockIdx.x;
    const int s0 = bstart[bkt], s1 = bstart[bkt + 1];
    if (threadIdx.x < 128) ldeg[threadIdx.x] = 0;
    __syncthreads();
    for (int i = s0 + threadIdx.x; i < s1; i += 256)
        atomicAdd(&ldeg[pairs[i] >> 16], 1);
    __syncthreads();
    if (threadIdx.x < 128) lscan[threadIdx.x] = ldeg[threadIdx.x];
    __syncthreads();
    for (int off = 1; off < 128; off <<= 1) {
        int v = 0;
        if (threadIdx.x < 128 && threadIdx.x >= off) v = lscan[threadIdx.x - off];
        __syncthreads();
        if (threadIdx.x < 128) lscan[threadIdx.x] += v;
        __syncthreads();
    }
    if (threadIdx.x < 128) {
        int node = (bkt << 7) + threadIdx.x;
        int exc = s0 + lscan[threadIdx.x] - ldeg[threadIdx.x];
        cur[threadIdx.x] = exc;
        float di = rsqrtf((float)(ldeg[threadIdx.x] + 1));  // +1 self-loop
        sdinv[threadIdx.x] = di;
        if (node < n) {
            row_start[node] = exc;
            deg_cnt[node] = ldeg[threadIdx.x];
            dinv[node] = di;
        }
    }
    __syncthreads();
    // csr scatter (u16 src)
    for (int i = s0 + threadIdx.x; i < s1; i += 256) {
        unsigned pr = pairs[i];
        int pos = atomicAdd(&cur[pr >> 16], 1);
        csr[pos] = (unsigned short)(pr & 0xFFFFu);
    }
    // fused cast: x rows of this bucket -> pre-scaled fp16 (linear, coalesced)
    for (int idx = threadIdx.x; idx < 128 * 32; idx += 256) {
        int ln = idx >> 5;         // local node
        int c4 = idx & 31;         // float4 chunk within row (128 feats)
        int node = (bkt << 7) + ln;
        if (node < n) {
            float4 v = ((const float4*)x)[(size_t)node * 32 + c4];
            float s = sdinv[ln];
            v.x *= s; v.y *= s; v.z *= s; v.w *= s;
            ((ushort4*)xh)[(size_t)node * 32 + c4] = f4_to_u8(v);
        }
    }
}

// ---------------------------------------------------------------------------
// all weights: f32 [K][M] -> transposed fp16 [M][K] (one launch);
// also zeroes gcount (replaces a rocclr fill dispatch)
// ---------------------------------------------------------------------------
__global__ void prep_weights_all(const float* __restrict__ W1, const float* __restrict__ W2,
                                 const float* __restrict__ W3,
                                 unsigned short* __restrict__ w1t,
                                 unsigned short* __restrict__ w2t,
                                 unsigned short* __restrict__ w3t,
                                 int* __restrict__ gcount) {
    int i = blockIdx.x * blockDim.x + threadIdx.x;
    if (i < NBKT + 1) gcount[i] = 0;
    const float* W;
    unsigned short* th;
    int K, M, j;
    if (i < 32768)      { W = W1; th = w1t; K = 128; M = 256; j = i; }
    else if (i < 65536) { W = W2; th = w2t; K = 256; M = 128; j = i - 32768; }
    else if (i < 69632) { W = W3; th = w3t; K = 128; M = 32;  j = i - 65536; }
    else return;
    int k = j / M, m = j % M;
    th[(size_t)m * K + k] = __half_as_ushort(__float2half_rn(W[j]));
}

// ---------------------------------------------------------------------------
// fp16 MFMA GEMM: C[N,M] = A[N,K](fp16) @ W[K,M](fp16, transposed), KS=64
// OUTF16: write fp16 (else f32). SCALE: multiply row by dscale[row].
// ---------------------------------------------------------------------------
template <int BM, int BN, int WM, int WN, bool BIAS, bool RELU, bool OUTF16, bool SCALE>
__global__ __launch_bounds__(256) void gemm_f16(
    const unsigned short* __restrict__ A,
    const unsigned short* __restrict__ Wt,
    const float* __restrict__ bias, const float* __restrict__ dscale,
    float* __restrict__ Cf, unsigned short* __restrict__ Ch,
    int N, int K, int M) {
    constexpr int KS = 64;
    constexpr int LDA = KS + 8;  // 72 halfs/row: rows spread 8 banks, 2-way only
    constexpr int WTM = BM / WM;
    constexpr int WTN = BN / WN;
    constexpr int FM = WTM / 16;
    constexpr int FN = WTN / 16;
    __shared__ unsigned short sA[BM][LDA], sW[BN][LDA];

    const int tid = threadIdx.x;
    const int lane = tid & 63;
    const int w = tid >> 6;
    const int wr = w / WN, wc = w % WN;
    const int row0 = blockIdx.y * BM;
    const int col0 = blockIdx.x * BN;

    f32x4 acc[FM][FN];
#pragma unroll
    for (int m = 0; m < FM; ++m)
#pragma unroll
        for (int nn = 0; nn < FN; ++nn) {
            f32x4 z = {0.f, 0.f, 0.f, 0.f};
            acc[m][nn] = z;
        }

    for (int k0 = 0; k0 < K; k0 += KS) {
        for (int idx = tid; idx < BM * KS / 8; idx += 256) {
            int r = idx / (KS / 8);
            int s = idx % (KS / 8);
            int gr = row0 + r;
            int4 va = make_int4(0, 0, 0, 0);
            if (gr < N) va = *(const int4*)&A[(size_t)gr * K + k0 + s * 8];
            *(int4*)&sA[r][s * 8] = va;
        }
        for (int idx = tid; idx < BN * KS / 8; idx += 256) {
            int c = idx / (KS / 8);
            int s = idx % (KS / 8);
            int gc = col0 + c;
            *(int4*)&sW[c][s * 8] = *(const int4*)&Wt[(size_t)gc * K + k0 + s * 8];
        }
        __syncthreads();

        half8v af[FM][2], wf[FN][2];
        const int koff = (lane >> 4) * 8;
        const int rsel = lane & 15;
#pragma unroll
        for (int m = 0; m < FM; ++m) {
            af[m][0] = *(const half8v*)&sA[wr * WTM + m * 16 + rsel][koff];
            af[m][1] = *(const half8v*)&sA[wr * WTM + m * 16 + rsel][32 + koff];
        }
#pragma unroll
        for (int nn = 0; nn < FN; ++nn) {
            wf[nn][0] = *(const half8v*)&sW[wc * WTN + nn * 16 + rsel][koff];
            wf[nn][1] = *(const half8v*)&sW[wc * WTN + nn * 16 + rsel][32 + koff];
        }
#pragma unroll
        for (int m = 0; m < FM; ++m)
#pragma unroll
            for (int nn = 0; nn < FN; ++nn) {
                acc[m][nn] = __builtin_amdgcn_mfma_f32_16x16x32_f16(af[m][0], wf[nn][0], acc[m][nn], 0, 0, 0);
                acc[m][nn] = __builtin_amdgcn_mfma_f32_16x16x32_f16(af[m][1], wf[nn][1], acc[m][nn], 0, 0, 0);
            }
        __syncthreads();
    }

    // epilogue: D layout col=lane&15, row=(lane>>4)*4+reg (m89-verified)
#pragma unroll
    for (int m = 0; m < FM; ++m) {
#pragma unroll
        for (int r = 0; r < 4; ++r) {
            int row = row0 + wr * WTM + m * 16 + (lane >> 4) * 4 + r;
            if (row >= N) continue;
            float rs = SCALE ? dscale[row] : 1.f;
#pragma unroll
            for (int nn = 0; nn < FN; ++nn) {
                int col = col0 + wc * WTN + nn * 16 + (lane & 15);
                float v = acc[m][nn][r];
                if (BIAS) v += bias[col];
                if (RELU) v = fmaxf(v, 0.f);
                if (SCALE) v *= rs;
                if constexpr (OUTF16) {
                    Ch[(size_t)row * M + col] = __half_as_ushort(__float2half_rn(v));
                } else {
                    Cf[(size_t)row * M + col] = v;
                }
            }
        }
    }
}

// ---------------------------------------------------------------------------
// CSR aggregation over PRE-SCALED fp16 table h' = dinv ⊙ h:
// out[d] = dinv[d] * (h'[d] + Σ_{s∈N(d)} h'[s]) + bias
// Fully-batched masked gather: ALL loads issue 8-deep (clamped idx, masked add)
// ---------------------------------------------------------------------------
__device__ __forceinline__ float4 add4(float4 v, float4 a) {
    a.x += v.x; a.y += v.y; a.z += v.z; a.w += v.w;
    return a;
}

template <int F, int NPB, bool BIAS, bool RELU, bool OUTF16>
__global__ __launch_bounds__((F / 4) * NPB) void agg4h(
    const unsigned short* __restrict__ h, const int* __restrict__ row_start,
    const int* __restrict__ deg_cnt, const unsigned short* __restrict__ csr,
    const float* __restrict__ dinv, const float* __restrict__ bias,
    float* __restrict__ outf, unsigned short* __restrict__ outh, int n) {
    constexpr int L = F / 4;
    const int local = threadIdx.x / L;
    const int lane = threadIdx.x % L;
    const int node = blockIdx.x * NPB + local;
    if (node >= n) return;

    const ushort4* __restrict__ h4 = (const ushort4*)h;
    const float di = dinv[node];

    float4 acc = u8_to_f4(h4[(size_t)node * L + lane]);  // self term h'[d]

    const int beg = row_start[node];
    const int num = deg_cnt[node];
    for (int e = 0; e < num; e += 8) {
        int c[8];
        ushort4 raw[8];
#pragma unroll
        for (int u = 0; u < 8; ++u) {
            int idx = min(e + u, num - 1);           // clamp: dup loads are L1-hot
            c[u] = csr[beg + idx];
        }
#pragma unroll
        for (int u = 0; u < 8; ++u) raw[u] = h4[(size_t)c[u] * L + lane];
#pragma unroll
        for (int u = 0; u < 8; ++u) {
            float4 v = u8_to_f4(raw[u]);
            if (e + u < num) acc = add4(v, acc);     // predicated; order unchanged
        }
    }
    acc.x *= di; acc.y *= di; acc.z *= di; acc.w *= di;
    if (BIAS) {
        const float4 b = ((const float4*)bias)[lane];
        acc.x += b.x; acc.y += b.y; acc.z += b.z; acc.w += b.w;
    }
    if (RELU) {
        acc.x = fmaxf(acc.x, 0.f); acc.y = fmaxf(acc.y, 0.f);
        acc.z = fmaxf(acc.z, 0.f); acc.w = fmaxf(acc.w, 0.f);
    }
    if constexpr (OUTF16) {
        ((ushort4*)outh)[(size_t)node * L + lane] = f4_to_u8(acc);
    } else {
        ((float4*)outf)[(size_t)node * L + lane] = acc;
    }
}

// ---------------------------------------------------------------------------
extern "C" void kernel_launch(void* const* d_in, const int* in_sizes, int n_in,
                              void* d_out, int out_size, void* d_ws, size_t ws_size,
                              hipStream_t stream) {
    const float* x   = (const float*)d_in[0];
    const int*   eix = (const int*)d_in[1];
    const float* W1  = (const float*)d_in[2];
    const float* b1  = (const float*)d_in[3];
    const float* W2  = (const float*)d_in[4];
    const float* b2  = (const float*)d_in[5];
    const float* W3  = (const float*)d_in[6];
    const float* b3  = (const float*)d_in[7];
    float* out = (float*)d_out;

    const int n = NN, E = NE;

    char* p = (char*)d_ws;
    auto alloc = [&](size_t bytes) { void* r = (void*)p; p += align_up(bytes, 256); return r; };
    int*   deg_cnt   = (int*)alloc((size_t)n * 4);
    float* dinv      = (float*)alloc((size_t)n * 4);
    int*   row_start = (int*)alloc((size_t)n * 4);
    int*   gcount    = (int*)alloc((size_t)(NBKT + 1) * 4);
    int*   bstart    = (int*)alloc((size_t)(NBKT + 1) * 4);
    int*   base      = (int*)alloc((size_t)P1B * NBKT * 4);
    unsigned* pairs  = (unsigned*)alloc((size_t)E * 4);
    unsigned short* csr = (unsigned short*)alloc((size_t)E * 2);
    unsigned short* w1t = (unsigned short*)alloc((size_t)128 * 256 * 2);
    unsigned short* w2t = (unsigned short*)alloc((size_t)256 * 128 * 2);
    unsigned short* w3t = (unsigned short*)alloc((size_t)128 * 32 * 2);
    unsigned short* xh   = (unsigned short*)alloc((size_t)n * 128 * 2);  // x'  fp16
    unsigned short* agg0 = (unsigned short*)alloc((size_t)n * 128 * 2);  // agg0 fp16
    unsigned short* h1   = (unsigned short*)alloc((size_t)n * 256 * 2);  // h1  fp16
    unsigned short* h2s  = (unsigned short*)alloc((size_t)n * 128 * 2);  // h2' fp16 (scaled)
    unsigned short* x3   = (unsigned short*)alloc((size_t)n * 128 * 2);  // x3  fp16
    unsigned short* h3s  = (unsigned short*)alloc((size_t)n * 32 * 2);   // h3' fp16 (scaled)
    (void)ws_size; (void)in_sizes; (void)n_in; (void)out_size;

    // ---- weight prep first (also zeroes gcount, ordered before bucket_hist) ----
    prep_weights_all<<<(69632 + 255) / 256, 256, 0, stream>>>(
        W1, W2, W3, w1t, w2t, w3t, gcount);

    // ---- graph preprocessing: bucket-sorted CSR build (+ fused x cast) ----
    bucket_hist<<<P1B, 256, 0, stream>>>(eix, gcount, base, E);
    bucket_scan<<<1, 512, 0, stream>>>(gcount, bstart, NBKT);
    bucket_scatter<<<P1B, 256, 0, stream>>>(eix, bstart, base, pairs, E);
    bucket_finalize<<<NBKT, 256, 0, stream>>>(pairs, bstart, x, row_start, deg_cnt,
                                              dinv, csr, xh, n);

    const int RB = (n + 127) / 128;  // 391 row blocks

    // ---- layer 1: agg0 = A_norm @ x (fp16); h1 = relu(agg0 @ W1 + b1) (fp16)
    agg4h<128, 8, false, false, true><<<(n + 7) / 8, 256, 0, stream>>>(
        xh, row_start, deg_cnt, csr, dinv, nullptr, nullptr, agg0, n);
    gemm_f16<128, 128, 2, 2, true, true, true, false><<<dim3(2, RB), 256, 0, stream>>>(
        agg0, w1t, b1, nullptr, nullptr, h1, n, 128, 256);

    // ---- layer 2: h2' = dinv ⊙ (h1 @ W2) (fp16); x3 = relu(agg + b2) (fp16)
    gemm_f16<128, 128, 2, 2, false, false, true, true><<<dim3(1, RB), 256, 0, stream>>>(
        h1, w2t, nullptr, dinv, nullptr, h2s, n, 256, 128);
    agg4h<128, 8, true, true, true><<<(n + 7) / 8, 256, 0, stream>>>(
        h2s, row_start, deg_cnt, csr, dinv, b2, nullptr, x3, n);

    // ---- layer 3: h3' = dinv ⊙ (x3 @ W3) (fp16); out = agg + b3 (f32)
    gemm_f16<128, 32, 4, 1, false, false, true, true><<<dim3(1, RB), 256, 0, stream>>>(
        x3, w3t, nullptr, dinv, nullptr, h3s, n, 128, 32);
    agg4h<32, 32, true, false, false><<<(n + 31) / 32, 256, 0, stream>>>(
        h3s, row_start, deg_cnt, csr, dinv, b3, out, nullptr, n);
}

// Round 11
// 173.300 us; speedup vs baseline: 4.9876x; 1.0074x over previous
//
#include <hip/hip_runtime.h>
#include <hip/hip_fp16.h>

#define NN 50000
#define NE 800000
#define NBKT 391          // ceil(50000/128) buckets of 128 nodes
#define P1B 256           // blocks in hist/scatter passes

typedef __attribute__((ext_vector_type(8))) _Float16 half8v;  // 8 fp16 in 4 VGPRs
typedef __attribute__((ext_vector_type(4))) float f32x4;

static inline size_t align_up(size_t x, size_t a) { return (x + a - 1) & ~(a - 1); }

union U8 {
    ushort4 u;
    __half2 h[2];
};

__device__ __forceinline__ float4 u8_to_f4(ushort4 uu) {
    U8 c;
    c.u = uu;
    float2 f01 = __half22float2(c.h[0]);
    float2 f23 = __half22float2(c.h[1]);
    return make_float4(f01.x, f01.y, f23.x, f23.y);
}

__device__ __forceinline__ ushort4 f4_to_u8(float4 v) {
    U8 c;
    c.h[0] = __floats2half2_rn(v.x, v.y);
    c.h[1] = __floats2half2_rn(v.z, v.w);
    return c.u;
}

// async global->LDS, 16B per lane (dest = wave-uniform base + lane*16)
__device__ __forceinline__ void gload_lds16(const unsigned short* g, unsigned short* l) {
    __builtin_amdgcn_global_load_lds(
        (const __attribute__((address_space(1))) unsigned int*)g,
        (__attribute__((address_space(3))) unsigned int*)l,
        16, 0, 0);
}

// int64-vs-int32 edge layout probe (values < 2^31 => odd words zero)
__device__ __forceinline__ int detect64(const int* __restrict__ e) {
    int ok = 1;
    for (int k = 1; k < 64; k += 2) ok &= (e[k] == 0);
    return ok;
}

// ---------------------------------------------------------------------------
// P1: per-block bucket histogram -> plain writes to base[block][bucket];
// spare lanes also do the weight transpose+cast (fused prep_weights)
// ---------------------------------------------------------------------------
__global__ __launch_bounds__(256) void bucket_hist(const int* __restrict__ e,
                                                   int* __restrict__ base,
                                                   const float* __restrict__ W1,
                                                   const float* __restrict__ W2,
                                                   const float* __restrict__ W3,
                                                   unsigned short* __restrict__ w1t,
                                                   unsigned short* __restrict__ w2t,
                                                   unsigned short* __restrict__ w3t,
                                                   int E) {
    __shared__ int hist[NBKT];
    const int is64 = detect64(e);
    for (int t = threadIdx.x; t < NBKT; t += 256) hist[t] = 0;
    __syncthreads();
    const int chunk = (E + P1B - 1) / P1B;
    const int b0 = blockIdx.x * chunk;
    const int b1 = min(E, b0 + chunk);
    for (int i = b0 + threadIdx.x; i < b1; i += 256) {
        int d = is64 ? e[2 * (E + i)] : e[E + i];
        atomicAdd(&hist[d >> 7], 1);
    }
    // fused weight prep (grid-stride over 69632 elems)
    for (int i = blockIdx.x * 256 + threadIdx.x; i < 69632; i += P1B * 256) {
        const float* W;
        unsigned short* th;
        int K, M, j;
        if (i < 32768)      { W = W1; th = w1t; K = 128; M = 256; j = i; }
        else if (i < 65536) { W = W2; th = w2t; K = 256; M = 128; j = i - 32768; }
        else                { W = W3; th = w3t; K = 128; M = 32;  j = i - 65536; }
        int k = j / M, m = j % M;
        th[(size_t)m * K + k] = __half_as_ushort(__float2half_rn(W[j]));
    }
    __syncthreads();
    for (int t = threadIdx.x; t < NBKT; t += 256)
        base[blockIdx.x * NBKT + t] = hist[t];
}

// ---------------------------------------------------------------------------
// P2: column prefix over base[P1B][NBKT] (per-block exclusive offsets) +
// bucket exclusive scan -> bstart[0..NBKT]. One block, 512 threads.
// ---------------------------------------------------------------------------
__global__ __launch_bounds__(512) void colsum_scan(int* __restrict__ base,
                                                   int* __restrict__ bstart) {
    __shared__ int s[512];
    const int t = threadIdx.x;
    int total = 0;
    if (t < NBKT) {
        for (int b0 = 0; b0 < P1B; b0 += 8) {
            int v[8];
#pragma unroll
            for (int u = 0; u < 8; ++u) v[u] = base[(size_t)(b0 + u) * NBKT + t];
#pragma unroll
            for (int u = 0; u < 8; ++u) {
                int nv = v[u];
                base[(size_t)(b0 + u) * NBKT + t] = total;
                total += nv;
            }
        }
    }
    s[t] = (t < NBKT) ? total : 0;
    __syncthreads();
    for (int off = 1; off < 512; off <<= 1) {
        int tv = (t >= off) ? s[t - off] : 0;
        __syncthreads();
        s[t] += tv;
        __syncthreads();
    }
    if (t < NBKT) bstart[t] = s[t] - total;
    if (t == 0) bstart[NBKT] = s[511];  // total = E
}

// ---------------------------------------------------------------------------
// P3: scatter packed edges (src u16 | dst_local u7) into bucket-binned order
// ---------------------------------------------------------------------------
__global__ __launch_bounds__(256) void bucket_scatter(const int* __restrict__ e,
                                                      const int* __restrict__ bstart,
                                                      const int* __restrict__ base,
                                                      unsigned* __restrict__ pairs, int E) {
    __shared__ int cur[NBKT];
    const int is64 = detect64(e);
    for (int t = threadIdx.x; t < NBKT; t += 256)
        cur[t] = bstart[t] + base[blockIdx.x * NBKT + t];
    __syncthreads();
    const int chunk = (E + P1B - 1) / P1B;
    const int b0 = blockIdx.x * chunk;
    const int b1 = min(E, b0 + chunk);
    for (int i = b0 + threadIdx.x; i < b1; i += 256) {
        int s = is64 ? e[2 * i] : e[i];
        int d = is64 ? e[2 * (E + i)] : e[E + i];
        int pos = atomicAdd(&cur[d >> 7], 1);
        pairs[pos] = (unsigned)s | ((unsigned)(d & 127) << 16);
    }
}

// ---------------------------------------------------------------------------
// P4: one block per bucket. (1) local deg count + scan -> deg/row_start/dinv;
// (2) LDS-cursor scatter src -> contiguous u16 CSR range; (3) fused cast of
// this bucket's x rows to pre-scaled fp16 (x' = dinv ⊙ x).
// ---------------------------------------------------------------------------
__global__ __launch_bounds__(256) void bucket_finalize(const unsigned* __restrict__ pairs,
                                                       const int* __restrict__ bstart,
                                                       const float* __restrict__ x,
                                                       int* __restrict__ row_start,
                                                       int* __restrict__ deg_cnt,
                                                       float* __restrict__ dinv,
                                                       unsigned short* __restrict__ csr,
                                                       unsigned short* __restrict__ xh, int n) {
    __shared__ int ldeg[128];
    __shared__ int lscan[128];
    __shared__ int cur[128];
    __shared__ float sdinv[128];
    const int bkt = blockIdx.x;
    const int s0 = bstart[bkt], s1 = bstart[bkt + 1];
    if (threadIdx.x < 128) ldeg[threadIdx.x] = 0;
    __syncthreads();
    for (int i = s0 + threadIdx.x; i < s1; i += 256)
        atomicAdd(&ldeg[pairs[i] >> 16], 1);
    __syncthreads();
    if (threadIdx.x < 128) lscan[threadIdx.x] = ldeg[threadIdx.x];
    __syncthreads();
    for (int off = 1; off < 128; off <<= 1) {
        int v = 0;
        if (threadIdx.x < 128 && threadIdx.x >= off) v = lscan[threadIdx.x - off];
        __syncthreads();
        if (threadIdx.x < 128) lscan[threadIdx.x] += v;
        __syncthreads();
    }
    if (threadIdx.x < 128) {
        int node = (bkt << 7) + threadIdx.x;
        int exc = s0 + lscan[threadIdx.x] - ldeg[threadIdx.x];
        cur[threadIdx.x] = exc;
        float di = rsqrtf((float)(ldeg[threadIdx.x] + 1));  // +1 self-loop
        sdinv[threadIdx.x] = di;
        if (node < n) {
            row_start[node] = exc;
            deg_cnt[node] = ldeg[threadIdx.x];
            dinv[node] = di;
        }
    }
    __syncthreads();
    // csr scatter (u16 src)
    for (int i = s0 + threadIdx.x; i < s1; i += 256) {
        unsigned pr = pairs[i];
        int pos = atomicAdd(&cur[pr >> 16], 1);
        csr[pos] = (unsigned short)(pr & 0xFFFFu);
    }
    // fused cast: x rows of this bucket -> pre-scaled fp16 (linear, coalesced)
    for (int idx = threadIdx.x; idx < 128 * 32; idx += 256) {
        int ln = idx >> 5;         // local node
        int c4 = idx & 31;         // float4 chunk within row (128 feats)
        int node = (bkt << 7) + ln;
        if (node < n) {
            float4 v = ((const float4*)x)[(size_t)node * 32 + c4];
            float s = sdinv[ln];
            v.x *= s; v.y *= s; v.z *= s; v.w *= s;
            ((ushort4*)xh)[(size_t)node * 32 + c4] = f4_to_u8(v);
        }
    }
}

// ---------------------------------------------------------------------------
// fp16 MFMA GEMM: C[N,M] = A[N,K](fp16) @ W[K,M](fp16, transposed), KS=64.
// Staging via global_load_lds (16B/lane) into UNPADDED [*][64] LDS with
// chunk XOR swizzle: slot s holds global chunk s^(r&7); read side applies
// the same XOR -> ~2-way conflicts only (free).
// OUTF16: write fp16 (else f32). SCALE: multiply row by dscale[row].
// ---------------------------------------------------------------------------
template <int BM, int BN, int WM, int WN, bool BIAS, bool RELU, bool OUTF16, bool SCALE>
__global__ __launch_bounds__(256) void gemm_f16(
    const unsigned short* __restrict__ A,
    const unsigned short* __restrict__ Wt,
    const float* __restrict__ bias, const float* __restrict__ dscale,
    float* __restrict__ Cf, unsigned short* __restrict__ Ch,
    int N, int K, int M) {
    constexpr int KS = 64;
    constexpr int WTM = BM / WM;
    constexpr int WTN = BN / WN;
    constexpr int FM = WTM / 16;
    constexpr int FN = WTN / 16;
    constexpr int ACH = BM * 8;  // 16B chunks in A tile (multiple of 256)
    constexpr int WCH = BN * 8;
    __shared__ unsigned short sA[BM][KS], sW[BN][KS];

    const int tid = threadIdx.x;
    const int lane = tid & 63;
    const int w = tid >> 6;
    const int wr = w / WN, wc = w % WN;
    const int row0 = blockIdx.y * BM;
    const int col0 = blockIdx.x * BN;

    f32x4 acc[FM][FN];
#pragma unroll
    for (int m = 0; m < FM; ++m)
#pragma unroll
        for (int nn = 0; nn < FN; ++nn) {
            f32x4 z = {0.f, 0.f, 0.f, 0.f};
            acc[m][nn] = z;
        }

    for (int k0 = 0; k0 < K; k0 += KS) {
        // stage A tile: chunk idx -> (r, s); source chunk pre-swizzled s^(r&7)
#pragma unroll
        for (int b = 0; b < ACH; b += 256) {
            int idx = b + tid;
            int r = idx >> 3, s = idx & 7;
            int gr = row0 + r;
            int sp = s ^ (r & 7);
            if (gr < N)
                gload_lds16(&A[(size_t)gr * K + k0 + sp * 8], &sA[0][0] + idx * 8);
            // rows >= N: LDS stays stale; their C rows are never stored
        }
#pragma unroll
        for (int b = 0; b < WCH; b += 256) {
            int idx = b + tid;
            int r = idx >> 3, s = idx & 7;
            int gc = col0 + r;  // always < M (M % BN == 0)
            int sp = s ^ (r & 7);
            gload_lds16(&Wt[(size_t)gc * K + k0 + sp * 8], &sW[0][0] + idx * 8);
        }
        __syncthreads();  // compiler drains vmcnt before barrier

        half8v af[FM][2], wf[FN][2];
        const int rsel = lane & 15;
        const int cb = lane >> 4;  // logical chunk 0..3 (first 32 halfs)
#pragma unroll
        for (int m = 0; m < FM; ++m) {
            int rr = wr * WTM + m * 16 + rsel;
            af[m][0] = *(const half8v*)&sA[rr][((cb) ^ (rr & 7)) * 8];
            af[m][1] = *(const half8v*)&sA[rr][((cb + 4) ^ (rr & 7)) * 8];
        }
#pragma unroll
        for (int nn = 0; nn < FN; ++nn) {
            int rr = wc * WTN + nn * 16 + rsel;
            wf[nn][0] = *(const half8v*)&sW[rr][((cb) ^ (rr & 7)) * 8];
            wf[nn][1] = *(const half8v*)&sW[rr][((cb + 4) ^ (rr & 7)) * 8];
        }
#pragma unroll
        for (int m = 0; m < FM; ++m)
#pragma unroll
            for (int nn = 0; nn < FN; ++nn) {
                acc[m][nn] = __builtin_amdgcn_mfma_f32_16x16x32_f16(af[m][0], wf[nn][0], acc[m][nn], 0, 0, 0);
                acc[m][nn] = __builtin_amdgcn_mfma_f32_16x16x32_f16(af[m][1], wf[nn][1], acc[m][nn], 0, 0, 0);
            }
        __syncthreads();
    }

    // epilogue: D layout col=lane&15, row=(lane>>4)*4+reg (m89-verified)
#pragma unroll
    for (int m = 0; m < FM; ++m) {
#pragma unroll
        for (int r = 0; r < 4; ++r) {
            int row = row0 + wr * WTM + m * 16 + (lane >> 4) * 4 + r;
            if (row >= N) continue;
            float rs = SCALE ? dscale[row] : 1.f;
#pragma unroll
            for (int nn = 0; nn < FN; ++nn) {
                int col = col0 + wc * WTN + nn * 16 + (lane & 15);
                float v = acc[m][nn][r];
                if (BIAS) v += bias[col];
                if (RELU) v = fmaxf(v, 0.f);
                if (SCALE) v *= rs;
                if constexpr (OUTF16) {
                    Ch[(size_t)row * M + col] = __half_as_ushort(__float2half_rn(v));
                } else {
                    Cf[(size_t)row * M + col] = v;
                }
            }
        }
    }
}

// ---------------------------------------------------------------------------
// CSR aggregation over PRE-SCALED fp16 table h' = dinv ⊙ h:
// out[d] = dinv[d] * (h'[d] + Σ_{s∈N(d)} h'[s]) + bias
// Fully-batched masked gather, 16-deep, dual f32 accumulators
// ---------------------------------------------------------------------------
__device__ __forceinline__ float4 add4(float4 v, float4 a) {
    a.x += v.x; a.y += v.y; a.z += v.z; a.w += v.w;
    return a;
}

template <int F, int NPB, bool BIAS, bool RELU, bool OUTF16>
__global__ __launch_bounds__((F / 4) * NPB) void agg4h(
    const unsigned short* __restrict__ h, const int* __restrict__ row_start,
    const int* __restrict__ deg_cnt, const unsigned short* __restrict__ csr,
    const float* __restrict__ dinv, const float* __restrict__ bias,
    float* __restrict__ outf, unsigned short* __restrict__ outh, int n) {
    constexpr int L = F / 4;
    const int local = threadIdx.x / L;
    const int lane = threadIdx.x % L;
    const int node = blockIdx.x * NPB + local;
    if (node >= n) return;

    const ushort4* __restrict__ h4 = (const ushort4*)h;
    const float di = dinv[node];

    float4 acc0 = u8_to_f4(h4[(size_t)node * L + lane]);  // self term h'[d]
    float4 acc1 = make_float4(0.f, 0.f, 0.f, 0.f);

    const int beg = row_start[node];
    const int num = deg_cnt[node];
    for (int e = 0; e < num; e += 16) {
        int c[16];
        ushort4 raw[16];
#pragma unroll
        for (int u = 0; u < 16; ++u) {
            int idx = min(e + u, num - 1);           // clamp: dup loads are L1-hot
            c[u] = csr[beg + idx];
        }
#pragma unroll
        for (int u = 0; u < 16; ++u) raw[u] = h4[(size_t)c[u] * L + lane];
#pragma unroll
        for (int u = 0; u < 8; ++u) {
            float4 v = u8_to_f4(raw[u]);
            if (e + u < num) acc0 = add4(v, acc0);   // predicated
        }
#pragma unroll
        for (int u = 8; u < 16; ++u) {
            float4 v = u8_to_f4(raw[u]);
            if (e + u < num) acc1 = add4(v, acc1);
        }
    }
    float4 acc = add4(acc1, acc0);
    acc.x *= di; acc.y *= di; acc.z *= di; acc.w *= di;
    if (BIAS) {
        const float4 b = ((const float4*)bias)[lane];
        acc.x += b.x; acc.y += b.y; acc.z += b.z; acc.w += b.w;
    }
    if (RELU) {
        acc.x = fmaxf(acc.x, 0.f); acc.y = fmaxf(acc.y, 0.f);
        acc.z = fmaxf(acc.z, 0.f); acc.w = fmaxf(acc.w, 0.f);
    }
    if constexpr (OUTF16) {
        ((ushort4*)outh)[(size_t)node * L + lane] = f4_to_u8(acc);
    } else {
        ((float4*)outf)[(size_t)node * L + lane] = acc;
    }
}

// ---------------------------------------------------------------------------
extern "C" void kernel_launch(void* const* d_in, const int* in_sizes, int n_in,
                              void* d_out, int out_size, void* d_ws, size_t ws_size,
                              hipStream_t stream) {
    const float* x   = (const float*)d_in[0];
    const int*   eix = (const int*)d_in[1];
    const float* W1  = (const float*)d_in[2];
    const float* b1  = (const float*)d_in[3];
    const float* W2  = (const float*)d_in[4];
    const float* b2  = (const float*)d_in[5];
    const float* W3  = (const float*)d_in[6];
    const float* b3  = (const float*)d_in[7];
    float* out = (float*)d_out;

    const int n = NN, E = NE;

    char* p = (char*)d_ws;
    auto alloc = [&](size_t bytes) { void* r = (void*)p; p += align_up(bytes, 256); return r; };
    int*   deg_cnt   = (int*)alloc((size_t)n * 4);
    float* dinv      = (float*)alloc((size_t)n * 4);
    int*   row_start = (int*)alloc((size_t)n * 4);
    int*   bstart    = (int*)alloc((size_t)(NBKT + 1) * 4);
    int*   base      = (int*)alloc((size_t)P1B * NBKT * 4);
    unsigned* pairs  = (unsigned*)alloc((size_t)E * 4);
    unsigned short* csr = (unsigned short*)alloc((size_t)E * 2);
    unsigned short* w1t = (unsigned short*)alloc((size_t)128 * 256 * 2);
    unsigned short* w2t = (unsigned short*)alloc((size_t)256 * 128 * 2);
    unsigned short* w3t = (unsigned short*)alloc((size_t)128 * 32 * 2);
    unsigned short* xh   = (unsigned short*)alloc((size_t)n * 128 * 2);  // x'  fp16
    unsigned short* agg0 = (unsigned short*)alloc((size_t)n * 128 * 2);  // agg0 fp16
    unsigned short* h1   = (unsigned short*)alloc((size_t)n * 256 * 2);  // h1  fp16
    unsigned short* h2s  = (unsigned short*)alloc((size_t)n * 128 * 2);  // h2' fp16 (scaled)
    unsigned short* x3   = (unsigned short*)alloc((size_t)n * 128 * 2);  // x3  fp16
    unsigned short* h3s  = (unsigned short*)alloc((size_t)n * 32 * 2);   // h3' fp16 (scaled)
    (void)ws_size; (void)in_sizes; (void)n_in; (void)out_size;

    // ---- CSR build: hist(+weight prep, plain writes) -> colsum+scan -> scatter
    //      -> finalize(+fused x cast). No memsets, no global atomics in hist.
    bucket_hist<<<P1B, 256, 0, stream>>>(eix, base, W1, W2, W3, w1t, w2t, w3t, E);
    colsum_scan<<<1, 512, 0, stream>>>(base, bstart);
    bucket_scatter<<<P1B, 256, 0, stream>>>(eix, bstart, base, pairs, E);
    bucket_finalize<<<NBKT, 256, 0, stream>>>(pairs, bstart, x, row_start, deg_cnt,
                                              dinv, csr, xh, n);

    const int RB = (n + 127) / 128;  // 391 row blocks

    // ---- layer 1: agg0 = A_norm @ x (fp16); h1 = relu(agg0 @ W1 + b1) (fp16)
    agg4h<128, 8, false, false, true><<<(n + 7) / 8, 256, 0, stream>>>(
        xh, row_start, deg_cnt, csr, dinv, nullptr, nullptr, agg0, n);
    gemm_f16<128, 128, 2, 2, true, true, true, false><<<dim3(2, RB), 256, 0, stream>>>(
        agg0, w1t, b1, nullptr, nullptr, h1, n, 128, 256);

    // ---- layer 2: h2' = dinv ⊙ (h1 @ W2) (fp16); x3 = relu(agg + b2) (fp16)
    gemm_f16<128, 128, 2, 2, false, false, true, true><<<dim3(1, RB), 256, 0, stream>>>(
        h1, w2t, nullptr, dinv, nullptr, h2s, n, 256, 128);
    agg4h<128, 8, true, true, true><<<(n + 7) / 8, 256, 0, stream>>>(
        h2s, row_start, deg_cnt, csr, dinv, b2, nullptr, x3, n);

    // ---- layer 3: h3' = dinv ⊙ (x3 @ W3) (fp16); out = agg + b3 (f32)
    gemm_f16<128, 32, 4, 1, false, false, true, true><<<dim3(1, RB), 256, 0, stream>>>(
        x3, w3t, nullptr, dinv, nullptr, h3s, n, 128, 32);
    agg4h<32, 32, true, false, false><<<(n + 31) / 32, 256, 0, stream>>>(
        h3s, row_start, deg_cnt, csr, dinv, b3, out, nullptr, n);
}

// Round 12
// 159.459 us; speedup vs baseline: 5.4205x; 1.0868x over previous
//
#include <hip/hip_runtime.h>
#include <hip/hip_fp16.h>

#define NN 50000
#define NE 800000
#define NBKT 391          // ceil(50000/128) buckets of 128 nodes
#define P1B 256           // blocks in hist/scatter passes

typedef __attribute__((ext_vector_type(8))) _Float16 half8v;  // 8 fp16 in 4 VGPRs
typedef __attribute__((ext_vector_type(4))) float f32x4;

static inline size_t align_up(size_t x, size_t a) { return (x + a - 1) & ~(a - 1); }

union U8 {
    ushort4 u;
    __half2 h[2];
};

__device__ __forceinline__ float4 u8_to_f4(ushort4 uu) {
    U8 c;
    c.u = uu;
    float2 f01 = __half22float2(c.h[0]);
    float2 f23 = __half22float2(c.h[1]);
    return make_float4(f01.x, f01.y, f23.x, f23.y);
}

__device__ __forceinline__ ushort4 f4_to_u8(float4 v) {
    U8 c;
    c.h[0] = __floats2half2_rn(v.x, v.y);
    c.h[1] = __floats2half2_rn(v.z, v.w);
    return c.u;
}

// async global->LDS, 16B per lane (dest = wave-uniform base + lane*16)
__device__ __forceinline__ void gload_lds16(const unsigned short* g, unsigned short* l) {
    __builtin_amdgcn_global_load_lds(
        (const __attribute__((address_space(1))) unsigned int*)g,
        (__attribute__((address_space(3))) unsigned int*)l,
        16, 0, 0);
}

// int64-vs-int32 edge layout probe (values < 2^31 => odd words zero)
__device__ __forceinline__ int detect64(const int* __restrict__ e) {
    int ok = 1;
    for (int k = 1; k < 64; k += 2) ok &= (e[k] == 0);
    return ok;
}

// ---------------------------------------------------------------------------
// P1: per-block bucket histogram -> plain writes to base[block][bucket];
// spare lanes also do the weight transpose+cast (fused prep_weights)
// ---------------------------------------------------------------------------
__global__ __launch_bounds__(256) void bucket_hist(const int* __restrict__ e,
                                                   int* __restrict__ base,
                                                   const float* __restrict__ W1,
                                                   const float* __restrict__ W2,
                                                   const float* __restrict__ W3,
                                                   unsigned short* __restrict__ w1t,
                                                   unsigned short* __restrict__ w2t,
                                                   unsigned short* __restrict__ w3t,
                                                   int E) {
    __shared__ int hist[NBKT];
    const int is64 = detect64(e);
    for (int t = threadIdx.x; t < NBKT; t += 256) hist[t] = 0;
    __syncthreads();
    const int chunk = (E + P1B - 1) / P1B;
    const int b0 = blockIdx.x * chunk;
    const int b1 = min(E, b0 + chunk);
    for (int i = b0 + threadIdx.x; i < b1; i += 256) {
        int d = is64 ? e[2 * (E + i)] : e[E + i];
        atomicAdd(&hist[d >> 7], 1);
    }
    // fused weight prep (grid-stride over 69632 elems)
    for (int i = blockIdx.x * 256 + threadIdx.x; i < 69632; i += P1B * 256) {
        const float* W;
        unsigned short* th;
        int K, M, j;
        if (i < 32768)      { W = W1; th = w1t; K = 128; M = 256; j = i; }
        else if (i < 65536) { W = W2; th = w2t; K = 256; M = 128; j = i - 32768; }
        else                { W = W3; th = w3t; K = 128; M = 32;  j = i - 65536; }
        int k = j / M, m = j % M;
        th[(size_t)m * K + k] = __half_as_ushort(__float2half_rn(W[j]));
    }
    __syncthreads();
    for (int t = threadIdx.x; t < NBKT; t += 256)
        base[blockIdx.x * NBKT + t] = hist[t];
}

// ---------------------------------------------------------------------------
// P2: column prefix over base[P1B][NBKT] (per-block exclusive offsets) +
// bucket exclusive scan -> bstart[0..NBKT]. One block, 512 threads.
// ---------------------------------------------------------------------------
__global__ __launch_bounds__(512) void colsum_scan(int* __restrict__ base,
                                                   int* __restrict__ bstart) {
    __shared__ int s[512];
    const int t = threadIdx.x;
    int total = 0;
    if (t < NBKT) {
        for (int b0 = 0; b0 < P1B; b0 += 8) {
            int v[8];
#pragma unroll
            for (int u = 0; u < 8; ++u) v[u] = base[(size_t)(b0 + u) * NBKT + t];
#pragma unroll
            for (int u = 0; u < 8; ++u) {
                int nv = v[u];
                base[(size_t)(b0 + u) * NBKT + t] = total;
                total += nv;
            }
        }
    }
    s[t] = (t < NBKT) ? total : 0;
    __syncthreads();
    for (int off = 1; off < 512; off <<= 1) {
        int tv = (t >= off) ? s[t - off] : 0;
        __syncthreads();
        s[t] += tv;
        __syncthreads();
    }
    if (t < NBKT) bstart[t] = s[t] - total;
    if (t == 0) bstart[NBKT] = s[511];  // total = E
}

// ---------------------------------------------------------------------------
// P3: scatter packed edges (src u16 | dst_local u7) into bucket-binned order
// ---------------------------------------------------------------------------
__global__ __launch_bounds__(256) void bucket_scatter(const int* __restrict__ e,
                                                      const int* __restrict__ bstart,
                                                      const int* __restrict__ base,
                                                      unsigned* __restrict__ pairs, int E) {
    __shared__ int cur[NBKT];
    const int is64 = detect64(e);
    for (int t = threadIdx.x; t < NBKT; t += 256)
        cur[t] = bstart[t] + base[blockIdx.x * NBKT + t];
    __syncthreads();
    const int chunk = (E + P1B - 1) / P1B;
    const int b0 = blockIdx.x * chunk;
    const int b1 = min(E, b0 + chunk);
    for (int i = b0 + threadIdx.x; i < b1; i += 256) {
        int s = is64 ? e[2 * i] : e[i];
        int d = is64 ? e[2 * (E + i)] : e[E + i];
        int pos = atomicAdd(&cur[d >> 7], 1);
        pairs[pos] = (unsigned)s | ((unsigned)(d & 127) << 16);
    }
}

// ---------------------------------------------------------------------------
// P4: one block per bucket. (1) local deg count + scan -> ninfo{beg,deg}/dinv;
// (2) LDS-cursor scatter src -> contiguous u16 CSR range; (3) fused cast of
// this bucket's x rows to pre-scaled fp16 (x' = dinv ⊙ x).
// ---------------------------------------------------------------------------
__global__ __launch_bounds__(256) void bucket_finalize(const unsigned* __restrict__ pairs,
                                                       const int* __restrict__ bstart,
                                                       const float* __restrict__ x,
                                                       int2* __restrict__ ninfo,
                                                       float* __restrict__ dinv,
                                                       unsigned short* __restrict__ csr,
                                                       unsigned short* __restrict__ xh, int n) {
    __shared__ int ldeg[128];
    __shared__ int lscan[128];
    __shared__ int cur[128];
    __shared__ float sdinv[128];
    const int bkt = blockIdx.x;
    const int s0 = bstart[bkt], s1 = bstart[bkt + 1];
    if (threadIdx.x < 128) ldeg[threadIdx.x] = 0;
    __syncthreads();
    for (int i = s0 + threadIdx.x; i < s1; i += 256)
        atomicAdd(&ldeg[pairs[i] >> 16], 1);
    __syncthreads();
    if (threadIdx.x < 128) lscan[threadIdx.x] = ldeg[threadIdx.x];
    __syncthreads();
    for (int off = 1; off < 128; off <<= 1) {
        int v = 0;
        if (threadIdx.x < 128 && threadIdx.x >= off) v = lscan[threadIdx.x - off];
        __syncthreads();
        if (threadIdx.x < 128) lscan[threadIdx.x] += v;
        __syncthreads();
    }
    if (threadIdx.x < 128) {
        int node = (bkt << 7) + threadIdx.x;
        int exc = s0 + lscan[threadIdx.x] - ldeg[threadIdx.x];
        cur[threadIdx.x] = exc;
        float di = rsqrtf((float)(ldeg[threadIdx.x] + 1));  // +1 self-loop
        sdinv[threadIdx.x] = di;
        if (node < n) {
            ninfo[node] = make_int2(exc, ldeg[threadIdx.x]);
            dinv[node] = di;
        }
    }
    __syncthreads();
    // csr scatter (u16 src)
    for (int i = s0 + threadIdx.x; i < s1; i += 256) {
        unsigned pr = pairs[i];
        int pos = atomicAdd(&cur[pr >> 16], 1);
        csr[pos] = (unsigned short)(pr & 0xFFFFu);
    }
    // fused cast: x rows of this bucket -> pre-scaled fp16 (linear, coalesced)
    for (int idx = threadIdx.x; idx < 128 * 32; idx += 256) {
        int ln = idx >> 5;         // local node
        int c4 = idx & 31;         // float4 chunk within row (128 feats)
        int node = (bkt << 7) + ln;
        if (node < n) {
            float4 v = ((const float4*)x)[(size_t)node * 32 + c4];
            float s = sdinv[ln];
            v.x *= s; v.y *= s; v.z *= s; v.w *= s;
            ((ushort4*)xh)[(size_t)node * 32 + c4] = f4_to_u8(v);
        }
    }
}

// ---------------------------------------------------------------------------
// FUSED layer-1+2 GEMM: per 128-row tile,
//   h1 = relu(agg0 @ W1 + b1)   [128 x 256]  (kept in LDS, never hits HBM)
//   h2' = dinv ⊙ (h1 @ W2)      [128 x 128]  (fp16 out)
// Processed in two 128-col halves of h1; sW reused for W1a/W2a/W1b/W2b.
// Chunk-XOR-swizzled gload_lds staging (as in gemm_f16); sH padded to 136.
// ---------------------------------------------------------------------------
__global__ __launch_bounds__(256) void gemm12(
    const unsigned short* __restrict__ A,     // agg0 [N][128] fp16
    const unsigned short* __restrict__ W1t,   // [256][128] fp16
    const unsigned short* __restrict__ W2t,   // [128][256] fp16
    const float* __restrict__ b1,
    const float* __restrict__ dinv,
    unsigned short* __restrict__ H2,          // [N][128] fp16 (scaled)
    int N) {
    __shared__ unsigned short sA[128][128];   // 32KB, swizzled chunks
    __shared__ unsigned short sW[128][128];   // 32KB, swizzled, reused 4x
    __shared__ unsigned short sH[128][136];   // 34.8KB, padded (16B-aligned rows)

    const int tid = threadIdx.x;
    const int lane = tid & 63;
    const int w = tid >> 6;
    const int wr = w >> 1, wc = w & 1;        // 2x2 waves over 128x128
    const int row0 = blockIdx.x * 128;
    const int rsel = lane & 15;
    const int cq = lane >> 4;                 // 0..3

    // stage A tile (rows x K=128): 2048 16B-chunks, slot s holds chunk (s&8)|((s^r)&7)
#pragma unroll
    for (int b = 0; b < 2048; b += 256) {
        int idx = b + tid;
        int r = idx >> 4, s = idx & 15;
        int gr = row0 + r;
        int sp = (s & 8) | ((s ^ r) & 7);
        if (gr < N) gload_lds16(&A[(size_t)gr * 128 + sp * 8], &sA[0][0] + idx * 8);
        // rows >= N: stale LDS; those output rows are never stored
    }

    f32x4 acc2[4][4];
#pragma unroll
    for (int m = 0; m < 4; ++m)
#pragma unroll
        for (int nn = 0; nn < 4; ++nn) {
            f32x4 z = {0.f, 0.f, 0.f, 0.f};
            acc2[m][nn] = z;
        }

    for (int half = 0; half < 2; ++half) {
        __syncthreads();  // drains A-stage (half 0) / prior acc2 reads of sW (half 1)
        // stage W1 half: h1-cols half*128..+127, K=128
#pragma unroll
        for (int b = 0; b < 2048; b += 256) {
            int idx = b + tid;
            int r = idx >> 4, s = idx & 15;
            int sp = (s & 8) | ((s ^ r) & 7);
            gload_lds16(&W1t[(size_t)(half * 128 + r) * 128 + sp * 8], &sW[0][0] + idx * 8);
        }
        __syncthreads();

        // acc1 = sA @ sW^T   (output 128x128, K=128)
        f32x4 acc1[4][4];
#pragma unroll
        for (int m = 0; m < 4; ++m)
#pragma unroll
            for (int nn = 0; nn < 4; ++nn) {
                f32x4 z = {0.f, 0.f, 0.f, 0.f};
                acc1[m][nn] = z;
            }
#pragma unroll
        for (int ks = 0; ks < 4; ++ks) {
            half8v af[4], wf[4];
            int c = ks * 4 + cq;
#pragma unroll
            for (int m = 0; m < 4; ++m) {
                int rr = wr * 64 + m * 16 + rsel;
                int cp = (c & 8) | ((c ^ rr) & 7);
                af[m] = *(const half8v*)&sA[rr][cp * 8];
            }
#pragma unroll
            for (int nn = 0; nn < 4; ++nn) {
                int rr = wc * 64 + nn * 16 + rsel;
                int cp = (c & 8) | ((c ^ rr) & 7);
                wf[nn] = *(const half8v*)&sW[rr][cp * 8];
            }
#pragma unroll
            for (int m = 0; m < 4; ++m)
#pragma unroll
                for (int nn = 0; nn < 4; ++nn)
                    acc1[m][nn] = __builtin_amdgcn_mfma_f32_16x16x32_f16(af[m], wf[nn], acc1[m][nn], 0, 0, 0);
        }

        // bias+relu -> fp16 -> sH (row-major h1 half)
        float b1v[4];
#pragma unroll
        for (int nn = 0; nn < 4; ++nn)
            b1v[nn] = b1[half * 128 + wc * 64 + nn * 16 + rsel];
#pragma unroll
        for (int m = 0; m < 4; ++m)
#pragma unroll
            for (int nn = 0; nn < 4; ++nn)
#pragma unroll
                for (int r = 0; r < 4; ++r) {
                    int rl = wr * 64 + m * 16 + cq * 4 + r;
                    int cl = wc * 64 + nn * 16 + rsel;
                    float v = fmaxf(acc1[m][nn][r] + b1v[nn], 0.f);
                    sH[rl][cl] = __half_as_ushort(__float2half_rn(v));
                }
        __syncthreads();  // sH complete; safe to overwrite sW

        // stage W2 K-slice: rows (h2 cols) 0..127, K in [half*128, half*128+128)
#pragma unroll
        for (int b = 0; b < 2048; b += 256) {
            int idx = b + tid;
            int r = idx >> 4, s = idx & 15;
            int sp = (s & 8) | ((s ^ r) & 7);
            gload_lds16(&W2t[(size_t)r * 256 + half * 128 + sp * 8], &sW[0][0] + idx * 8);
        }
        __syncthreads();

        // acc2 += sH @ sW^T  (K=128 local)
#pragma unroll
        for (int ks = 0; ks < 4; ++ks) {
            half8v ah[4], wf[4];
            int koff = ks * 32 + cq * 8;
            int c = ks * 4 + cq;
#pragma unroll
            for (int m = 0; m < 4; ++m) {
                int rr = wr * 64 + m * 16 + rsel;
                ah[m] = *(const half8v*)&sH[rr][koff];
            }
#pragma unroll
            for (int nn = 0; nn < 4; ++nn) {
                int rr = wc * 64 + nn * 16 + rsel;
                int cp = (c & 8) | ((c ^ rr) & 7);
                wf[nn] = *(const half8v*)&sW[rr][cp * 8];
            }
#pragma unroll
            for (int m = 0; m < 4; ++m)
#pragma unroll
                for (int nn = 0; nn < 4; ++nn)
                    acc2[m][nn] = __builtin_amdgcn_mfma_f32_16x16x32_f16(ah[m], wf[nn], acc2[m][nn], 0, 0, 0);
        }
    }

    // epilogue: h2' = dinv ⊙ acc2, fp16 out
#pragma unroll
    for (int m = 0; m < 4; ++m)
#pragma unroll
        for (int r = 0; r < 4; ++r) {
            int row = row0 + wr * 64 + m * 16 + cq * 4 + r;
            if (row >= N) continue;
            float rs = dinv[row];
#pragma unroll
            for (int nn = 0; nn < 4; ++nn) {
                int col = wc * 64 + nn * 16 + rsel;
                H2[(size_t)row * 128 + col] =
                    __half_as_ushort(__float2half_rn(acc2[m][nn][r] * rs));
            }
        }
}

// ---------------------------------------------------------------------------
// fp16 MFMA GEMM (single): C[N,M] = A[N,K](fp16) @ W[K,M](fp16, transposed),
// KS=64, gload_lds + chunk-XOR swizzle. OUTF16 / SCALE as before.
// ---------------------------------------------------------------------------
template <int BM, int BN, int WM, int WN, bool BIAS, bool RELU, bool OUTF16, bool SCALE>
__global__ __launch_bounds__(256) void gemm_f16(
    const unsigned short* __restrict__ A,
    const unsigned short* __restrict__ Wt,
    const float* __restrict__ bias, const float* __restrict__ dscale,
    float* __restrict__ Cf, unsigned short* __restrict__ Ch,
    int N, int K, int M) {
    constexpr int KS = 64;
    constexpr int WTM = BM / WM;
    constexpr int WTN = BN / WN;
    constexpr int FM = WTM / 16;
    constexpr int FN = WTN / 16;
    constexpr int ACH = BM * 8;
    constexpr int WCH = BN * 8;
    __shared__ unsigned short sA[BM][KS], sW[BN][KS];

    const int tid = threadIdx.x;
    const int lane = tid & 63;
    const int w = tid >> 6;
    const int wr = w / WN, wc = w % WN;
    const int row0 = blockIdx.y * BM;
    const int col0 = blockIdx.x * BN;

    f32x4 acc[FM][FN];
#pragma unroll
    for (int m = 0; m < FM; ++m)
#pragma unroll
        for (int nn = 0; nn < FN; ++nn) {
            f32x4 z = {0.f, 0.f, 0.f, 0.f};
            acc[m][nn] = z;
        }

    for (int k0 = 0; k0 < K; k0 += KS) {
#pragma unroll
        for (int b = 0; b < ACH; b += 256) {
            int idx = b + tid;
            int r = idx >> 3, s = idx & 7;
            int gr = row0 + r;
            int sp = s ^ (r & 7);
            if (gr < N)
                gload_lds16(&A[(size_t)gr * K + k0 + sp * 8], &sA[0][0] + idx * 8);
        }
#pragma unroll
        for (int b = 0; b < WCH; b += 256) {
            int idx = b + tid;
            int r = idx >> 3, s = idx & 7;
            int gc = col0 + r;
            int sp = s ^ (r & 7);
            gload_lds16(&Wt[(size_t)gc * K + k0 + sp * 8], &sW[0][0] + idx * 8);
        }
        __syncthreads();

        half8v af[FM][2], wf[FN][2];
        const int rsel = lane & 15;
        const int cb = lane >> 4;
#pragma unroll
        for (int m = 0; m < FM; ++m) {
            int rr = wr * WTM + m * 16 + rsel;
            af[m][0] = *(const half8v*)&sA[rr][((cb) ^ (rr & 7)) * 8];
            af[m][1] = *(const half8v*)&sA[rr][((cb + 4) ^ (rr & 7)) * 8];
        }
#pragma unroll
        for (int nn = 0; nn < FN; ++nn) {
            int rr = wc * WTN + nn * 16 + rsel;
            wf[nn][0] = *(const half8v*)&sW[rr][((cb) ^ (rr & 7)) * 8];
            wf[nn][1] = *(const half8v*)&sW[rr][((cb + 4) ^ (rr & 7)) * 8];
        }
#pragma unroll
        for (int m = 0; m < FM; ++m)
#pragma unroll
            for (int nn = 0; nn < FN; ++nn) {
                acc[m][nn] = __builtin_amdgcn_mfma_f32_16x16x32_f16(af[m][0], wf[nn][0], acc[m][nn], 0, 0, 0);
                acc[m][nn] = __builtin_amdgcn_mfma_f32_16x16x32_f16(af[m][1], wf[nn][1], acc[m][nn], 0, 0, 0);
            }
        __syncthreads();
    }

#pragma unroll
    for (int m = 0; m < FM; ++m) {
#pragma unroll
        for (int r = 0; r < 4; ++r) {
            int row = row0 + wr * WTM + m * 16 + (lane >> 4) * 4 + r;
            if (row >= N) continue;
            float rs = SCALE ? dscale[row] : 1.f;
#pragma unroll
            for (int nn = 0; nn < FN; ++nn) {
                int col = col0 + wc * WTN + nn * 16 + (lane & 15);
                float v = acc[m][nn][r];
                if (BIAS) v += bias[col];
                if (RELU) v = fmaxf(v, 0.f);
                if (SCALE) v *= rs;
                if constexpr (OUTF16) {
                    Ch[(size_t)row * M + col] = __half_as_ushort(__float2half_rn(v));
                } else {
                    Cf[(size_t)row * M + col] = v;
                }
            }
        }
    }
}

// ---------------------------------------------------------------------------
// CSR aggregation over PRE-SCALED fp16 table h' = dinv ⊙ h:
// out[d] = dinv[d] * (h'[d] + Σ_{s∈N(d)} h'[s]) + bias
// ninfo = {beg, deg} packed; fully-batched 16-deep gathers, dual accumulators
// ---------------------------------------------------------------------------
__device__ __forceinline__ float4 add4(float4 v, float4 a) {
    a.x += v.x; a.y += v.y; a.z += v.z; a.w += v.w;
    return a;
}

template <int F, int NPB, bool BIAS, bool RELU, bool OUTF16>
__global__ __launch_bounds__((F / 4) * NPB) void agg4h(
    const unsigned short* __restrict__ h, const int2* __restrict__ ninfo,
    const unsigned short* __restrict__ csr,
    const float* __restrict__ dinv, const float* __restrict__ bias,
    float* __restrict__ outf, unsigned short* __restrict__ outh, int n) {
    constexpr int L = F / 4;
    const int local = threadIdx.x / L;
    const int lane = threadIdx.x % L;
    const int node = blockIdx.x * NPB + local;
    if (node >= n) return;

    const ushort4* __restrict__ h4 = (const ushort4*)h;
    const float di = dinv[node];
    const int2 info = ninfo[node];
    const int beg = info.x;
    const int num = info.y;

    float4 acc0 = u8_to_f4(h4[(size_t)node * L + lane]);  // self term h'[d]
    float4 acc1 = make_float4(0.f, 0.f, 0.f, 0.f);

    for (int e = 0; e < num; e += 16) {
        int c[16];
        ushort4 raw[16];
#pragma unroll
        for (int u = 0; u < 16; ++u) {
            int idx = min(e + u, num - 1);           // clamp: dup loads are L1-hot
            c[u] = csr[beg + idx];
        }
#pragma unroll
        for (int u = 0; u < 16; ++u) raw[u] = h4[(size_t)c[u] * L + lane];
#pragma unroll
        for (int u = 0; u < 8; ++u) {
            float4 v = u8_to_f4(raw[u]);
            if (e + u < num) acc0 = add4(v, acc0);   // predicated
        }
#pragma unroll
        for (int u = 8; u < 16; ++u) {
            float4 v = u8_to_f4(raw[u]);
            if (e + u < num) acc1 = add4(v, acc1);
        }
    }
    float4 acc = add4(acc1, acc0);
    acc.x *= di; acc.y *= di; acc.z *= di; acc.w *= di;
    if (BIAS) {
        const float4 b = ((const float4*)bias)[lane];
        acc.x += b.x; acc.y += b.y; acc.z += b.z; acc.w += b.w;
    }
    if (RELU) {
        acc.x = fmaxf(acc.x, 0.f); acc.y = fmaxf(acc.y, 0.f);
        acc.z = fmaxf(acc.z, 0.f); acc.w = fmaxf(acc.w, 0.f);
    }
    if constexpr (OUTF16) {
        ((ushort4*)outh)[(size_t)node * L + lane] = f4_to_u8(acc);
    } else {
        ((float4*)outf)[(size_t)node * L + lane] = acc;
    }
}

// ---------------------------------------------------------------------------
extern "C" void kernel_launch(void* const* d_in, const int* in_sizes, int n_in,
                              void* d_out, int out_size, void* d_ws, size_t ws_size,
                              hipStream_t stream) {
    const float* x   = (const float*)d_in[0];
    const int*   eix = (const int*)d_in[1];
    const float* W1  = (const float*)d_in[2];
    const float* b1  = (const float*)d_in[3];
    const float* W2  = (const float*)d_in[4];
    const float* b2  = (const float*)d_in[5];
    const float* W3  = (const float*)d_in[6];
    const float* b3  = (const float*)d_in[7];
    float* out = (float*)d_out;

    const int n = NN, E = NE;

    char* p = (char*)d_ws;
    auto alloc = [&](size_t bytes) { void* r = (void*)p; p += align_up(bytes, 256); return r; };
    int2*  ninfo     = (int2*)alloc((size_t)n * 8);
    float* dinv      = (float*)alloc((size_t)n * 4);
    int*   bstart    = (int*)alloc((size_t)(NBKT + 1) * 4);
    int*   base      = (int*)alloc((size_t)P1B * NBKT * 4);
    unsigned* pairs  = (unsigned*)alloc((size_t)E * 4);
    unsigned short* csr = (unsigned short*)alloc((size_t)E * 2);
    unsigned short* w1t = (unsigned short*)alloc((size_t)128 * 256 * 2);
    unsigned short* w2t = (unsigned short*)alloc((size_t)256 * 128 * 2);
    unsigned short* w3t = (unsigned short*)alloc((size_t)128 * 32 * 2);
    unsigned short* xh   = (unsigned short*)alloc((size_t)n * 128 * 2);  // x'  fp16
    unsigned short* agg0 = (unsigned short*)alloc((size_t)n * 128 * 2);  // agg0 fp16
    unsigned short* h2s  = (unsigned short*)alloc((size_t)n * 128 * 2);  // h2' fp16 (scaled)
    unsigned short* x3   = (unsigned short*)alloc((size_t)n * 128 * 2);  // x3  fp16
    unsigned short* h3s  = (unsigned short*)alloc((size_t)n * 32 * 2);   // h3' fp16 (scaled)
    (void)ws_size; (void)in_sizes; (void)n_in; (void)out_size;

    // ---- CSR build: hist(+weight prep) -> colsum+scan -> scatter ->
    //      finalize(+fused x cast)
    bucket_hist<<<P1B, 256, 0, stream>>>(eix, base, W1, W2, W3, w1t, w2t, w3t, E);
    colsum_scan<<<1, 512, 0, stream>>>(base, bstart);
    bucket_scatter<<<P1B, 256, 0, stream>>>(eix, bstart, base, pairs, E);
    bucket_finalize<<<NBKT, 256, 0, stream>>>(pairs, bstart, x, ninfo, dinv, csr, xh, n);

    const int RB = (n + 127) / 128;  // 391 row blocks

    // ---- layer 1 agg: agg0 = A_norm-gather(x') (fp16)
    agg4h<128, 8, false, false, true><<<(n + 7) / 8, 256, 0, stream>>>(
        xh, ninfo, csr, dinv, nullptr, nullptr, agg0, n);

    // ---- FUSED gemm1+gemm2: h2' = dinv ⊙ (relu(agg0 @ W1 + b1) @ W2) (fp16)
    gemm12<<<RB, 256, 0, stream>>>(agg0, w1t, w2t, b1, dinv, h2s, n);

    // ---- layer 2 agg: x3 = relu(agg(h2') + b2) (fp16)
    agg4h<128, 8, true, true, true><<<(n + 7) / 8, 256, 0, stream>>>(
        h2s, ninfo, csr, dinv, b2, nullptr, x3, n);

    // ---- layer 3: h3' = dinv ⊙ (x3 @ W3) (fp16); out = agg(h3') + b3 (f32)
    gemm_f16<128, 32, 4, 1, false, false, true, true><<<dim3(1, RB), 256, 0, stream>>>(
        x3, w3t, nullptr, dinv, nullptr, h3s, n, 128, 32);
    agg4h<32, 32, true, false, false><<<(n + 31) / 32, 256, 0, stream>>>(
        h3s, ninfo, csr, dinv, b3, out, nullptr, n);
}